// Round 1
// baseline (562.929 us; speedup 1.0000x reference)
//
#include <hip/hip_runtime.h>
#include <hip/hip_bf16.h>
#include <cstddef>

// ---------------- problem constants ----------------
#define LSEQ   1024
#define DM     384
#define DSSM   512
#define NSTATE 512      // K * D_STATE (shared across heads in the reference einsums)
#define HK     32       // K * NHEADS combined heads
#define HD     64       // head dim
#define CHUNKSZ 256
#define NC     4
#define CBCDT  264
#define CTOT   776      // 512 + 264
#define DMLP   256

__device__ __forceinline__ float siluf(float x)    { return x / (1.f + expf(-x)); }
__device__ __forceinline__ float softplusf(float x){ return fmaxf(x, 0.f) + log1pf(expf(-fabsf(x))); }

// direction k, sequence pos l -> row-major spatial index m (32x32 grid)
__device__ __forceinline__ int dir_src(int k, int l) {
  switch (k) {
    case 0:  return l;
    case 1:  return ((l & 31) << 5) | (l >> 5);
    case 2:  return 1023 - l;
    default: { int lr = 1023 - l; return ((lr & 31) << 5) | (lr >> 5); }
  }
}

#define FMA16(a,b) do{ \
  acc[0][0] += (a).x*(b).x; acc[0][1] += (a).x*(b).y; acc[0][2] += (a).x*(b).z; acc[0][3] += (a).x*(b).w; \
  acc[1][0] += (a).y*(b).x; acc[1][1] += (a).y*(b).y; acc[1][2] += (a).y*(b).z; acc[1][3] += (a).y*(b).w; \
  acc[2][0] += (a).z*(b).x; acc[2][1] += (a).z*(b).y; acc[2][2] += (a).z*(b).z; acc[2][3] += (a).z*(b).w; \
  acc[3][0] += (a).w*(b).x; acc[3][1] += (a).w*(b).y; acc[3][2] += (a).w*(b).z; acc[3][3] += (a).w*(b).w; \
}while(0)

// ---------------- generic SGEMM: C[s] = A[s](MxK) * B(KxN), row-major ----------------
// grid: (ceil(N/64), M/64, 2 streams); block 256. K multiple of 16, M multiple of 64.
__global__ __launch_bounds__(256) void sgemm_nn(
    const float* __restrict__ A0, const float* __restrict__ A1,
    const float* __restrict__ B, float* __restrict__ C,
    int M, int N, int Kc, long long cstride)
{
  __shared__ float As[16][68];   // [k][m]
  __shared__ float Bs[16][68];   // [k][n]
  const int s = blockIdx.z;
  const float* A = s ? A1 : A0;
  float* Cp = C + (size_t)s * (size_t)cstride;
  const int n0 = blockIdx.x * 64, m0 = blockIdx.y * 64;
  const int tid = threadIdx.x, tx = tid & 15, ty = tid >> 4;
  float acc[4][4] = {};
  for (int k0 = 0; k0 < Kc; k0 += 16) {
#pragma unroll
    for (int i = 0; i < 4; ++i) {
      int idx = tid + i * 256;
      int r = idx >> 4, c = idx & 15;
      As[c][r] = A[(size_t)(m0 + r) * Kc + k0 + c];
    }
#pragma unroll
    for (int i = 0; i < 4; ++i) {
      int idx = tid + i * 256;
      int r = idx >> 6, c = idx & 63;
      int n = n0 + c;
      Bs[r][c] = (n < N) ? B[(size_t)(k0 + r) * N + n] : 0.f;
    }
    __syncthreads();
#pragma unroll
    for (int k = 0; k < 16; ++k) {
      float4 a = *(const float4*)&As[k][ty * 4];
      float4 b = *(const float4*)&Bs[k][tx * 4];
      FMA16(a, b);
    }
    __syncthreads();
  }
#pragma unroll
  for (int i = 0; i < 4; ++i) {
    int m = m0 + ty * 4 + i;
#pragma unroll
    for (int j = 0; j < 4; ++j) {
      int n = n0 + tx * 4 + j;
      if (n < N) Cp[(size_t)m * N + n] = acc[i][j];
    }
  }
}

// ---------------- depthwise 3x3 conv + bias + SiLU; writes xbcT[s][m][c] ----------------
// grid (1024, 2), block 256 (lanes over channels -> coalesced)
__global__ __launch_bounds__(256) void k_conv(
    const float* __restrict__ xs_pre, const float* __restrict__ bc_pre,
    const float* __restrict__ wxs, const float* __restrict__ bxs,
    const float* __restrict__ wbc, const float* __restrict__ bbc,
    float* __restrict__ xbcT)
{
  const int m = blockIdx.x, s = blockIdx.y;
  const int h = m >> 5, w = m & 31;
  const float* xp = xs_pre + (size_t)s * LSEQ * DSSM;
  const float* bp = bc_pre + (size_t)s * LSEQ * CBCDT;
  for (int c = threadIdx.x; c < CTOT; c += 256) {
    const float* src; int stride; const float* wt; float bias;
    if (c < DSSM) { src = xp + c; stride = DSSM; wt = wxs + (size_t)c * 9; bias = bxs[c]; }
    else { int cb = c - DSSM; src = bp + cb; stride = CBCDT; wt = wbc + (size_t)cb * 9; bias = bbc[cb]; }
    float acc = bias;
#pragma unroll
    for (int dh = -1; dh <= 1; ++dh) {
      int h2 = h + dh; if (h2 < 0 || h2 > 31) continue;
#pragma unroll
      for (int dw = -1; dw <= 1; ++dw) {
        int w2 = w + dw; if (w2 < 0 || w2 > 31) continue;
        acc += src[(size_t)(h2 * 32 + w2) * stride] * wt[(dh + 1) * 3 + (dw + 1)];
      }
    }
    xbcT[((size_t)s * LSEQ + m) * CTOT + c] = siluf(acc);
  }
}

// ---------------- gather x*dt into Xh[s][kh][l][p] ----------------
// grid (256, 32, 2), block 256: 4 l-rows per block, 64 p-lanes
__global__ __launch_bounds__(256) void k_gather_x(
    const float* __restrict__ xbcT, const float* __restrict__ dt_bias,
    float* __restrict__ Xh)
{
  const int s = blockIdx.z, kh = blockIdx.y;
  const int l = blockIdx.x * 4 + (threadIdx.x >> 6);
  const int p = threadIdx.x & 63;
  const int k = kh >> 3, hh = kh & 7;
  const int m = dir_src(k, l);
  const float* row = xbcT + ((size_t)s * LSEQ + m) * CTOT;
  float dtv = softplusf(row[768 + hh] + dt_bias[kh]);
  Xh[(((size_t)s * HK + kh) * LSEQ + l) * HD + p] = row[hh * HD + p] * dtv;
}

// ---------------- gather B/C + dA ----------------
// grid (1024, 4, 2), block 128
__global__ __launch_bounds__(128) void k_gather_bc(
    const float* __restrict__ xbcT, const float* __restrict__ dt_bias,
    const float* __restrict__ A_logs,
    float* __restrict__ Bmat, float* __restrict__ Cmat, float* __restrict__ dAbuf)
{
  const int l = blockIdx.x, k = blockIdx.y, s = blockIdx.z;
  const int n = threadIdx.x;
  const int m = dir_src(k, l);
  const float* row = xbcT + ((size_t)s * LSEQ + m) * CTOT;
  Bmat[((size_t)s * LSEQ + l) * NSTATE + k * 128 + n] = row[512 + n];
  Cmat[((size_t)s * LSEQ + l) * NSTATE + k * 128 + n] = row[640 + n];
  if (n < 8) {
    int kh = k * 8 + n;
    float dtv = softplusf(row[768 + n] + dt_bias[kh]);
    dAbuf[((size_t)s * HK + kh) * LSEQ + l] = dtv * (-expf(A_logs[kh]));
  }
}

// ---------------- inclusive cumsum of dA within each chunk ----------------
// grid (4, 32, 2), block 256
__global__ __launch_bounds__(256) void k_cumsum(float* __restrict__ dAbuf)
{
  __shared__ float buf[CHUNKSZ];
  const int z = blockIdx.x, kh = blockIdx.y, s = blockIdx.z, t = threadIdx.x;
  float* p = dAbuf + ((size_t)s * HK + kh) * LSEQ + z * CHUNKSZ;
  buf[t] = p[t];
  __syncthreads();
  for (int off = 1; off < CHUNKSZ; off <<= 1) {
    float add = (t >= off) ? buf[t - off] : 0.f;
    __syncthreads();
    buf[t] += add;
    __syncthreads();
  }
  p[t] = buf[t];
}

// ---------------- CB[s][z] = Cr * Br^T (256x256, K=512) ----------------
// grid (4, 4, 8=s*4+z), block 256
__global__ __launch_bounds__(256) void k_cb(
    const float* __restrict__ Cmat, const float* __restrict__ Bmat,
    float* __restrict__ CBb)
{
  __shared__ float As[16][68];   // [k][i]
  __shared__ float Bs[16][68];   // [k][j]
  const int sz = blockIdx.z, s = sz >> 2, z = sz & 3;
  const float* Ap = Cmat + ((size_t)s * LSEQ + z * CHUNKSZ) * NSTATE;
  const float* Bp = Bmat + ((size_t)s * LSEQ + z * CHUNKSZ) * NSTATE;
  float* Cp = CBb + (size_t)sz * CHUNKSZ * CHUNKSZ;
  const int i0 = blockIdx.y * 64, j0 = blockIdx.x * 64;
  const int tid = threadIdx.x, tx = tid & 15, ty = tid >> 4;
  float acc[4][4] = {};
  for (int k0 = 0; k0 < NSTATE; k0 += 16) {
#pragma unroll
    for (int i = 0; i < 4; ++i) {
      int idx = tid + i * 256;
      int r = idx >> 4, c = idx & 15;
      As[c][r] = Ap[(size_t)(i0 + r) * NSTATE + k0 + c];
    }
#pragma unroll
    for (int i = 0; i < 4; ++i) {
      int idx = tid + i * 256;
      int r = idx >> 4, c = idx & 15;
      Bs[c][r] = Bp[(size_t)(j0 + r) * NSTATE + k0 + c];
    }
    __syncthreads();
#pragma unroll
    for (int k = 0; k < 16; ++k) {
      float4 a = *(const float4*)&As[k][ty * 4];
      float4 b = *(const float4*)&Bs[k][tx * 4];
      FMA16(a, b);
    }
    __syncthreads();
  }
#pragma unroll
  for (int i = 0; i < 4; ++i)
#pragma unroll
    for (int j = 0; j < 4; ++j)
      Cp[(size_t)(i0 + ty * 4 + i) * CHUNKSZ + j0 + tx * 4 + j] = acc[i][j];
}

// ---------------- states[s][z][kh][p][n] = sum_c xdt[c][p]*decay[c] * B[c][n] ----------------
// grid (8 n-tiles, 32, 8), block 256
__global__ __launch_bounds__(256) void k_states(
    const float* __restrict__ Xh, const float* __restrict__ Bmat,
    const float* __restrict__ dAcs, float* __restrict__ states)
{
  __shared__ float decay[CHUNKSZ];
  __shared__ float As[16][68];   // [c][p]
  __shared__ float Bs[16][68];   // [c][n]
  const int sz = blockIdx.z, s = sz >> 2, z = sz & 3;
  const int kh = blockIdx.y, n0 = blockIdx.x * 64;
  const int tid = threadIdx.x, tx = tid & 15, ty = tid >> 4;
  const float* dAp = dAcs + ((size_t)s * HK + kh) * LSEQ + z * CHUNKSZ;
  decay[tid] = expf(dAp[CHUNKSZ - 1] - dAp[tid]);
  __syncthreads();
  const float* Xp = Xh + (((size_t)s * HK + kh) * LSEQ + z * CHUNKSZ) * HD;
  const float* Bp = Bmat + ((size_t)s * LSEQ + z * CHUNKSZ) * NSTATE;
  float acc[4][4] = {};
  for (int c0 = 0; c0 < CHUNKSZ; c0 += 16) {
#pragma unroll
    for (int i = 0; i < 4; ++i) {
      int idx = tid + i * 256;
      int r = idx >> 6, c = idx & 63;
      As[r][c] = Xp[(size_t)(c0 + r) * HD + c] * decay[c0 + r];
    }
#pragma unroll
    for (int i = 0; i < 4; ++i) {
      int idx = tid + i * 256;
      int r = idx >> 6, c = idx & 63;
      Bs[r][c] = Bp[(size_t)(c0 + r) * NSTATE + n0 + c];
    }
    __syncthreads();
#pragma unroll
    for (int k = 0; k < 16; ++k) {
      float4 a = *(const float4*)&As[k][ty * 4];
      float4 b = *(const float4*)&Bs[k][tx * 4];
      FMA16(a, b);
    }
    __syncthreads();
  }
  float* Sp = states + (((size_t)sz * HK + kh) * HD) * NSTATE + n0;
#pragma unroll
  for (int i = 0; i < 4; ++i)
#pragma unroll
    for (int j = 0; j < 4; ++j)
      Sp[(size_t)(ty * 4 + i) * NSTATE + tx * 4 + j] = acc[i][j];
}

// ---------------- inter-chunk scan in place: states[z] := state entering chunk z ----------------
// grid (8192), block 256
__global__ __launch_bounds__(256) void k_scan(
    float* __restrict__ states, const float* __restrict__ dAcs)
{
  size_t gid = (size_t)blockIdx.x * 256 + threadIdx.x;   // 2*32*64*512 total
  const int n = gid & 511;
  const int p = (gid >> 9) & 63;
  const int kh = (gid >> 15) & 31;
  const int s = (int)(gid >> 20);
  const float* dA = dAcs + ((size_t)s * HK + kh) * LSEQ;
  float carry = 0.f;
#pragma unroll
  for (int z = 0; z < NC; ++z) {
    size_t off = ((((size_t)(s * 4 + z) * HK + kh) * HD) + p) * NSTATE + n;
    float tmp = states[off];
    states[off] = carry;
    float cdec = expf(dA[z * CHUNKSZ + CHUNKSZ - 1]);
    carry = carry * cdec + tmp;
  }
}

// ---------------- Y = Ydiag + Yoff (per chunk, head, 64-row i-tile) ----------------
// grid (4 i-tiles, 32, 8), block 256
__global__ __launch_bounds__(256) void k_y(
    const float* __restrict__ CBb, const float* __restrict__ Xh,
    const float* __restrict__ Cmat, const float* __restrict__ prev,
    const float* __restrict__ dAcs, float* __restrict__ Y)
{
  __shared__ float seg[CHUNKSZ];
  __shared__ float eA[64];
  __shared__ float As[16][68];
  __shared__ float Bs[16][68];
  const int sz = blockIdx.z, s = sz >> 2, z = sz & 3;
  const int kh = blockIdx.y, it = blockIdx.x, i0 = it * 64;
  const int tid = threadIdx.x, tx = tid & 15, ty = tid >> 4;

  const float* dAp = dAcs + ((size_t)s * HK + kh) * LSEQ + z * CHUNKSZ;
  seg[tid] = dAp[tid];
  __syncthreads();
  if (tid < 64) eA[tid] = expf(seg[i0 + tid]);
  float segI[4];
#pragma unroll
  for (int m = 0; m < 4; ++m) segI[m] = seg[i0 + ty * 4 + m];
  __syncthreads();

  float acc[4][4] = {};
  const float* CBp = CBb + (size_t)sz * CHUNKSZ * CHUNKSZ;
  const float* Xp  = Xh + (((size_t)s * HK + kh) * LSEQ + z * CHUNKSZ) * HD;

  // phase 1: Ydiag  (j <= i lower-triangular)
  for (int k0 = 0; k0 < i0 + 64; k0 += 16) {
#pragma unroll
    for (int i = 0; i < 4; ++i) {
      int idx = tid + i * 256;
      int r = idx >> 4, c = idx & 15;
      As[c][r] = CBp[(size_t)(i0 + r) * CHUNKSZ + k0 + c];
    }
#pragma unroll
    for (int i = 0; i < 4; ++i) {
      int idx = tid + i * 256;
      int r = idx >> 6, c = idx & 63;
      Bs[r][c] = Xp[(size_t)(k0 + r) * HD + c];
    }
    __syncthreads();
    if (k0 + 16 <= i0) {
#pragma unroll
      for (int k = 0; k < 16; ++k) {
        float sj = seg[k0 + k];
        float4 b = *(const float4*)&Bs[k][tx * 4];
#pragma unroll
        for (int m = 0; m < 4; ++m) {
          float w = As[k][ty * 4 + m] * expf(segI[m] - sj);
          acc[m][0] += w * b.x; acc[m][1] += w * b.y; acc[m][2] += w * b.z; acc[m][3] += w * b.w;
        }
      }
    } else {
#pragma unroll
      for (int k = 0; k < 16; ++k) {
        int j = k0 + k;
        float sj = seg[j];
        float4 b = *(const float4*)&Bs[k][tx * 4];
#pragma unroll
        for (int m = 0; m < 4; ++m) {
          int i = i0 + ty * 4 + m;
          float w = (i >= j) ? As[k][ty * 4 + m] * expf(segI[m] - sj) : 0.f;
          acc[m][0] += w * b.x; acc[m][1] += w * b.y; acc[m][2] += w * b.z; acc[m][3] += w * b.w;
        }
      }
    }
    __syncthreads();
  }

  // phase 2: Yoff = (Cr * exp(dAcs)) @ prev^T   (K = NSTATE)
  const float* Cp = Cmat + ((size_t)s * LSEQ + z * CHUNKSZ) * NSTATE;
  const float* Pp = prev + (((size_t)sz * HK + kh) * HD) * NSTATE;
  for (int n0 = 0; n0 < NSTATE; n0 += 16) {
#pragma unroll
    for (int i = 0; i < 4; ++i) {
      int idx = tid + i * 256;
      int r = idx >> 4, c = idx & 15;
      As[c][r] = Cp[(size_t)(i0 + r) * NSTATE + n0 + c] * eA[r];
    }
#pragma unroll
    for (int i = 0; i < 4; ++i) {
      int idx = tid + i * 256;
      int p = idx >> 4, c = idx & 15;
      Bs[c][p] = Pp[(size_t)p * NSTATE + n0 + c];
    }
    __syncthreads();
#pragma unroll
    for (int k = 0; k < 16; ++k) {
      float4 b = *(const float4*)&Bs[k][tx * 4];
#pragma unroll
      for (int m = 0; m < 4; ++m) {
        float w = As[k][ty * 4 + m];
        acc[m][0] += w * b.x; acc[m][1] += w * b.y; acc[m][2] += w * b.z; acc[m][3] += w * b.w;
      }
    }
    __syncthreads();
  }

  float* Yp = Y + (((size_t)s * LSEQ + z * CHUNKSZ + i0) * HK + kh) * HD;
#pragma unroll
  for (int m = 0; m < 4; ++m)
#pragma unroll
    for (int j = 0; j < 4; ++j)
      Yp[(size_t)(ty * 4 + m) * HK * HD + tx * 4 + j] = acc[m][j];
}

// ---------------- combine 4 directions + D*x + gated RMSNorm + MLP half ----------------
// grid (1024, 2), block 256
__global__ __launch_bounds__(256) void k_combine(
    const float* __restrict__ Y, const float* __restrict__ xbcT,
    const float* __restrict__ skip, const float* __restrict__ Ds,
    const float* __restrict__ normw, float* __restrict__ out768)
{
  const int m = blockIdx.x, s = blockIdx.y, t = threadIdx.x;
  const int h = m >> 5, w = m & 31;
  const int l0 = m, l1 = (w << 5) | h, l2 = 1023 - m, l3 = 1023 - ((w << 5) | h);
  const float* Yb = Y + (size_t)s * LSEQ * (HK * HD);
  const float* xrow = xbcT + ((size_t)s * LSEQ + m) * CTOT;
  const float* srow = skip + ((size_t)s * LSEQ + m) * 1024;

  float g[2];
  float ss = 0.f;
#pragma unroll
  for (int q = 0; q < 2; ++q) {
    int d = t + q * 256;
    int hh = d >> 6, p = d & 63;
    float dsum = Ds[hh] + Ds[hh + 8] + Ds[hh + 16] + Ds[hh + 24];
    float val = Yb[((size_t)l0 * HK + hh) * HD + p]
              + Yb[((size_t)l1 * HK + 8 + hh) * HD + p]
              + Yb[((size_t)l2 * HK + 16 + hh) * HD + p]
              + Yb[((size_t)l3 * HK + 24 + hh) * HD + p]
              + xrow[d] * dsum;
    float zv = srow[512 + d];
    g[q] = val * siluf(zv);
    ss += g[q] * g[q];
  }
  // block reduce over 512 values
  for (int off = 32; off > 0; off >>= 1) ss += __shfl_down(ss, off, 64);
  __shared__ float red[4];
  if ((t & 63) == 0) red[t >> 6] = ss;
  __syncthreads();
  float total = red[0] + red[1] + red[2] + red[3];
  float scale = rsqrtf(total * (1.f / 512.f) + 1e-5f);

  float* orow = out768 + ((size_t)s * LSEQ + m) * 768;
#pragma unroll
  for (int q = 0; q < 2; ++q) {
    int d = t + q * 256;
    orow[256 + d] = g[q] * scale * normw[d];
  }
  float z0 = srow[t], x0 = srow[256 + t];
  orow[t] = siluf(z0) * x0;
}

// ---------------- workspace layout (floats) ----------------
constexpr size_t SZ_SKIP = 2u * LSEQ * 1024;
constexpr size_t SZ_XBCT = 2u * LSEQ * CTOT;
constexpr size_t SZ_XH   = 2u * HK * LSEQ * HD;
constexpr size_t SZ_BC   = 2u * LSEQ * NSTATE;
constexpr size_t SZ_DA   = 2u * HK * LSEQ;
constexpr size_t SZ_CB   = 2u * NC * CHUNKSZ * CHUNKSZ;
constexpr size_t SZ_Y    = 2u * LSEQ * HK * HD;
constexpr size_t SZ_O768 = 2u * LSEQ * 768;
constexpr size_t SZ_ST   = 2u * NC * HK * HD * NSTATE;

constexpr size_t OFF_SKIP = 0;
constexpr size_t OFF_XBCT = OFF_SKIP + SZ_SKIP;
constexpr size_t OFF_XH   = OFF_XBCT + SZ_XBCT;
constexpr size_t OFF_B    = OFF_XH + SZ_XH;
constexpr size_t OFF_C    = OFF_B + SZ_BC;
constexpr size_t OFF_DA   = OFF_C + SZ_BC;
constexpr size_t OFF_CB   = OFF_DA + SZ_DA;
constexpr size_t OFF_Y    = OFF_CB + SZ_CB;
constexpr size_t OFF_O768 = OFF_Y + SZ_Y;
constexpr size_t OFF_ST   = OFF_O768 + SZ_O768;
// xs_pre / bc_pre lifetimes (gemm->conv) are disjoint from states (k_states->k_y): overlay
constexpr size_t OFF_XSP  = OFF_ST;
constexpr size_t OFF_BCP  = OFF_XSP + 2u * LSEQ * DSSM;

extern "C" void kernel_launch(void* const* d_in, const int* in_sizes, int n_in,
                              void* d_out, int out_size, void* d_ws, size_t ws_size,
                              hipStream_t stream)
{
  const float* u1     = (const float*)d_in[0];
  const float* u2     = (const float*)d_in[1];
  const float* u2c1   = (const float*)d_in[2];
  const float* u1c2   = (const float*)d_in[3];
  const float* W_skip = (const float*)d_in[4];
  const float* W_xs   = (const float*)d_in[5];
  const float* W_bcdt = (const float*)d_in[6];
  const float* cxw    = (const float*)d_in[7];
  const float* cxb    = (const float*)d_in[8];
  const float* cbw    = (const float*)d_in[9];
  const float* cbb    = (const float*)d_in[10];
  const float* Ds     = (const float*)d_in[11];
  const float* normw  = (const float*)d_in[12];
  const float* W_out  = (const float*)d_in[13];
  const float* dt_b   = (const float*)d_in[14];
  const float* A_logs = (const float*)d_in[15];
  float* out = (float*)d_out;
  float* ws  = (float*)d_ws;

  float* skip   = ws + OFF_SKIP;
  float* xbcT   = ws + OFF_XBCT;
  float* Xh     = ws + OFF_XH;
  float* Bmat   = ws + OFF_B;
  float* Cmat   = ws + OFF_C;
  float* dAcs   = ws + OFF_DA;
  float* CBb    = ws + OFF_CB;
  float* Ybuf   = ws + OFF_Y;
  float* o768   = ws + OFF_O768;
  float* states = ws + OFF_ST;
  float* xs_pre = ws + OFF_XSP;
  float* bc_pre = ws + OFF_BCP;

  // 1-3: input GEMMs
  sgemm_nn<<<dim3(16, 16, 2), 256, 0, stream>>>(u1, u2, W_skip, skip, LSEQ, 1024, DM, (long long)LSEQ * 1024);
  sgemm_nn<<<dim3(8, 16, 2), 256, 0, stream>>>(u1, u2, W_xs, xs_pre, LSEQ, DSSM, DM, (long long)LSEQ * DSSM);
  sgemm_nn<<<dim3(5, 16, 2), 256, 0, stream>>>(u2c1, u1c2, W_bcdt, bc_pre, LSEQ, CBCDT, DM, (long long)LSEQ * CBCDT);
  // 4: depthwise conv + silu
  k_conv<<<dim3(1024, 2), 256, 0, stream>>>(xs_pre, bc_pre, cxw, cxb, cbw, cbb, xbcT);
  // 5-6: directional gathers
  k_gather_x<<<dim3(256, 32, 2), 256, 0, stream>>>(xbcT, dt_b, Xh);
  k_gather_bc<<<dim3(1024, 4, 2), 128, 0, stream>>>(xbcT, dt_b, A_logs, Bmat, Cmat, dAcs);
  // 7: per-chunk cumsum
  k_cumsum<<<dim3(4, 32, 2), 256, 0, stream>>>(dAcs);
  // 8: CB
  k_cb<<<dim3(4, 4, 8), 256, 0, stream>>>(Cmat, Bmat, CBb);
  // 9: per-chunk states
  k_states<<<dim3(8, 32, 8), 256, 0, stream>>>(Xh, Bmat, dAcs, states);
  // 10: inter-chunk scan (states -> prev, in place)
  k_scan<<<dim3(8192), 256, 0, stream>>>(states, dAcs);
  // 11: Ydiag + Yoff
  k_y<<<dim3(4, 32, 8), 256, 0, stream>>>(CBb, Xh, Cmat, states, dAcs, Ybuf);
  // 12: combine + gated rmsnorm + mlp half
  k_combine<<<dim3(1024, 2), 256, 0, stream>>>(Ybuf, xbcT, skip, Ds, normw, o768);
  // 13: output GEMM
  sgemm_nn<<<dim3(6, 16, 2), 256, 0, stream>>>(o768, o768 + (size_t)LSEQ * 768, W_out, out, LSEQ, DM, 768, (long long)LSEQ * DM);
}

// Round 2
// 301.969 us; speedup vs baseline: 1.8642x; 1.8642x over previous
//
#include <hip/hip_runtime.h>
#include <hip/hip_bf16.h>
#include <cstddef>

// ---------------- problem constants ----------------
#define LSEQ   1024
#define DM     384
#define DSSM   512
#define NSTATE 512      // K * D_STATE (shared across heads in the reference einsums)
#define HK     32       // K * NHEADS combined heads
#define HD     64       // head dim
#define CHUNKSZ 256
#define NC     4
#define CBCDT  264
#define CTOT   776      // 512 + 264
#define DMLP   256

typedef __attribute__((ext_vector_type(8))) short short8;
typedef __attribute__((ext_vector_type(4))) float f32x4;

__device__ __forceinline__ float siluf(float x)    { return x / (1.f + expf(-x)); }
__device__ __forceinline__ float softplusf(float x){ return fmaxf(x, 0.f) + log1pf(expf(-fabsf(x))); }

__device__ __forceinline__ ushort f2bf(float f) {
  union { float f; unsigned u; } v; v.f = f;
  unsigned r = v.u + 0x7fffu + ((v.u >> 16) & 1u);
  return (ushort)(r >> 16);
}
__device__ __forceinline__ float bf2f(ushort h) {
  union { unsigned u; float f; } v; v.u = ((unsigned)h) << 16;
  return v.f;
}

// direction k, sequence pos l -> row-major spatial index m (32x32 grid)
__device__ __forceinline__ int dir_src(int k, int l) {
  switch (k) {
    case 0:  return l;
    case 1:  return ((l & 31) << 5) | (l >> 5);
    case 2:  return 1023 - l;
    default: { int lr = 1023 - l; return ((lr & 31) << 5) | (lr >> 5); }
  }
}

#define FMA16(a,b) do{ \
  acc[0][0] += (a).x*(b).x; acc[0][1] += (a).x*(b).y; acc[0][2] += (a).x*(b).z; acc[0][3] += (a).x*(b).w; \
  acc[1][0] += (a).y*(b).x; acc[1][1] += (a).y*(b).y; acc[1][2] += (a).y*(b).z; acc[1][3] += (a).y*(b).w; \
  acc[2][0] += (a).z*(b).x; acc[2][1] += (a).z*(b).y; acc[2][2] += (a).z*(b).z; acc[2][3] += (a).z*(b).w; \
  acc[3][0] += (a).w*(b).x; acc[3][1] += (a).w*(b).y; acc[3][2] += (a).w*(b).z; acc[3][3] += (a).w*(b).w; \
}while(0)

// ---------------- generic SGEMM: C[s] = A[s](MxK) * B(KxN), row-major ----------------
__global__ __launch_bounds__(256) void sgemm_nn(
    const float* __restrict__ A0, const float* __restrict__ A1,
    const float* __restrict__ B, float* __restrict__ C,
    int M, int N, int Kc, long long cstride)
{
  __shared__ float As[16][68];
  __shared__ float Bs[16][68];
  const int s = blockIdx.z;
  const float* A = s ? A1 : A0;
  float* Cp = C + (size_t)s * (size_t)cstride;
  const int n0 = blockIdx.x * 64, m0 = blockIdx.y * 64;
  const int tid = threadIdx.x, tx = tid & 15, ty = tid >> 4;
  float acc[4][4] = {};
  for (int k0 = 0; k0 < Kc; k0 += 16) {
#pragma unroll
    for (int i = 0; i < 4; ++i) {
      int idx = tid + i * 256;
      int r = idx >> 4, c = idx & 15;
      As[c][r] = A[(size_t)(m0 + r) * Kc + k0 + c];
    }
#pragma unroll
    for (int i = 0; i < 4; ++i) {
      int idx = tid + i * 256;
      int r = idx >> 6, c = idx & 63;
      int n = n0 + c;
      Bs[r][c] = (n < N) ? B[(size_t)(k0 + r) * N + n] : 0.f;
    }
    __syncthreads();
#pragma unroll
    for (int k = 0; k < 16; ++k) {
      float4 a = *(const float4*)&As[k][ty * 4];
      float4 b = *(const float4*)&Bs[k][tx * 4];
      FMA16(a, b);
    }
    __syncthreads();
  }
#pragma unroll
  for (int i = 0; i < 4; ++i) {
    int m = m0 + ty * 4 + i;
#pragma unroll
    for (int j = 0; j < 4; ++j) {
      int n = n0 + tx * 4 + j;
      if (n < N) Cp[(size_t)m * N + n] = acc[i][j];
    }
  }
}

// ---------------- depthwise 3x3 conv + bias + SiLU; writes xbcT[s][m][c] ----------------
__global__ __launch_bounds__(256) void k_conv(
    const float* __restrict__ xs_pre, const float* __restrict__ bc_pre,
    const float* __restrict__ wxs, const float* __restrict__ bxs,
    const float* __restrict__ wbc, const float* __restrict__ bbc,
    float* __restrict__ xbcT)
{
  const int m = blockIdx.x, s = blockIdx.y;
  const int h = m >> 5, w = m & 31;
  const float* xp = xs_pre + (size_t)s * LSEQ * DSSM;
  const float* bp = bc_pre + (size_t)s * LSEQ * CBCDT;
  for (int c = threadIdx.x; c < CTOT; c += 256) {
    const float* src; int stride; const float* wt; float bias;
    if (c < DSSM) { src = xp + c; stride = DSSM; wt = wxs + (size_t)c * 9; bias = bxs[c]; }
    else { int cb = c - DSSM; src = bp + cb; stride = CBCDT; wt = wbc + (size_t)cb * 9; bias = bbc[cb]; }
    float acc = bias;
#pragma unroll
    for (int dh = -1; dh <= 1; ++dh) {
      int h2 = h + dh; if (h2 < 0 || h2 > 31) continue;
#pragma unroll
      for (int dw = -1; dw <= 1; ++dw) {
        int w2 = w + dw; if (w2 < 0 || w2 > 31) continue;
        acc += src[(size_t)(h2 * 32 + w2) * stride] * wt[(dh + 1) * 3 + (dw + 1)];
      }
    }
    xbcT[((size_t)s * LSEQ + m) * CTOT + c] = siluf(acc);
  }
}

// ---------------- gather x*dt (bf16) into XhT[s][kh][p=64][l=1024] via LDS transpose ----------------
// grid (16, 32, 2), block 256
__global__ __launch_bounds__(256) void k_gather_x2(
    const float* __restrict__ xbcT, const float* __restrict__ dt_bias,
    ushort* __restrict__ XhT)
{
  __shared__ __align__(16) ushort T[64 * 72];   // [p][r] padded
  const int lt = blockIdx.x, kh = blockIdx.y, s = blockIdx.z;
  const int k = kh >> 3, hh = kh & 7;
  const int t = threadIdx.x;
  const int r = t >> 2, q = t & 3;
  const int l = lt * 64 + r;
  const int m = dir_src(k, l);
  const float* row = xbcT + ((size_t)s * LSEQ + m) * CTOT;
  float dtv = softplusf(row[768 + hh] + dt_bias[kh]);
  const float* xp = row + hh * 64 + q * 16;
#pragma unroll
  for (int i = 0; i < 16; ++i)
    T[(q * 16 + i) * 72 + r] = f2bf(xp[i] * dtv);
  __syncthreads();
  ushort* dst = XhT + (((size_t)s * HK + kh) * HD + r) * LSEQ + lt * 64 + q * 16;
  *(uint4*)dst       = *(const uint4*)&T[r * 72 + q * 16];
  *(uint4*)(dst + 8) = *(const uint4*)&T[r * 72 + q * 16 + 8];
}

// ---------------- gather B/C (bf16) + dA ----------------
// grid (1024, 4, 2), block 128
__global__ __launch_bounds__(128) void k_gather_bc(
    const float* __restrict__ xbcT, const float* __restrict__ dt_bias,
    const float* __restrict__ A_logs,
    ushort* __restrict__ Bbf, ushort* __restrict__ Cbf, float* __restrict__ dAbuf)
{
  const int l = blockIdx.x, k = blockIdx.y, s = blockIdx.z;
  const int n = threadIdx.x;
  const int m = dir_src(k, l);
  const float* row = xbcT + ((size_t)s * LSEQ + m) * CTOT;
  Bbf[((size_t)s * LSEQ + l) * NSTATE + k * 128 + n] = f2bf(row[512 + n]);
  Cbf[((size_t)s * LSEQ + l) * NSTATE + k * 128 + n] = f2bf(row[640 + n]);
  if (n < 8) {
    int kh = k * 8 + n;
    float dtv = softplusf(row[768 + n] + dt_bias[kh]);
    dAbuf[((size_t)s * HK + kh) * LSEQ + l] = dtv * (-expf(A_logs[kh]));
  }
}

// ---------------- transpose Bmat_bf [l][n] -> BmatT_bf [n][l] ----------------
// grid (16 lt, 8 nt, 2 s), block 256
__global__ __launch_bounds__(256) void k_transp(
    const ushort* __restrict__ Bbf, ushort* __restrict__ BT)
{
  __shared__ __align__(16) ushort T[64 * 72];
  const int lt = blockIdx.x, nt = blockIdx.y, s = blockIdx.z;
  const int t = threadIdx.x, r = t >> 2, q = t & 3;
  const ushort* src = Bbf + ((size_t)s * LSEQ + lt * 64 + r) * NSTATE + nt * 64 + q * 16;
  ushort tmp[16];
  *(uint4*)tmp       = *(const uint4*)src;
  *(uint4*)(tmp + 8) = *(const uint4*)(src + 8);
#pragma unroll
  for (int i = 0; i < 16; ++i) T[(q * 16 + i) * 72 + r] = tmp[i];
  __syncthreads();
  ushort* dst = BT + ((size_t)s * NSTATE + nt * 64 + r) * LSEQ + lt * 64 + q * 16;
  *(uint4*)dst       = *(const uint4*)&T[r * 72 + q * 16];
  *(uint4*)(dst + 8) = *(const uint4*)&T[r * 72 + q * 16 + 8];
}

// ---------------- inclusive cumsum of dA within each chunk ----------------
__global__ __launch_bounds__(256) void k_cumsum(float* __restrict__ dAbuf)
{
  __shared__ float buf[CHUNKSZ];
  const int z = blockIdx.x, kh = blockIdx.y, s = blockIdx.z, t = threadIdx.x;
  float* p = dAbuf + ((size_t)s * HK + kh) * LSEQ + z * CHUNKSZ;
  buf[t] = p[t];
  __syncthreads();
  for (int off = 1; off < CHUNKSZ; off <<= 1) {
    float add = (t >= off) ? buf[t - off] : 0.f;
    __syncthreads();
    buf[t] += add;
    __syncthreads();
  }
  p[t] = buf[t];
}

// ---------------- CB[s][z] = Cr * Br^T (MFMA) ----------------
// grid (4 jt, 4 it, 8 sz), block 256
__global__ __launch_bounds__(256) void k_cb_mfma(
    const ushort* __restrict__ Cbf, const ushort* __restrict__ Bbf,
    float* __restrict__ CBb)
{
  __shared__ __align__(16) ushort As[64 * 40];
  __shared__ __align__(16) ushort Bs[64 * 40];
  const int jt = blockIdx.x, it = blockIdx.y, sz = blockIdx.z, s = sz >> 2, z = sz & 3;
  const int t = threadIdx.x, lane = t & 63, wv = t >> 6;
  const int lrow = lane & 15, lk = (lane >> 4) * 8;
  const ushort* Ap = Cbf + ((size_t)s * LSEQ + z * CHUNKSZ + it * 64) * NSTATE;
  const ushort* Bp = Bbf + ((size_t)s * LSEQ + z * CHUNKSZ + jt * 64) * NSTATE;
  f32x4 acc[4] = {};
  const int r = t >> 2, c0 = (t & 3) * 8;
  for (int kt = 0; kt < 16; ++kt) {
    *(uint4*)&As[r * 40 + c0] = *(const uint4*)(Ap + (size_t)r * NSTATE + kt * 32 + c0);
    *(uint4*)&Bs[r * 40 + c0] = *(const uint4*)(Bp + (size_t)r * NSTATE + kt * 32 + c0);
    __syncthreads();
    short8 a = *(const short8*)&As[(16 * wv + lrow) * 40 + lk];
#pragma unroll
    for (int fj = 0; fj < 4; ++fj) {
      short8 b = *(const short8*)&Bs[(16 * fj + lrow) * 40 + lk];
      acc[fj] = __builtin_amdgcn_mfma_f32_16x16x32_bf16(a, b, acc[fj], 0, 0, 0);
    }
    __syncthreads();
  }
  float* Cp = CBb + (size_t)sz * CHUNKSZ * CHUNKSZ;
  const int row0 = it * 64 + 16 * wv + (lane >> 4) * 4;
#pragma unroll
  for (int fj = 0; fj < 4; ++fj) {
    int col = jt * 64 + 16 * fj + lrow;
#pragma unroll
    for (int rr = 0; rr < 4; ++rr)
      Cp[(size_t)(row0 + rr) * CHUNKSZ + col] = acc[fj][rr];
  }
}

// ---------------- statesT[s,z,kh][n][p] = sum_c B[c,n]*decay[c]*xdt[c,p]  (MFMA, bf16 out) ----------------
// grid (2 nh, 32 kh, 8 sz), block 256
__global__ __launch_bounds__(256) void k_states_mfma(
    const ushort* __restrict__ BT, const ushort* __restrict__ XhT,
    const float* __restrict__ dAcs, ushort* __restrict__ statesT)
{
  __shared__ __align__(16) ushort As[256 * 40];
  __shared__ __align__(16) ushort Bs[64 * 40];
  __shared__ float decay[CHUNKSZ];
  const int nh = blockIdx.x, kh = blockIdx.y, sz = blockIdx.z, s = sz >> 2, z = sz & 3;
  const int t = threadIdx.x, lane = t & 63, wv = t >> 6;
  const int lrow = lane & 15, lk = (lane >> 4) * 8;
  const float* dAp = dAcs + ((size_t)s * HK + kh) * LSEQ + z * CHUNKSZ;
  decay[t] = __expf(dAp[CHUNKSZ - 1] - dAp[t]);
  __syncthreads();
  f32x4 acc[4][4] = {};
  const ushort* Ap = BT + ((size_t)s * NSTATE + nh * 256) * LSEQ + z * CHUNKSZ;
  const ushort* Xp = XhT + ((size_t)s * HK + kh) * HD * LSEQ + z * CHUNKSZ;
  const int rb = t >> 2, c0 = (t & 3) * 8;
  for (int kt = 0; kt < 8; ++kt) {
#pragma unroll
    for (int q = 0; q < 4; ++q) {
      int rr = rb + 64 * q;
      *(uint4*)&As[rr * 40 + c0] = *(const uint4*)(Ap + (size_t)rr * LSEQ + kt * 32 + c0);
    }
    {
      const ushort* src = Xp + (size_t)rb * LSEQ + kt * 32 + c0;
      uint4 raw = *(const uint4*)src;
      ushort tmp[8]; *(uint4*)tmp = raw;
#pragma unroll
      for (int i2 = 0; i2 < 4; ++i2) {
        int c = kt * 32 + c0 + 2 * i2;
        unsigned wpk = (unsigned)f2bf(bf2f(tmp[2 * i2]) * decay[c]) |
                       ((unsigned)f2bf(bf2f(tmp[2 * i2 + 1]) * decay[c + 1]) << 16);
        *(unsigned*)&Bs[rb * 40 + c0 + 2 * i2] = wpk;
      }
    }
    __syncthreads();
    short8 a[4], b[4];
#pragma unroll
    for (int f = 0; f < 4; ++f) {
      a[f] = *(const short8*)&As[(64 * wv + 16 * f + lrow) * 40 + lk];
      b[f] = *(const short8*)&Bs[(16 * f + lrow) * 40 + lk];
    }
#pragma unroll
    for (int fi = 0; fi < 4; ++fi)
#pragma unroll
      for (int fj = 0; fj < 4; ++fj)
        acc[fi][fj] = __builtin_amdgcn_mfma_f32_16x16x32_bf16(a[fi], b[fj], acc[fi][fj], 0, 0, 0);
    __syncthreads();
  }
  ushort* Sp = statesT + (((size_t)sz * HK + kh) * NSTATE + nh * 256) * HD;
#pragma unroll
  for (int fi = 0; fi < 4; ++fi) {
    int row0 = 64 * wv + 16 * fi + (lane >> 4) * 4;
#pragma unroll
    for (int fj = 0; fj < 4; ++fj) {
      int col = 16 * fj + lrow;
#pragma unroll
      for (int rr = 0; rr < 4; ++rr)
        Sp[(size_t)(row0 + rr) * HD + col] = f2bf(acc[fi][fj][rr]);
    }
  }
}

// ---------------- inter-chunk scan: statesT (bf16) -> prevP[p][n] (bf16) ----------------
// grid (8 nt, 32 kh, 2 s), block 256
__global__ __launch_bounds__(256) void k_scan2(
    const ushort* __restrict__ statesT, const float* __restrict__ dAcs,
    ushort* __restrict__ prevP)
{
  __shared__ __align__(16) ushort T[64 * 72];
  const int nt = blockIdx.x, kh = blockIdx.y, s = blockIdx.z;
  const int t = threadIdx.x, rn = t >> 2, p0 = (t & 3) * 16;
  const float* dA = dAcs + ((size_t)s * HK + kh) * LSEQ;
  float carry[16];
#pragma unroll
  for (int i = 0; i < 16; ++i) carry[i] = 0.f;
  for (int z = 0; z < NC; ++z) {
    int sz = s * 4 + z;
    const ushort* Sp = statesT + (((size_t)sz * HK + kh) * NSTATE + nt * 64 + rn) * HD + p0;
    ushort raw[16];
    *(uint4*)raw       = *(const uint4*)Sp;
    *(uint4*)(raw + 8) = *(const uint4*)(Sp + 8);
#pragma unroll
    for (int i = 0; i < 16; ++i) T[(p0 + i) * 72 + rn] = f2bf(carry[i]);
    float cdec = __expf(dA[z * CHUNKSZ + CHUNKSZ - 1]);
#pragma unroll
    for (int i = 0; i < 16; ++i) carry[i] = carry[i] * cdec + bf2f(raw[i]);
    __syncthreads();
    ushort* dst = prevP + (((size_t)sz * HK + kh) * HD + rn) * NSTATE + nt * 64 + p0;
    *(uint4*)dst       = *(const uint4*)&T[rn * 72 + p0];
    *(uint4*)(dst + 8) = *(const uint4*)&T[rn * 72 + p0 + 8];
    __syncthreads();
  }
}

// ---------------- Y = Ydiag + Yoff (MFMA) ----------------
// grid (32 kh, 8 sz), block 256
__global__ __launch_bounds__(256) void k_y_mfma(
    const float* __restrict__ CBb, const ushort* __restrict__ XhT,
    const ushort* __restrict__ Cbf, const ushort* __restrict__ prevP,
    const float* __restrict__ dAcs, float* __restrict__ Y)
{
  __shared__ __align__(16) ushort As[256 * 40];
  __shared__ __align__(16) ushort Bs[64 * 40];
  __shared__ float seg[CHUNKSZ];
  __shared__ float eA[CHUNKSZ];
  const int kh = blockIdx.x, sz = blockIdx.y, s = sz >> 2, z = sz & 3;
  const int t = threadIdx.x, lane = t & 63, wv = t >> 6;
  const int lrow = lane & 15, lk = (lane >> 4) * 8;

  const float* dAp = dAcs + ((size_t)s * HK + kh) * LSEQ + z * CHUNKSZ;
  {
    float v = dAp[t];
    seg[t] = v;
    eA[t] = __expf(v);
  }
  __syncthreads();

  f32x4 acc[4][4] = {};
  const float* CBp = CBb + (size_t)sz * CHUNKSZ * CHUNKSZ;
  const ushort* Xp = XhT + ((size_t)s * HK + kh) * HD * LSEQ + z * CHUNKSZ;

  // phase 1: Ydiag, A = CB .* exp(seg_i - seg_j) masked, B = xdt
  for (int kt = 0; kt < 8; ++kt) {
    {
      const int r = t;
      const int jbase = kt * 32;
      if (jbase <= r) {
        float si = seg[r];
        const float* cbrow = CBp + (size_t)r * CHUNKSZ + jbase;
#pragma unroll
        for (int c = 0; c < 32; c += 2) {
          int j0 = jbase + c, j1 = j0 + 1;
          float v0 = (j0 <= r) ? cbrow[c]     * __expf(si - seg[j0]) : 0.f;
          float v1 = (j1 <= r) ? cbrow[c + 1] * __expf(si - seg[j1]) : 0.f;
          *(unsigned*)&As[r * 40 + c] = (unsigned)f2bf(v0) | ((unsigned)f2bf(v1) << 16);
        }
      } else {
#pragma unroll
        for (int c = 0; c < 32; c += 2) *(unsigned*)&As[r * 40 + c] = 0u;
      }
    }
    {
      int p = t >> 2, c0 = (t & 3) * 8;
      *(uint4*)&Bs[p * 40 + c0] = *(const uint4*)(Xp + (size_t)p * LSEQ + kt * 32 + c0);
    }
    __syncthreads();
    if (kt <= 2 * wv + 1) {
      short8 a[4], b[4];
#pragma unroll
      for (int f = 0; f < 4; ++f) {
        a[f] = *(const short8*)&As[(64 * wv + 16 * f + lrow) * 40 + lk];
        b[f] = *(const short8*)&Bs[(16 * f + lrow) * 40 + lk];
      }
#pragma unroll
      for (int fi = 0; fi < 4; ++fi)
#pragma unroll
        for (int fj = 0; fj < 4; ++fj)
          acc[fi][fj] = __builtin_amdgcn_mfma_f32_16x16x32_bf16(a[fi], b[fj], acc[fi][fj], 0, 0, 0);
    }
    __syncthreads();
  }

  // phase 2: Yoff, A = C .* eA[i], B = prevP
  const ushort* Cp = Cbf + ((size_t)s * LSEQ + z * CHUNKSZ) * NSTATE;
  const ushort* Pp = prevP + ((size_t)sz * HK + kh) * HD * NSTATE;
  for (int nt = 0; nt < 16; ++nt) {
    {
      const int rb = t >> 2, c0 = (t & 3) * 8;
#pragma unroll
      for (int q = 0; q < 4; ++q) {
        int r = rb + 64 * q;
        const ushort* src = Cp + (size_t)r * NSTATE + nt * 32 + c0;
        float e = eA[r];
        uint4 raw = *(const uint4*)src;
        ushort tmp[8]; *(uint4*)tmp = raw;
#pragma unroll
        for (int i2 = 0; i2 < 4; ++i2) {
          unsigned wpk = (unsigned)f2bf(bf2f(tmp[2 * i2]) * e) |
                         ((unsigned)f2bf(bf2f(tmp[2 * i2 + 1]) * e) << 16);
          *(unsigned*)&As[r * 40 + c0 + 2 * i2] = wpk;
        }
      }
      *(uint4*)&Bs[rb * 40 + c0] = *(const uint4*)(Pp + (size_t)rb * NSTATE + nt * 32 + c0);
    }
    __syncthreads();
    {
      short8 b[4];
#pragma unroll
      for (int f = 0; f < 4; ++f) b[f] = *(const short8*)&Bs[(16 * f + lrow) * 40 + lk];
#pragma unroll
      for (int fi = 0; fi < 4; ++fi) {
        short8 a = *(const short8*)&As[(64 * wv + 16 * fi + lrow) * 40 + lk];
#pragma unroll
        for (int fj = 0; fj < 4; ++fj)
          acc[fi][fj] = __builtin_amdgcn_mfma_f32_16x16x32_bf16(a, b[fj], acc[fi][fj], 0, 0, 0);
      }
    }
    __syncthreads();
  }

  float* Yp = Y + (((size_t)s * LSEQ + z * CHUNKSZ) * HK + kh) * HD;
#pragma unroll
  for (int fi = 0; fi < 4; ++fi) {
    int row0 = 64 * wv + 16 * fi + (lane >> 4) * 4;
#pragma unroll
    for (int fj = 0; fj < 4; ++fj) {
      int col = 16 * fj + lrow;
#pragma unroll
      for (int rr = 0; rr < 4; ++rr)
        Yp[(size_t)(row0 + rr) * (HK * HD) + col] = acc[fi][fj][rr];
    }
  }
}

// ---------------- combine 4 directions + D*x + gated RMSNorm + MLP half ----------------
__global__ __launch_bounds__(256) void k_combine(
    const float* __restrict__ Y, const float* __restrict__ xbcT,
    const float* __restrict__ skip, const float* __restrict__ Ds,
    const float* __restrict__ normw, float* __restrict__ out768)
{
  const int m = blockIdx.x, s = blockIdx.y, t = threadIdx.x;
  const int h = m >> 5, w = m & 31;
  const int l0 = m, l1 = (w << 5) | h, l2 = 1023 - m, l3 = 1023 - ((w << 5) | h);
  const float* Yb = Y + (size_t)s * LSEQ * (HK * HD);
  const float* xrow = xbcT + ((size_t)s * LSEQ + m) * CTOT;
  const float* srow = skip + ((size_t)s * LSEQ + m) * 1024;

  float g[2];
  float ss = 0.f;
#pragma unroll
  for (int q = 0; q < 2; ++q) {
    int d = t + q * 256;
    int hh = d >> 6, p = d & 63;
    float dsum = Ds[hh] + Ds[hh + 8] + Ds[hh + 16] + Ds[hh + 24];
    float val = Yb[((size_t)l0 * HK + hh) * HD + p]
              + Yb[((size_t)l1 * HK + 8 + hh) * HD + p]
              + Yb[((size_t)l2 * HK + 16 + hh) * HD + p]
              + Yb[((size_t)l3 * HK + 24 + hh) * HD + p]
              + xrow[d] * dsum;
    float zv = srow[512 + d];
    g[q] = val * siluf(zv);
    ss += g[q] * g[q];
  }
  for (int off = 32; off > 0; off >>= 1) ss += __shfl_down(ss, off, 64);
  __shared__ float red[4];
  if ((t & 63) == 0) red[t >> 6] = ss;
  __syncthreads();
  float total = red[0] + red[1] + red[2] + red[3];
  float scale = rsqrtf(total * (1.f / 512.f) + 1e-5f);

  float* orow = out768 + ((size_t)s * LSEQ + m) * 768;
#pragma unroll
  for (int q = 0; q < 2; ++q) {
    int d = t + q * 256;
    orow[256 + d] = g[q] * scale * normw[d];
  }
  float z0 = srow[t], x0 = srow[256 + t];
  orow[t] = siluf(z0) * x0;
}

// ---------------- workspace layout (float units; bf16 buffers use 2 ushorts per float slot) ----------------
constexpr size_t OFF_SKIP = 0;                              // 2*1024*1024 f32
constexpr size_t OFF_XBCT = 2097152;                        // 2*1024*776 f32
constexpr size_t OFF_XHT  = OFF_XBCT + 1589248;             // 2*32*64*1024 bf16 = 2097152 f-slots
constexpr size_t OFF_BBF  = OFF_XHT + 2097152;              // 2*1024*512 bf16 = 524288
constexpr size_t OFF_CBF  = OFF_BBF + 524288;               // 524288
constexpr size_t OFF_BTBF = OFF_CBF + 524288;               // 524288
constexpr size_t OFF_DA   = OFF_BTBF + 524288;              // 65536 f32
constexpr size_t OFF_CB   = OFF_DA + 65536;                 // 8*256*256 f32 = 524288
constexpr size_t OFF_ST   = OFF_CB + 524288;                // 8*32*512*64 bf16 = 4194304 f-slots
constexpr size_t OFF_PREV = OFF_ST + 4194304;               // same bf16 size = 4194304
constexpr size_t OFF_Y    = OFF_PREV + 4194304;             // 2*1024*2048 f32 = 4194304
constexpr size_t OFF_O768 = OFF_Y + 4194304;                // 2*1024*768 f32 = 1572864
// xs_pre/bc_pre (gemm->conv) overlay statesT region (k_states->k_scan) - disjoint lifetimes
constexpr size_t OFF_XSP  = OFF_ST;
constexpr size_t OFF_BCP  = OFF_XSP + 1048576;

extern "C" void kernel_launch(void* const* d_in, const int* in_sizes, int n_in,
                              void* d_out, int out_size, void* d_ws, size_t ws_size,
                              hipStream_t stream)
{
  const float* u1     = (const float*)d_in[0];
  const float* u2     = (const float*)d_in[1];
  const float* u2c1   = (const float*)d_in[2];
  const float* u1c2   = (const float*)d_in[3];
  const float* W_skip = (const float*)d_in[4];
  const float* W_xs   = (const float*)d_in[5];
  const float* W_bcdt = (const float*)d_in[6];
  const float* cxw    = (const float*)d_in[7];
  const float* cxb    = (const float*)d_in[8];
  const float* cbw    = (const float*)d_in[9];
  const float* cbb    = (const float*)d_in[10];
  const float* Ds     = (const float*)d_in[11];
  const float* normw  = (const float*)d_in[12];
  const float* W_out  = (const float*)d_in[13];
  const float* dt_b   = (const float*)d_in[14];
  const float* A_logs = (const float*)d_in[15];
  float* out = (float*)d_out;
  float* ws  = (float*)d_ws;

  float*  skip    = ws + OFF_SKIP;
  float*  xbcT    = ws + OFF_XBCT;
  ushort* XhT     = (ushort*)(ws + OFF_XHT);
  ushort* Bbf     = (ushort*)(ws + OFF_BBF);
  ushort* Cbf     = (ushort*)(ws + OFF_CBF);
  ushort* BTbf    = (ushort*)(ws + OFF_BTBF);
  float*  dAcs    = ws + OFF_DA;
  float*  CBb     = ws + OFF_CB;
  ushort* statesT = (ushort*)(ws + OFF_ST);
  ushort* prevP   = (ushort*)(ws + OFF_PREV);
  float*  Ybuf    = ws + OFF_Y;
  float*  o768    = ws + OFF_O768;
  float*  xs_pre  = ws + OFF_XSP;
  float*  bc_pre  = ws + OFF_BCP;

  sgemm_nn<<<dim3(16, 16, 2), 256, 0, stream>>>(u1, u2, W_skip, skip, LSEQ, 1024, DM, (long long)LSEQ * 1024);
  sgemm_nn<<<dim3(8, 16, 2), 256, 0, stream>>>(u1, u2, W_xs, xs_pre, LSEQ, DSSM, DM, (long long)LSEQ * DSSM);
  sgemm_nn<<<dim3(5, 16, 2), 256, 0, stream>>>(u2c1, u1c2, W_bcdt, bc_pre, LSEQ, CBCDT, DM, (long long)LSEQ * CBCDT);
  k_conv<<<dim3(1024, 2), 256, 0, stream>>>(xs_pre, bc_pre, cxw, cxb, cbw, cbb, xbcT);
  k_gather_x2<<<dim3(16, 32, 2), 256, 0, stream>>>(xbcT, dt_b, XhT);
  k_gather_bc<<<dim3(1024, 4, 2), 128, 0, stream>>>(xbcT, dt_b, A_logs, Bbf, Cbf, dAcs);
  k_transp<<<dim3(16, 8, 2), 256, 0, stream>>>(Bbf, BTbf);
  k_cumsum<<<dim3(4, 32, 2), 256, 0, stream>>>(dAcs);
  k_cb_mfma<<<dim3(4, 4, 8), 256, 0, stream>>>(Cbf, Bbf, CBb);
  k_states_mfma<<<dim3(2, 32, 8), 256, 0, stream>>>(BTbf, XhT, dAcs, statesT);
  k_scan2<<<dim3(8, 32, 2), 256, 0, stream>>>(statesT, dAcs, prevP);
  k_y_mfma<<<dim3(32, 8), 256, 0, stream>>>(CBb, XhT, Cbf, prevP, dAcs, Ybuf);
  k_combine<<<dim3(1024, 2), 256, 0, stream>>>(Ybuf, xbcT, skip, Ds, normw, o768);
  sgemm_nn<<<dim3(6, 16, 2), 256, 0, stream>>>(o768, o768 + (size_t)LSEQ * 768, W_out, out, LSEQ, DM, 768, (long long)LSEQ * DM);
}

// Round 3
// 197.750 us; speedup vs baseline: 2.8467x; 1.5270x over previous
//
#include <hip/hip_runtime.h>
#include <hip/hip_bf16.h>
#include <cstddef>

// ---------------- problem constants ----------------
#define LSEQ   1024
#define DM     384
#define DSSM   512
#define NSTATE 512      // K * D_STATE (shared across heads in the reference einsums)
#define HK     32       // K * NHEADS combined heads
#define HD     64       // head dim
#define CHUNKSZ 256
#define NC     4
#define CBCDT  264
#define CTOT   776      // 512 + 264
#define DMLP   256

typedef __attribute__((ext_vector_type(8))) short short8;
typedef __attribute__((ext_vector_type(4))) float f32x4;

__device__ __forceinline__ float siluf(float x)    { return x / (1.f + expf(-x)); }
__device__ __forceinline__ float softplusf(float x){ return fmaxf(x, 0.f) + log1pf(expf(-fabsf(x))); }

__device__ __forceinline__ ushort f2bf(float f) {
  union { float f; unsigned u; } v; v.f = f;
  unsigned r = v.u + 0x7fffu + ((v.u >> 16) & 1u);
  return (ushort)(r >> 16);
}
__device__ __forceinline__ float bf2f(ushort h) {
  union { unsigned u; float f; } v; v.u = ((unsigned)h) << 16;
  return v.f;
}

// direction k, sequence pos l -> row-major spatial index m (32x32 grid)
__device__ __forceinline__ int dir_src(int k, int l) {
  switch (k) {
    case 0:  return l;
    case 1:  return ((l & 31) << 5) | (l >> 5);
    case 2:  return 1023 - l;
    default: { int lr = 1023 - l; return ((lr & 31) << 5) | (lr >> 5); }
  }
}

// ---------------- cast u / uc (f32) -> bf16 [2048][384] ----------------
// grid (768, 2), block 256; 4 elems/thread
__global__ __launch_bounds__(256) void k_cast_u(
    const float* __restrict__ u1, const float* __restrict__ u2,
    const float* __restrict__ uc1, const float* __restrict__ uc2,
    ushort* __restrict__ Ubf, ushort* __restrict__ UCbf)
{
  const int i = (blockIdx.x * 256 + threadIdx.x) * 4;   // [0, 786432)
  const float* s0 = blockIdx.y ? uc1 : u1;
  const float* s1 = blockIdx.y ? uc2 : u2;
  ushort* dst = blockIdx.y ? UCbf : Ubf;
  float4 v = (i < 393216) ? *(const float4*)(s0 + i) : *(const float4*)(s1 + i - 393216);
  ushort o[4] = { f2bf(v.x), f2bf(v.y), f2bf(v.z), f2bf(v.w) };
  *(uint2*)(dst + i) = *(const uint2*)o;
}

// ---------------- transpose-cast weight: src f32 [K][N] -> dst bf16 [N][ldd] ----------------
// grid (ceil(N/64), K/64), block 256
__global__ __launch_bounds__(256) void k_wtransp(
    const float* __restrict__ src, ushort* __restrict__ dst, int N, int ldd)
{
  __shared__ __align__(16) ushort T[64 * 72];
  const int n0 = blockIdx.x * 64, k0 = blockIdx.y * 64;
  const int t = threadIdx.x, rk = t >> 2, q = t & 3;
  const int k = k0 + rk;
  const float* srow = src + (size_t)k * N + n0 + q * 16;
#pragma unroll
  for (int i = 0; i < 16; ++i) {
    int n = n0 + q * 16 + i;
    T[(q * 16 + i) * 72 + rk] = (n < N) ? f2bf(srow[i]) : (ushort)0;
  }
  __syncthreads();
  int n = n0 + rk;
  if (n < N) {
    ushort* d = dst + (size_t)n * ldd + k0 + q * 16;
    *(uint4*)d       = *(const uint4*)&T[rk * 72 + q * 16];
    *(uint4*)(d + 8) = *(const uint4*)&T[rk * 72 + q * 16 + 8];
  }
}

// ---------------- bf16 MFMA GEMM: C[M][N] f32 = A[M][K] * BT[N][K] ----------------
// grid (ceil(N/128), M/128), block 256 (4 waves 2x2). K multiple of 32, M multiple of 128.
__global__ __launch_bounds__(256) void gemm_bf16(
    const ushort* __restrict__ A, const ushort* __restrict__ BT,
    float* __restrict__ C, int M, int N, int K)
{
  __shared__ __align__(16) ushort As[128 * 40];
  __shared__ __align__(16) ushort Bs[128 * 40];
  const int n0 = blockIdx.x * 128, m0 = blockIdx.y * 128;
  const int t = threadIdx.x, lane = t & 63, wv = t >> 6;
  const int wm = wv & 1, wn = wv >> 1;
  const int lrow = lane & 15, lk8 = (lane >> 4) * 8;
  const int rowL = t >> 1, cL = (t & 1) * 16;
  f32x4 acc[4][4] = {};
  for (int k0 = 0; k0 < K; k0 += 32) {
    {
      const ushort* src = A + (size_t)(m0 + rowL) * K + k0 + cL;
      *(uint4*)&As[rowL * 40 + cL]     = *(const uint4*)src;
      *(uint4*)&As[rowL * 40 + cL + 8] = *(const uint4*)(src + 8);
    }
    {
      int n = n0 + rowL;
      if (n < N) {
        const ushort* src = BT + (size_t)n * K + k0 + cL;
        *(uint4*)&Bs[rowL * 40 + cL]     = *(const uint4*)src;
        *(uint4*)&Bs[rowL * 40 + cL + 8] = *(const uint4*)(src + 8);
      } else {
        uint4 z = {0, 0, 0, 0};
        *(uint4*)&Bs[rowL * 40 + cL] = z;
        *(uint4*)&Bs[rowL * 40 + cL + 8] = z;
      }
    }
    __syncthreads();
    short8 a[4], b[4];
#pragma unroll
    for (int f = 0; f < 4; ++f) {
      a[f] = *(const short8*)&As[(wm * 64 + 16 * f + lrow) * 40 + lk8];
      b[f] = *(const short8*)&Bs[(wn * 64 + 16 * f + lrow) * 40 + lk8];
    }
#pragma unroll
    for (int fi = 0; fi < 4; ++fi)
#pragma unroll
      for (int fj = 0; fj < 4; ++fj)
        acc[fi][fj] = __builtin_amdgcn_mfma_f32_16x16x32_bf16(a[fi], b[fj], acc[fi][fj], 0, 0, 0);
    __syncthreads();
  }
#pragma unroll
  for (int fi = 0; fi < 4; ++fi) {
    int row0 = m0 + wm * 64 + 16 * fi + (lane >> 4) * 4;
#pragma unroll
    for (int fj = 0; fj < 4; ++fj) {
      int col = n0 + wn * 64 + 16 * fj + lrow;
      if (col < N)
#pragma unroll
        for (int rr = 0; rr < 4; ++rr)
          C[(size_t)(row0 + rr) * N + col] = acc[fi][fj][rr];
    }
  }
}

// ---------------- depthwise 3x3 conv + bias + SiLU; writes xbcT[s][m][c] ----------------
__global__ __launch_bounds__(256) void k_conv(
    const float* __restrict__ skipxs, const float* __restrict__ bc_pre,
    const float* __restrict__ wxs, const float* __restrict__ bxs,
    const float* __restrict__ wbc, const float* __restrict__ bbc,
    float* __restrict__ xbcT)
{
  const int m = blockIdx.x, s = blockIdx.y;
  const int h = m >> 5, w = m & 31;
  const float* xp = skipxs + (size_t)s * LSEQ * 1536 + 1024;   // xs part, stride 1536
  const float* bp = bc_pre + (size_t)s * LSEQ * CBCDT;
  for (int c = threadIdx.x; c < CTOT; c += 256) {
    const float* src; int stride; const float* wt; float bias;
    if (c < DSSM) { src = xp + c; stride = 1536; wt = wxs + (size_t)c * 9; bias = bxs[c]; }
    else { int cb = c - DSSM; src = bp + cb; stride = CBCDT; wt = wbc + (size_t)cb * 9; bias = bbc[cb]; }
    float acc = bias;
#pragma unroll
    for (int dh = -1; dh <= 1; ++dh) {
      int h2 = h + dh; if (h2 < 0 || h2 > 31) continue;
#pragma unroll
      for (int dw = -1; dw <= 1; ++dw) {
        int w2 = w + dw; if (w2 < 0 || w2 > 31) continue;
        acc += src[(size_t)(h2 * 32 + w2) * stride] * wt[(dh + 1) * 3 + (dw + 1)];
      }
    }
    xbcT[((size_t)s * LSEQ + m) * CTOT + c] = siluf(acc);
  }
}

// ---------------- gather x*dt (bf16) into XhT[s][kh][p=64][l=1024] via LDS transpose ----------------
__global__ __launch_bounds__(256) void k_gather_x2(
    const float* __restrict__ xbcT, const float* __restrict__ dt_bias,
    ushort* __restrict__ XhT)
{
  __shared__ __align__(16) ushort T[64 * 72];
  const int lt = blockIdx.x, kh = blockIdx.y, s = blockIdx.z;
  const int k = kh >> 3, hh = kh & 7;
  const int t = threadIdx.x;
  const int r = t >> 2, q = t & 3;
  const int l = lt * 64 + r;
  const int m = dir_src(k, l);
  const float* row = xbcT + ((size_t)s * LSEQ + m) * CTOT;
  float dtv = softplusf(row[768 + hh] + dt_bias[kh]);
  const float* xp = row + hh * 64 + q * 16;
#pragma unroll
  for (int i = 0; i < 16; ++i)
    T[(q * 16 + i) * 72 + r] = f2bf(xp[i] * dtv);
  __syncthreads();
  ushort* dst = XhT + (((size_t)s * HK + kh) * HD + r) * LSEQ + lt * 64 + q * 16;
  *(uint4*)dst       = *(const uint4*)&T[r * 72 + q * 16];
  *(uint4*)(dst + 8) = *(const uint4*)&T[r * 72 + q * 16 + 8];
}

// ---------------- gather B/C (bf16) + dA ----------------
__global__ __launch_bounds__(128) void k_gather_bc(
    const float* __restrict__ xbcT, const float* __restrict__ dt_bias,
    const float* __restrict__ A_logs,
    ushort* __restrict__ Bbf, ushort* __restrict__ Cbf, float* __restrict__ dAbuf)
{
  const int l = blockIdx.x, k = blockIdx.y, s = blockIdx.z;
  const int n = threadIdx.x;
  const int m = dir_src(k, l);
  const float* row = xbcT + ((size_t)s * LSEQ + m) * CTOT;
  Bbf[((size_t)s * LSEQ + l) * NSTATE + k * 128 + n] = f2bf(row[512 + n]);
  Cbf[((size_t)s * LSEQ + l) * NSTATE + k * 128 + n] = f2bf(row[640 + n]);
  if (n < 8) {
    int kh = k * 8 + n;
    float dtv = softplusf(row[768 + n] + dt_bias[kh]);
    dAbuf[((size_t)s * HK + kh) * LSEQ + l] = dtv * (-expf(A_logs[kh]));
  }
}

// ---------------- transpose Bmat_bf [l][n] -> BmatT_bf [n][l] ----------------
__global__ __launch_bounds__(256) void k_transp(
    const ushort* __restrict__ Bbf, ushort* __restrict__ BT)
{
  __shared__ __align__(16) ushort T[64 * 72];
  const int lt = blockIdx.x, nt = blockIdx.y, s = blockIdx.z;
  const int t = threadIdx.x, r = t >> 2, q = t & 3;
  const ushort* src = Bbf + ((size_t)s * LSEQ + lt * 64 + r) * NSTATE + nt * 64 + q * 16;
  ushort tmp[16];
  *(uint4*)tmp       = *(const uint4*)src;
  *(uint4*)(tmp + 8) = *(const uint4*)(src + 8);
#pragma unroll
  for (int i = 0; i < 16; ++i) T[(q * 16 + i) * 72 + r] = tmp[i];
  __syncthreads();
  ushort* dst = BT + ((size_t)s * NSTATE + nt * 64 + r) * LSEQ + lt * 64 + q * 16;
  *(uint4*)dst       = *(const uint4*)&T[r * 72 + q * 16];
  *(uint4*)(dst + 8) = *(const uint4*)&T[r * 72 + q * 16 + 8];
}

// ---------------- inclusive cumsum of dA within each chunk ----------------
__global__ __launch_bounds__(256) void k_cumsum(float* __restrict__ dAbuf)
{
  __shared__ float buf[CHUNKSZ];
  const int z = blockIdx.x, kh = blockIdx.y, s = blockIdx.z, t = threadIdx.x;
  float* p = dAbuf + ((size_t)s * HK + kh) * LSEQ + z * CHUNKSZ;
  buf[t] = p[t];
  __syncthreads();
  for (int off = 1; off < CHUNKSZ; off <<= 1) {
    float add = (t >= off) ? buf[t - off] : 0.f;
    __syncthreads();
    buf[t] += add;
    __syncthreads();
  }
  p[t] = buf[t];
}

// ---------------- CB[s][z] = Cr * Br^T (MFMA) ----------------
__global__ __launch_bounds__(256) void k_cb_mfma(
    const ushort* __restrict__ Cbf, const ushort* __restrict__ Bbf,
    float* __restrict__ CBb)
{
  __shared__ __align__(16) ushort As[64 * 40];
  __shared__ __align__(16) ushort Bs[64 * 40];
  const int jt = blockIdx.x, it = blockIdx.y, sz = blockIdx.z, s = sz >> 2, z = sz & 3;
  const int t = threadIdx.x, lane = t & 63, wv = t >> 6;
  const int lrow = lane & 15, lk = (lane >> 4) * 8;
  const ushort* Ap = Cbf + ((size_t)s * LSEQ + z * CHUNKSZ + it * 64) * NSTATE;
  const ushort* Bp = Bbf + ((size_t)s * LSEQ + z * CHUNKSZ + jt * 64) * NSTATE;
  f32x4 acc[4] = {};
  const int r = t >> 2, c0 = (t & 3) * 8;
  for (int kt = 0; kt < 16; ++kt) {
    *(uint4*)&As[r * 40 + c0] = *(const uint4*)(Ap + (size_t)r * NSTATE + kt * 32 + c0);
    *(uint4*)&Bs[r * 40 + c0] = *(const uint4*)(Bp + (size_t)r * NSTATE + kt * 32 + c0);
    __syncthreads();
    short8 a = *(const short8*)&As[(16 * wv + lrow) * 40 + lk];
#pragma unroll
    for (int fj = 0; fj < 4; ++fj) {
      short8 b = *(const short8*)&Bs[(16 * fj + lrow) * 40 + lk];
      acc[fj] = __builtin_amdgcn_mfma_f32_16x16x32_bf16(a, b, acc[fj], 0, 0, 0);
    }
    __syncthreads();
  }
  float* Cp = CBb + (size_t)sz * CHUNKSZ * CHUNKSZ;
  const int row0 = it * 64 + 16 * wv + (lane >> 4) * 4;
#pragma unroll
  for (int fj = 0; fj < 4; ++fj) {
    int col = jt * 64 + 16 * fj + lrow;
#pragma unroll
    for (int rr = 0; rr < 4; ++rr)
      Cp[(size_t)(row0 + rr) * CHUNKSZ + col] = acc[fj][rr];
  }
}

// ---------------- statesT[s,z,kh][n][p] = sum_c B[c,n]*decay[c]*xdt[c,p]  (MFMA, bf16 out) ----------------
__global__ __launch_bounds__(256) void k_states_mfma(
    const ushort* __restrict__ BT, const ushort* __restrict__ XhT,
    const float* __restrict__ dAcs, ushort* __restrict__ statesT)
{
  __shared__ __align__(16) ushort As[256 * 40];
  __shared__ __align__(16) ushort Bs[64 * 40];
  __shared__ float decay[CHUNKSZ];
  const int nh = blockIdx.x, kh = blockIdx.y, sz = blockIdx.z, s = sz >> 2, z = sz & 3;
  const int t = threadIdx.x, lane = t & 63, wv = t >> 6;
  const int lrow = lane & 15, lk = (lane >> 4) * 8;
  const float* dAp = dAcs + ((size_t)s * HK + kh) * LSEQ + z * CHUNKSZ;
  decay[t] = __expf(dAp[CHUNKSZ - 1] - dAp[t]);
  __syncthreads();
  f32x4 acc[4][4] = {};
  const ushort* Ap = BT + ((size_t)s * NSTATE + nh * 256) * LSEQ + z * CHUNKSZ;
  const ushort* Xp = XhT + ((size_t)s * HK + kh) * HD * LSEQ + z * CHUNKSZ;
  const int rb = t >> 2, c0 = (t & 3) * 8;
  for (int kt = 0; kt < 8; ++kt) {
#pragma unroll
    for (int q = 0; q < 4; ++q) {
      int rr = rb + 64 * q;
      *(uint4*)&As[rr * 40 + c0] = *(const uint4*)(Ap + (size_t)rr * LSEQ + kt * 32 + c0);
    }
    {
      const ushort* src = Xp + (size_t)rb * LSEQ + kt * 32 + c0;
      uint4 raw = *(const uint4*)src;
      ushort tmp[8]; *(uint4*)tmp = raw;
#pragma unroll
      for (int i2 = 0; i2 < 4; ++i2) {
        int c = kt * 32 + c0 + 2 * i2;
        unsigned wpk = (unsigned)f2bf(bf2f(tmp[2 * i2]) * decay[c]) |
                       ((unsigned)f2bf(bf2f(tmp[2 * i2 + 1]) * decay[c + 1]) << 16);
        *(unsigned*)&Bs[rb * 40 + c0 + 2 * i2] = wpk;
      }
    }
    __syncthreads();
    short8 a[4], b[4];
#pragma unroll
    for (int f = 0; f < 4; ++f) {
      a[f] = *(const short8*)&As[(64 * wv + 16 * f + lrow) * 40 + lk];
      b[f] = *(const short8*)&Bs[(16 * f + lrow) * 40 + lk];
    }
#pragma unroll
    for (int fi = 0; fi < 4; ++fi)
#pragma unroll
      for (int fj = 0; fj < 4; ++fj)
        acc[fi][fj] = __builtin_amdgcn_mfma_f32_16x16x32_bf16(a[fi], b[fj], acc[fi][fj], 0, 0, 0);
    __syncthreads();
  }
  ushort* Sp = statesT + (((size_t)sz * HK + kh) * NSTATE + nh * 256) * HD;
#pragma unroll
  for (int fi = 0; fi < 4; ++fi) {
    int row0 = 64 * wv + 16 * fi + (lane >> 4) * 4;
#pragma unroll
    for (int fj = 0; fj < 4; ++fj) {
      int col = 16 * fj + lrow;
#pragma unroll
      for (int rr = 0; rr < 4; ++rr)
        Sp[(size_t)(row0 + rr) * HD + col] = f2bf(acc[fi][fj][rr]);
    }
  }
}

// ---------------- inter-chunk scan: statesT (bf16) -> prevP[p][n] (bf16) ----------------
__global__ __launch_bounds__(256) void k_scan2(
    const ushort* __restrict__ statesT, const float* __restrict__ dAcs,
    ushort* __restrict__ prevP)
{
  __shared__ __align__(16) ushort T[64 * 72];
  const int nt = blockIdx.x, kh = blockIdx.y, s = blockIdx.z;
  const int t = threadIdx.x, rn = t >> 2, p0 = (t & 3) * 16;
  const float* dA = dAcs + ((size_t)s * HK + kh) * LSEQ;
  float carry[16];
#pragma unroll
  for (int i = 0; i < 16; ++i) carry[i] = 0.f;
  for (int z = 0; z < NC; ++z) {
    int sz = s * 4 + z;
    const ushort* Sp = statesT + (((size_t)sz * HK + kh) * NSTATE + nt * 64 + rn) * HD + p0;
    ushort raw[16];
    *(uint4*)raw       = *(const uint4*)Sp;
    *(uint4*)(raw + 8) = *(const uint4*)(Sp + 8);
#pragma unroll
    for (int i = 0; i < 16; ++i) T[(p0 + i) * 72 + rn] = f2bf(carry[i]);
    float cdec = __expf(dA[z * CHUNKSZ + CHUNKSZ - 1]);
#pragma unroll
    for (int i = 0; i < 16; ++i) carry[i] = carry[i] * cdec + bf2f(raw[i]);
    __syncthreads();
    ushort* dst = prevP + (((size_t)sz * HK + kh) * HD + rn) * NSTATE + nt * 64 + p0;
    *(uint4*)dst       = *(const uint4*)&T[rn * 72 + p0];
    *(uint4*)(dst + 8) = *(const uint4*)&T[rn * 72 + p0 + 8];
    __syncthreads();
  }
}

// ---------------- Y = Ydiag + Yoff (MFMA) ----------------
__global__ __launch_bounds__(256) void k_y_mfma(
    const float* __restrict__ CBb, const ushort* __restrict__ XhT,
    const ushort* __restrict__ Cbf, const ushort* __restrict__ prevP,
    const float* __restrict__ dAcs, float* __restrict__ Y)
{
  __shared__ __align__(16) ushort As[256 * 40];
  __shared__ __align__(16) ushort Bs[64 * 40];
  __shared__ float seg[CHUNKSZ];
  __shared__ float eA[CHUNKSZ];
  const int kh = blockIdx.x, sz = blockIdx.y, s = sz >> 2, z = sz & 3;
  const int t = threadIdx.x, lane = t & 63, wv = t >> 6;
  const int lrow = lane & 15, lk = (lane >> 4) * 8;

  const float* dAp = dAcs + ((size_t)s * HK + kh) * LSEQ + z * CHUNKSZ;
  {
    float v = dAp[t];
    seg[t] = v;
    eA[t] = __expf(v);
  }
  __syncthreads();

  f32x4 acc[4][4] = {};
  const float* CBp = CBb + (size_t)sz * CHUNKSZ * CHUNKSZ;
  const ushort* Xp = XhT + ((size_t)s * HK + kh) * HD * LSEQ + z * CHUNKSZ;

  // phase 1: Ydiag, A = CB .* exp(seg_i - seg_j) masked, B = xdt
  for (int kt = 0; kt < 8; ++kt) {
    {
      const int r = t;
      const int jbase = kt * 32;
      if (jbase <= r) {
        float si = seg[r];
        const float* cbrow = CBp + (size_t)r * CHUNKSZ + jbase;
#pragma unroll
        for (int c = 0; c < 32; c += 2) {
          int j0 = jbase + c, j1 = j0 + 1;
          float v0 = (j0 <= r) ? cbrow[c]     * __expf(si - seg[j0]) : 0.f;
          float v1 = (j1 <= r) ? cbrow[c + 1] * __expf(si - seg[j1]) : 0.f;
          *(unsigned*)&As[r * 40 + c] = (unsigned)f2bf(v0) | ((unsigned)f2bf(v1) << 16);
        }
      } else {
#pragma unroll
        for (int c = 0; c < 32; c += 2) *(unsigned*)&As[r * 40 + c] = 0u;
      }
    }
    {
      int p = t >> 2, c0 = (t & 3) * 8;
      *(uint4*)&Bs[p * 40 + c0] = *(const uint4*)(Xp + (size_t)p * LSEQ + kt * 32 + c0);
    }
    __syncthreads();
    if (kt <= 2 * wv + 1) {
      short8 a[4], b[4];
#pragma unroll
      for (int f = 0; f < 4; ++f) {
        a[f] = *(const short8*)&As[(64 * wv + 16 * f + lrow) * 40 + lk];
        b[f] = *(const short8*)&Bs[(16 * f + lrow) * 40 + lk];
      }
#pragma unroll
      for (int fi = 0; fi < 4; ++fi)
#pragma unroll
        for (int fj = 0; fj < 4; ++fj)
          acc[fi][fj] = __builtin_amdgcn_mfma_f32_16x16x32_bf16(a[fi], b[fj], acc[fi][fj], 0, 0, 0);
    }
    __syncthreads();
  }

  // phase 2: Yoff, A = C .* eA[i], B = prevP
  const ushort* Cp = Cbf + ((size_t)s * LSEQ + z * CHUNKSZ) * NSTATE;
  const ushort* Pp = prevP + ((size_t)sz * HK + kh) * HD * NSTATE;
  for (int nt = 0; nt < 16; ++nt) {
    {
      const int rb = t >> 2, c0 = (t & 3) * 8;
#pragma unroll
      for (int q = 0; q < 4; ++q) {
        int r = rb + 64 * q;
        const ushort* src = Cp + (size_t)r * NSTATE + nt * 32 + c0;
        float e = eA[r];
        uint4 raw = *(const uint4*)src;
        ushort tmp[8]; *(uint4*)tmp = raw;
#pragma unroll
        for (int i2 = 0; i2 < 4; ++i2) {
          unsigned wpk = (unsigned)f2bf(bf2f(tmp[2 * i2]) * e) |
                         ((unsigned)f2bf(bf2f(tmp[2 * i2 + 1]) * e) << 16);
          *(unsigned*)&As[r * 40 + c0 + 2 * i2] = wpk;
        }
      }
      *(uint4*)&Bs[rb * 40 + c0] = *(const uint4*)(Pp + (size_t)rb * NSTATE + nt * 32 + c0);
    }
    __syncthreads();
    {
      short8 b[4];
#pragma unroll
      for (int f = 0; f < 4; ++f) b[f] = *(const short8*)&Bs[(16 * f + lrow) * 40 + lk];
#pragma unroll
      for (int fi = 0; fi < 4; ++fi) {
        short8 a = *(const short8*)&As[(64 * wv + 16 * fi + lrow) * 40 + lk];
#pragma unroll
        for (int fj = 0; fj < 4; ++fj)
          acc[fi][fj] = __builtin_amdgcn_mfma_f32_16x16x32_bf16(a, b[fj], acc[fi][fj], 0, 0, 0);
      }
    }
    __syncthreads();
  }

  float* Yp = Y + (((size_t)s * LSEQ + z * CHUNKSZ) * HK + kh) * HD;
#pragma unroll
  for (int fi = 0; fi < 4; ++fi) {
    int row0 = 64 * wv + 16 * fi + (lane >> 4) * 4;
#pragma unroll
    for (int fj = 0; fj < 4; ++fj) {
      int col = 16 * fj + lrow;
#pragma unroll
      for (int rr = 0; rr < 4; ++rr)
        Yp[(size_t)(row0 + rr) * (HK * HD) + col] = acc[fi][fj][rr];
    }
  }
}

// ---------------- combine 4 directions + D*x + gated RMSNorm + MLP half (bf16 out) ----------------
__global__ __launch_bounds__(256) void k_combine(
    const float* __restrict__ Y, const float* __restrict__ xbcT,
    const float* __restrict__ skipxs, const float* __restrict__ Ds,
    const float* __restrict__ normw, ushort* __restrict__ o768bf)
{
  const int m = blockIdx.x, s = blockIdx.y, t = threadIdx.x;
  const int h = m >> 5, w = m & 31;
  const int l0 = m, l1 = (w << 5) | h, l2 = 1023 - m, l3 = 1023 - ((w << 5) | h);
  const float* Yb = Y + (size_t)s * LSEQ * (HK * HD);
  const float* xrow = xbcT + ((size_t)s * LSEQ + m) * CTOT;
  const float* srow = skipxs + ((size_t)s * LSEQ + m) * 1536;

  float g[2];
  float ss = 0.f;
#pragma unroll
  for (int q = 0; q < 2; ++q) {
    int d = t + q * 256;
    int hh = d >> 6, p = d & 63;
    float dsum = Ds[hh] + Ds[hh + 8] + Ds[hh + 16] + Ds[hh + 24];
    float val = Yb[((size_t)l0 * HK + hh) * HD + p]
              + Yb[((size_t)l1 * HK + 8 + hh) * HD + p]
              + Yb[((size_t)l2 * HK + 16 + hh) * HD + p]
              + Yb[((size_t)l3 * HK + 24 + hh) * HD + p]
              + xrow[d] * dsum;
    float zv = srow[512 + d];
    g[q] = val * siluf(zv);
    ss += g[q] * g[q];
  }
  for (int off = 32; off > 0; off >>= 1) ss += __shfl_down(ss, off, 64);
  __shared__ float red[4];
  if ((t & 63) == 0) red[t >> 6] = ss;
  __syncthreads();
  float total = red[0] + red[1] + red[2] + red[3];
  float scale = rsqrtf(total * (1.f / 512.f) + 1e-5f);

  ushort* orow = o768bf + ((size_t)s * LSEQ + m) * 768;
#pragma unroll
  for (int q = 0; q < 2; ++q) {
    int d = t + q * 256;
    orow[256 + d] = f2bf(g[q] * scale * normw[d]);
  }
  float z0 = srow[t], x0 = srow[256 + t];
  orow[t] = f2bf(siluf(z0) * x0);
}

// ---------------- workspace layout (float units) ----------------
constexpr size_t OFF_SKIPXS = 0;                        // 2048*1536 f32 = 3145728
constexpr size_t OFF_XBCT = 3145728;                    // 2*1024*776 f32 = 1589248
constexpr size_t OFF_XHT  = OFF_XBCT + 1589248;         // bf16 2*32*64*1024 -> 2097152 f
constexpr size_t OFF_BBF  = OFF_XHT + 2097152;          // 524288
constexpr size_t OFF_CBF  = OFF_BBF + 524288;           // 524288
constexpr size_t OFF_BTBF = OFF_CBF + 524288;           // 524288
constexpr size_t OFF_DA   = OFF_BTBF + 524288;          // 65536
constexpr size_t OFF_CB   = OFF_DA + 65536;             // 524288
constexpr size_t OFF_ST   = OFF_CB + 524288;            // 4194304 (statesT bf16; overlays below)
constexpr size_t OFF_PREV = OFF_ST + 4194304;           // 4194304
constexpr size_t OFF_O768 = OFF_PREV + 4194304;         // bf16 2048*768 -> 786432 f
constexpr size_t OFF_WSXT = OFF_O768 + 786432;          // bf16 1536*384 -> 294912 f
constexpr size_t OFF_WBCT = OFF_WSXT + 294912;          // bf16 264*384 -> 50688 f
constexpr size_t OFF_WOUT = OFF_WBCT + 50688;           // bf16 384*768 -> 147456 f
// overlays in ST region (disjoint lifetimes):
//   Ubf/UCbf (cast -> gemm1/2), bc_pre (gemm2 -> conv)  all dead before k_states
//   Y (written by k_y after statesT consumed by k_scan2, read by k_combine)
constexpr size_t OFF_UBF  = OFF_ST;                     // bf16 2048*384 -> 393216 f
constexpr size_t OFF_UCBF = OFF_UBF + 393216;           // 393216 f
constexpr size_t OFF_BCP  = OFF_UCBF + 393216;          // f32 2048*264 = 540672
constexpr size_t OFF_Y    = OFF_ST;                     // f32 4194304

extern "C" void kernel_launch(void* const* d_in, const int* in_sizes, int n_in,
                              void* d_out, int out_size, void* d_ws, size_t ws_size,
                              hipStream_t stream)
{
  const float* u1     = (const float*)d_in[0];
  const float* u2     = (const float*)d_in[1];
  const float* u2c1   = (const float*)d_in[2];
  const float* u1c2   = (const float*)d_in[3];
  const float* W_skip = (const float*)d_in[4];
  const float* W_xs   = (const float*)d_in[5];
  const float* W_bcdt = (const float*)d_in[6];
  const float* cxw    = (const float*)d_in[7];
  const float* cxb    = (const float*)d_in[8];
  const float* cbw    = (const float*)d_in[9];
  const float* cbb    = (const float*)d_in[10];
  const float* Ds     = (const float*)d_in[11];
  const float* normw  = (const float*)d_in[12];
  const float* W_out  = (const float*)d_in[13];
  const float* dt_b   = (const float*)d_in[14];
  const float* A_logs = (const float*)d_in[15];
  float* out = (float*)d_out;
  float* ws  = (float*)d_ws;

  float*  skipxs  = ws + OFF_SKIPXS;
  float*  xbcT    = ws + OFF_XBCT;
  ushort* XhT     = (ushort*)(ws + OFF_XHT);
  ushort* Bbf     = (ushort*)(ws + OFF_BBF);
  ushort* Cbf     = (ushort*)(ws + OFF_CBF);
  ushort* BTbf    = (ushort*)(ws + OFF_BTBF);
  float*  dAcs    = ws + OFF_DA;
  float*  CBb     = ws + OFF_CB;
  ushort* statesT = (ushort*)(ws + OFF_ST);
  ushort* prevP   = (ushort*)(ws + OFF_PREV);
  ushort* o768bf  = (ushort*)(ws + OFF_O768);
  ushort* WsxT    = (ushort*)(ws + OFF_WSXT);
  ushort* WbcdtT  = (ushort*)(ws + OFF_WBCT);
  ushort* WoutT   = (ushort*)(ws + OFF_WOUT);
  ushort* Ubf     = (ushort*)(ws + OFF_UBF);
  ushort* UCbf    = (ushort*)(ws + OFF_UCBF);
  float*  bc_pre  = ws + OFF_BCP;
  float*  Ybuf    = ws + OFF_Y;

  // prep: casts + weight transposes
  k_cast_u<<<dim3(768, 2), 256, 0, stream>>>(u1, u2, u2c1, u1c2, Ubf, UCbf);
  k_wtransp<<<dim3(16, 6), 256, 0, stream>>>(W_skip, WsxT, 1024, 384);
  k_wtransp<<<dim3(8, 6),  256, 0, stream>>>(W_xs, WsxT + (size_t)1024 * 384, 512, 384);
  k_wtransp<<<dim3(5, 6),  256, 0, stream>>>(W_bcdt, WbcdtT, 264, 384);
  k_wtransp<<<dim3(6, 12), 256, 0, stream>>>(W_out, WoutT, 384, 768);
  // input GEMMs (MFMA)
  gemm_bf16<<<dim3(12, 16), 256, 0, stream>>>(Ubf, WsxT, skipxs, 2048, 1536, 384);
  gemm_bf16<<<dim3(3, 16),  256, 0, stream>>>(UCbf, WbcdtT, bc_pre, 2048, 264, 384);
  // conv + gathers
  k_conv<<<dim3(1024, 2), 256, 0, stream>>>(skipxs, bc_pre, cxw, cxb, cbw, cbb, xbcT);
  k_gather_x2<<<dim3(16, 32, 2), 256, 0, stream>>>(xbcT, dt_b, XhT);
  k_gather_bc<<<dim3(1024, 4, 2), 128, 0, stream>>>(xbcT, dt_b, A_logs, Bbf, Cbf, dAcs);
  k_transp<<<dim3(16, 8, 2), 256, 0, stream>>>(Bbf, BTbf);
  k_cumsum<<<dim3(4, 32, 2), 256, 0, stream>>>(dAcs);
  // scan core (MFMA)
  k_cb_mfma<<<dim3(4, 4, 8), 256, 0, stream>>>(Cbf, Bbf, CBb);
  k_states_mfma<<<dim3(2, 32, 8), 256, 0, stream>>>(BTbf, XhT, dAcs, statesT);
  k_scan2<<<dim3(8, 32, 2), 256, 0, stream>>>(statesT, dAcs, prevP);
  k_y_mfma<<<dim3(32, 8), 256, 0, stream>>>(CBb, XhT, Cbf, prevP, dAcs, Ybuf);
  // epilogue
  k_combine<<<dim3(1024, 2), 256, 0, stream>>>(Ybuf, xbcT, skipxs, Ds, normw, o768bf);
  gemm_bf16<<<dim3(3, 16), 256, 0, stream>>>(o768bf, WoutT, out, 2048, 384, 768);
}

// Round 4
// 186.285 us; speedup vs baseline: 3.0219x; 1.0615x over previous
//
#include <hip/hip_runtime.h>
#include <hip/hip_bf16.h>
#include <cstddef>

// ---------------- problem constants ----------------
#define LSEQ   1024
#define DM     384
#define DSSM   512
#define NSTATE 512      // K * D_STATE (shared across heads in the reference einsums)
#define HK     32       // K * NHEADS combined heads
#define HD     64       // head dim
#define CHUNKSZ 256
#define NC     4
#define CBCDT  264
#define CTOT   776      // 512 + 264
#define DMLP   256

typedef __attribute__((ext_vector_type(8))) short short8;
typedef __attribute__((ext_vector_type(4))) float f32x4;

__device__ __forceinline__ float siluf(float x)    { return x / (1.f + expf(-x)); }
__device__ __forceinline__ float softplusf(float x){ return fmaxf(x, 0.f) + log1pf(expf(-fabsf(x))); }

__device__ __forceinline__ ushort f2bf(float f) {
  union { float f; unsigned u; } v; v.f = f;
  unsigned r = v.u + 0x7fffu + ((v.u >> 16) & 1u);
  return (ushort)(r >> 16);
}
__device__ __forceinline__ float bf2f(ushort h) {
  union { unsigned u; float f; } v; v.u = ((unsigned)h) << 16;
  return v.f;
}

// direction k, sequence pos l -> row-major spatial index m (32x32 grid)
__device__ __forceinline__ int dir_src(int k, int l) {
  switch (k) {
    case 0:  return l;
    case 1:  return ((l & 31) << 5) | (l >> 5);
    case 2:  return 1023 - l;
    default: { int lr = 1023 - l; return ((lr & 31) << 5) | (lr >> 5); }
  }
}

// ---------------- cast u / uc (f32) -> bf16 [2048][384] ----------------
__global__ __launch_bounds__(256) void k_cast_u(
    const float* __restrict__ u1, const float* __restrict__ u2,
    const float* __restrict__ uc1, const float* __restrict__ uc2,
    ushort* __restrict__ Ubf, ushort* __restrict__ UCbf)
{
  const int i = (blockIdx.x * 256 + threadIdx.x) * 4;   // [0, 786432)
  const float* s0 = blockIdx.y ? uc1 : u1;
  const float* s1 = blockIdx.y ? uc2 : u2;
  ushort* dst = blockIdx.y ? UCbf : Ubf;
  float4 v = (i < 393216) ? *(const float4*)(s0 + i) : *(const float4*)(s1 + i - 393216);
  ushort o[4] = { f2bf(v.x), f2bf(v.y), f2bf(v.z), f2bf(v.w) };
  *(uint2*)(dst + i) = *(const uint2*)o;
}

// ---------------- transpose-cast weight: src f32 [K][N] -> dst bf16 [N][ldd] ----------------
__global__ __launch_bounds__(256) void k_wtransp(
    const float* __restrict__ src, ushort* __restrict__ dst, int N, int ldd)
{
  __shared__ __align__(16) ushort T[64 * 72];
  const int n0 = blockIdx.x * 64, k0 = blockIdx.y * 64;
  const int t = threadIdx.x, rk = t >> 2, q = t & 3;
  const int k = k0 + rk;
  const float* srow = src + (size_t)k * N + n0 + q * 16;
#pragma unroll
  for (int i = 0; i < 16; ++i) {
    int n = n0 + q * 16 + i;
    T[(q * 16 + i) * 72 + rk] = (n < N) ? f2bf(srow[i]) : (ushort)0;
  }
  __syncthreads();
  int n = n0 + rk;
  if (n < N) {
    ushort* d = dst + (size_t)n * ldd + k0 + q * 16;
    *(uint4*)d       = *(const uint4*)&T[rk * 72 + q * 16];
    *(uint4*)(d + 8) = *(const uint4*)&T[rk * 72 + q * 16 + 8];
  }
}

// ---------------- bf16 MFMA GEMM: C[M][N] f32 = A[M][K] * BT[N][K] ----------------
__global__ __launch_bounds__(256) void gemm_bf16(
    const ushort* __restrict__ A, const ushort* __restrict__ BT,
    float* __restrict__ C, int M, int N, int K)
{
  __shared__ __align__(16) ushort As[128 * 40];
  __shared__ __align__(16) ushort Bs[128 * 40];
  const int n0 = blockIdx.x * 128, m0 = blockIdx.y * 128;
  const int t = threadIdx.x, lane = t & 63, wv = t >> 6;
  const int wm = wv & 1, wn = wv >> 1;
  const int lrow = lane & 15, lk8 = (lane >> 4) * 8;
  const int rowL = t >> 1, cL = (t & 1) * 16;
  f32x4 acc[4][4] = {};
  for (int k0 = 0; k0 < K; k0 += 32) {
    {
      const ushort* src = A + (size_t)(m0 + rowL) * K + k0 + cL;
      *(uint4*)&As[rowL * 40 + cL]     = *(const uint4*)src;
      *(uint4*)&As[rowL * 40 + cL + 8] = *(const uint4*)(src + 8);
    }
    {
      int n = n0 + rowL;
      if (n < N) {
        const ushort* src = BT + (size_t)n * K + k0 + cL;
        *(uint4*)&Bs[rowL * 40 + cL]     = *(const uint4*)src;
        *(uint4*)&Bs[rowL * 40 + cL + 8] = *(const uint4*)(src + 8);
      } else {
        uint4 z = {0, 0, 0, 0};
        *(uint4*)&Bs[rowL * 40 + cL] = z;
        *(uint4*)&Bs[rowL * 40 + cL + 8] = z;
      }
    }
    __syncthreads();
    short8 a[4], b[4];
#pragma unroll
    for (int f = 0; f < 4; ++f) {
      a[f] = *(const short8*)&As[(wm * 64 + 16 * f + lrow) * 40 + lk8];
      b[f] = *(const short8*)&Bs[(wn * 64 + 16 * f + lrow) * 40 + lk8];
    }
#pragma unroll
    for (int fi = 0; fi < 4; ++fi)
#pragma unroll
      for (int fj = 0; fj < 4; ++fj)
        acc[fi][fj] = __builtin_amdgcn_mfma_f32_16x16x32_bf16(a[fi], b[fj], acc[fi][fj], 0, 0, 0);
    __syncthreads();
  }
#pragma unroll
  for (int fi = 0; fi < 4; ++fi) {
    int row0 = m0 + wm * 64 + 16 * fi + (lane >> 4) * 4;
#pragma unroll
    for (int fj = 0; fj < 4; ++fj) {
      int col = n0 + wn * 64 + 16 * fj + lrow;
      if (col < N)
#pragma unroll
        for (int rr = 0; rr < 4; ++rr)
          C[(size_t)(row0 + rr) * N + col] = acc[fi][fj][rr];
    }
  }
}

// ---------------- depthwise 3x3 conv + bias + SiLU; writes xbcT[s][m][c] ----------------
__global__ __launch_bounds__(256) void k_conv(
    const float* __restrict__ skipxs, const float* __restrict__ bc_pre,
    const float* __restrict__ wxs, const float* __restrict__ bxs,
    const float* __restrict__ wbc, const float* __restrict__ bbc,
    float* __restrict__ xbcT)
{
  const int m = blockIdx.x, s = blockIdx.y;
  const int h = m >> 5, w = m & 31;
  const float* xp = skipxs + (size_t)s * LSEQ * 1536 + 1024;   // xs part, stride 1536
  const float* bp = bc_pre + (size_t)s * LSEQ * CBCDT;
  for (int c = threadIdx.x; c < CTOT; c += 256) {
    const float* src; int stride; const float* wt; float bias;
    if (c < DSSM) { src = xp + c; stride = 1536; wt = wxs + (size_t)c * 9; bias = bxs[c]; }
    else { int cb = c - DSSM; src = bp + cb; stride = CBCDT; wt = wbc + (size_t)cb * 9; bias = bbc[cb]; }
    float acc = bias;
#pragma unroll
    for (int dh = -1; dh <= 1; ++dh) {
      int h2 = h + dh; if (h2 < 0 || h2 > 31) continue;
#pragma unroll
      for (int dw = -1; dw <= 1; ++dw) {
        int w2 = w + dw; if (w2 < 0 || w2 > 31) continue;
        acc += src[(size_t)(h2 * 32 + w2) * stride] * wt[(dh + 1) * 3 + (dw + 1)];
      }
    }
    xbcT[((size_t)s * LSEQ + m) * CTOT + c] = siluf(acc);
  }
}

// ---------------- gather x*dt (bf16) into XhT[s][kh][p=64][l=1024] via LDS transpose ----------------
__global__ __launch_bounds__(256) void k_gather_x2(
    const float* __restrict__ xbcT, const float* __restrict__ dt_bias,
    ushort* __restrict__ XhT)
{
  __shared__ __align__(16) ushort T[64 * 72];
  const int lt = blockIdx.x, kh = blockIdx.y, s = blockIdx.z;
  const int k = kh >> 3, hh = kh & 7;
  const int t = threadIdx.x;
  const int r = t >> 2, q = t & 3;
  const int l = lt * 64 + r;
  const int m = dir_src(k, l);
  const float* row = xbcT + ((size_t)s * LSEQ + m) * CTOT;
  float dtv = softplusf(row[768 + hh] + dt_bias[kh]);
  const float* xp = row + hh * 64 + q * 16;
#pragma unroll
  for (int i = 0; i < 16; ++i)
    T[(q * 16 + i) * 72 + r] = f2bf(xp[i] * dtv);
  __syncthreads();
  ushort* dst = XhT + (((size_t)s * HK + kh) * HD + r) * LSEQ + lt * 64 + q * 16;
  *(uint4*)dst       = *(const uint4*)&T[r * 72 + q * 16];
  *(uint4*)(dst + 8) = *(const uint4*)&T[r * 72 + q * 16 + 8];
}

// ---------------- gather B/C (bf16) + dA ----------------
__global__ __launch_bounds__(128) void k_gather_bc(
    const float* __restrict__ xbcT, const float* __restrict__ dt_bias,
    const float* __restrict__ A_logs,
    ushort* __restrict__ Bbf, ushort* __restrict__ Cbf, float* __restrict__ dAbuf)
{
  const int l = blockIdx.x, k = blockIdx.y, s = blockIdx.z;
  const int n = threadIdx.x;
  const int m = dir_src(k, l);
  const float* row = xbcT + ((size_t)s * LSEQ + m) * CTOT;
  Bbf[((size_t)s * LSEQ + l) * NSTATE + k * 128 + n] = f2bf(row[512 + n]);
  Cbf[((size_t)s * LSEQ + l) * NSTATE + k * 128 + n] = f2bf(row[640 + n]);
  if (n < 8) {
    int kh = k * 8 + n;
    float dtv = softplusf(row[768 + n] + dt_bias[kh]);
    dAbuf[((size_t)s * HK + kh) * LSEQ + l] = dtv * (-expf(A_logs[kh]));
  }
}

// ---------------- transpose Bmat_bf [l][n] -> BmatT_bf [n][l] ----------------
__global__ __launch_bounds__(256) void k_transp(
    const ushort* __restrict__ Bbf, ushort* __restrict__ BT)
{
  __shared__ __align__(16) ushort T[64 * 72];
  const int lt = blockIdx.x, nt = blockIdx.y, s = blockIdx.z;
  const int t = threadIdx.x, r = t >> 2, q = t & 3;
  const ushort* src = Bbf + ((size_t)s * LSEQ + lt * 64 + r) * NSTATE + nt * 64 + q * 16;
  ushort tmp[16];
  *(uint4*)tmp       = *(const uint4*)src;
  *(uint4*)(tmp + 8) = *(const uint4*)(src + 8);
#pragma unroll
  for (int i = 0; i < 16; ++i) T[(q * 16 + i) * 72 + r] = tmp[i];
  __syncthreads();
  ushort* dst = BT + ((size_t)s * NSTATE + nt * 64 + r) * LSEQ + lt * 64 + q * 16;
  *(uint4*)dst       = *(const uint4*)&T[r * 72 + q * 16];
  *(uint4*)(dst + 8) = *(const uint4*)&T[r * 72 + q * 16 + 8];
}

// ---------------- inclusive cumsum of dA within each chunk ----------------
__global__ __launch_bounds__(256) void k_cumsum(float* __restrict__ dAbuf)
{
  __shared__ float buf[CHUNKSZ];
  const int z = blockIdx.x, kh = blockIdx.y, s = blockIdx.z, t = threadIdx.x;
  float* p = dAbuf + ((size_t)s * HK + kh) * LSEQ + z * CHUNKSZ;
  buf[t] = p[t];
  __syncthreads();
  for (int off = 1; off < CHUNKSZ; off <<= 1) {
    float add = (t >= off) ? buf[t - off] : 0.f;
    __syncthreads();
    buf[t] += add;
    __syncthreads();
  }
  p[t] = buf[t];
}

// ---------------- CB[s][z] = Cr * Br^T (MFMA) ----------------
__global__ __launch_bounds__(256) void k_cb_mfma(
    const ushort* __restrict__ Cbf, const ushort* __restrict__ Bbf,
    float* __restrict__ CBb)
{
  __shared__ __align__(16) ushort As[64 * 40];
  __shared__ __align__(16) ushort Bs[64 * 40];
  const int jt = blockIdx.x, it = blockIdx.y, sz = blockIdx.z, s = sz >> 2, z = sz & 3;
  const int t = threadIdx.x, lane = t & 63, wv = t >> 6;
  const int lrow = lane & 15, lk = (lane >> 4) * 8;
  const ushort* Ap = Cbf + ((size_t)s * LSEQ + z * CHUNKSZ + it * 64) * NSTATE;
  const ushort* Bp = Bbf + ((size_t)s * LSEQ + z * CHUNKSZ + jt * 64) * NSTATE;
  f32x4 acc[4] = {};
  const int r = t >> 2, c0 = (t & 3) * 8;
  for (int kt = 0; kt < 16; ++kt) {
    *(uint4*)&As[r * 40 + c0] = *(const uint4*)(Ap + (size_t)r * NSTATE + kt * 32 + c0);
    *(uint4*)&Bs[r * 40 + c0] = *(const uint4*)(Bp + (size_t)r * NSTATE + kt * 32 + c0);
    __syncthreads();
    short8 a = *(const short8*)&As[(16 * wv + lrow) * 40 + lk];
#pragma unroll
    for (int fj = 0; fj < 4; ++fj) {
      short8 b = *(const short8*)&Bs[(16 * fj + lrow) * 40 + lk];
      acc[fj] = __builtin_amdgcn_mfma_f32_16x16x32_bf16(a, b, acc[fj], 0, 0, 0);
    }
    __syncthreads();
  }
  float* Cp = CBb + (size_t)sz * CHUNKSZ * CHUNKSZ;
  const int row0 = it * 64 + 16 * wv + (lane >> 4) * 4;
#pragma unroll
  for (int fj = 0; fj < 4; ++fj) {
    int col = jt * 64 + 16 * fj + lrow;
#pragma unroll
    for (int rr = 0; rr < 4; ++rr)
      Cp[(size_t)(row0 + rr) * CHUNKSZ + col] = acc[fj][rr];
  }
}

// ---------------- statesT[s,z,kh][n][p] = sum_c B[c,n]*decay[c]*xdt[c,p]  (MFMA, bf16 out) ----------------
// grid (4 nh, 32 kh, 8 sz), block 256; each block 128 n-rows
__global__ __launch_bounds__(256) void k_states_mfma(
    const ushort* __restrict__ BT, const ushort* __restrict__ XhT,
    const float* __restrict__ dAcs, ushort* __restrict__ statesT)
{
  __shared__ __align__(16) ushort As[128 * 40];
  __shared__ __align__(16) ushort Bs[64 * 40];
  __shared__ float decay[CHUNKSZ];
  const int nh = blockIdx.x, kh = blockIdx.y, sz = blockIdx.z, s = sz >> 2, z = sz & 3;
  const int t = threadIdx.x, lane = t & 63, wv = t >> 6;
  const int lrow = lane & 15, lk = (lane >> 4) * 8;
  const float* dAp = dAcs + ((size_t)s * HK + kh) * LSEQ + z * CHUNKSZ;
  decay[t] = __expf(dAp[CHUNKSZ - 1] - dAp[t]);
  __syncthreads();
  f32x4 acc[2][4] = {};
  const ushort* Ap = BT + ((size_t)s * NSTATE + nh * 128) * LSEQ + z * CHUNKSZ;
  const ushort* Xp = XhT + ((size_t)s * HK + kh) * HD * LSEQ + z * CHUNKSZ;
  const int rA = t >> 1, cA = (t & 1) * 16;
  const int rB = t >> 2, cB = (t & 3) * 8;
  for (int kt = 0; kt < 8; ++kt) {
    {
      const ushort* src = Ap + (size_t)rA * LSEQ + kt * 32 + cA;
      *(uint4*)&As[rA * 40 + cA]     = *(const uint4*)src;
      *(uint4*)&As[rA * 40 + cA + 8] = *(const uint4*)(src + 8);
    }
    {
      const ushort* src = Xp + (size_t)rB * LSEQ + kt * 32 + cB;
      ushort tmp[8]; *(uint4*)tmp = *(const uint4*)src;
#pragma unroll
      for (int i2 = 0; i2 < 4; ++i2) {
        int c = kt * 32 + cB + 2 * i2;
        unsigned wpk = (unsigned)f2bf(bf2f(tmp[2 * i2]) * decay[c]) |
                       ((unsigned)f2bf(bf2f(tmp[2 * i2 + 1]) * decay[c + 1]) << 16);
        *(unsigned*)&Bs[rB * 40 + cB + 2 * i2] = wpk;
      }
    }
    __syncthreads();
    short8 a[2], b[4];
#pragma unroll
    for (int f = 0; f < 2; ++f) a[f] = *(const short8*)&As[(32 * wv + 16 * f + lrow) * 40 + lk];
#pragma unroll
    for (int f = 0; f < 4; ++f) b[f] = *(const short8*)&Bs[(16 * f + lrow) * 40 + lk];
#pragma unroll
    for (int fi = 0; fi < 2; ++fi)
#pragma unroll
      for (int fj = 0; fj < 4; ++fj)
        acc[fi][fj] = __builtin_amdgcn_mfma_f32_16x16x32_bf16(a[fi], b[fj], acc[fi][fj], 0, 0, 0);
    __syncthreads();
  }
  ushort* Sp = statesT + (((size_t)sz * HK + kh) * NSTATE + nh * 128) * HD;
#pragma unroll
  for (int fi = 0; fi < 2; ++fi) {
    int row0 = 32 * wv + 16 * fi + (lane >> 4) * 4;
#pragma unroll
    for (int fj = 0; fj < 4; ++fj) {
      int col = 16 * fj + lrow;
#pragma unroll
      for (int rr = 0; rr < 4; ++rr)
        Sp[(size_t)(row0 + rr) * HD + col] = f2bf(acc[fi][fj][rr]);
    }
  }
}

// ---------------- inter-chunk scan: statesT (bf16) -> prevP[p][n] (bf16) ----------------
__global__ __launch_bounds__(256) void k_scan2(
    const ushort* __restrict__ statesT, const float* __restrict__ dAcs,
    ushort* __restrict__ prevP)
{
  __shared__ __align__(16) ushort T[64 * 72];
  const int nt = blockIdx.x, kh = blockIdx.y, s = blockIdx.z;
  const int t = threadIdx.x, rn = t >> 2, p0 = (t & 3) * 16;
  const float* dA = dAcs + ((size_t)s * HK + kh) * LSEQ;
  float carry[16];
#pragma unroll
  for (int i = 0; i < 16; ++i) carry[i] = 0.f;
  for (int z = 0; z < NC; ++z) {
    int sz = s * 4 + z;
    const ushort* Sp = statesT + (((size_t)sz * HK + kh) * NSTATE + nt * 64 + rn) * HD + p0;
    ushort raw[16];
    *(uint4*)raw       = *(const uint4*)Sp;
    *(uint4*)(raw + 8) = *(const uint4*)(Sp + 8);
#pragma unroll
    for (int i = 0; i < 16; ++i) T[(p0 + i) * 72 + rn] = f2bf(carry[i]);
    float cdec = __expf(dA[z * CHUNKSZ + CHUNKSZ - 1]);
#pragma unroll
    for (int i = 0; i < 16; ++i) carry[i] = carry[i] * cdec + bf2f(raw[i]);
    __syncthreads();
    ushort* dst = prevP + (((size_t)sz * HK + kh) * HD + rn) * NSTATE + nt * 64 + p0;
    *(uint4*)dst       = *(const uint4*)&T[rn * 72 + p0];
    *(uint4*)(dst + 8) = *(const uint4*)&T[rn * 72 + p0 + 8];
    __syncthreads();
  }
}

// ---------------- Y = Ydiag + Yoff (MFMA, restructured) ----------------
// grid (2 it, 32 kh, 8 sz), block 256; block handles 128 rows x 64 cols
// Phase A: acc = C @ prev^T (straight copies); acc *= eA_i
// Phase B: acc += [CB_ij * e^{si-sb}]_masked @ [e^{sb-sj} * xdt_jp]  (slice-factored)
__global__ __launch_bounds__(256) void k_y_mfma(
    const float* __restrict__ CBb, const ushort* __restrict__ XhT,
    const ushort* __restrict__ Cbf, const ushort* __restrict__ prevP,
    const float* __restrict__ dAcs, float* __restrict__ Y)
{
  __shared__ __align__(16) ushort As[128 * 40];
  __shared__ __align__(16) ushort Bs[64 * 40];
  __shared__ float seg[CHUNKSZ];
  __shared__ float f2s[CHUNKSZ];   // f2s[j] = exp(seg[jbase(j)] - seg[j])
  const int it = blockIdx.x, kh = blockIdx.y, sz = blockIdx.z, s = sz >> 2, z = sz & 3;
  const int t = threadIdx.x, lane = t & 63, wv = t >> 6;
  const int lrow = lane & 15, lk = (lane >> 4) * 8;
  const int i0 = it * 128;

  const float* dAp = dAcs + ((size_t)s * HK + kh) * LSEQ + z * CHUNKSZ;
  seg[t] = dAp[t];
  __syncthreads();
  f2s[t] = __expf(seg[(t >> 5) << 5] - seg[t]);

  f32x4 acc[2][4] = {};

  // ---- phase A: Yoff raw = C @ prev^T ----
  const ushort* Cp = Cbf + ((size_t)s * LSEQ + z * CHUNKSZ + i0) * NSTATE;
  const ushort* Pp = prevP + ((size_t)sz * HK + kh) * HD * NSTATE;
  const int rA = t >> 1, cA = (t & 1) * 16;
  const int rB = t >> 2, cB = (t & 3) * 8;
  for (int nt = 0; nt < 16; ++nt) {
    {
      const ushort* src = Cp + (size_t)rA * NSTATE + nt * 32 + cA;
      *(uint4*)&As[rA * 40 + cA]     = *(const uint4*)src;
      *(uint4*)&As[rA * 40 + cA + 8] = *(const uint4*)(src + 8);
    }
    *(uint4*)&Bs[rB * 40 + cB] = *(const uint4*)(Pp + (size_t)rB * NSTATE + nt * 32 + cB);
    __syncthreads();
    short8 a[2], b[4];
#pragma unroll
    for (int f = 0; f < 2; ++f) a[f] = *(const short8*)&As[(32 * wv + 16 * f + lrow) * 40 + lk];
#pragma unroll
    for (int f = 0; f < 4; ++f) b[f] = *(const short8*)&Bs[(16 * f + lrow) * 40 + lk];
#pragma unroll
    for (int fi = 0; fi < 2; ++fi)
#pragma unroll
      for (int fj = 0; fj < 4; ++fj)
        acc[fi][fj] = __builtin_amdgcn_mfma_f32_16x16x32_bf16(a[fi], b[fj], acc[fi][fj], 0, 0, 0);
    __syncthreads();
  }

  // ---- scale by eA_i ----
#pragma unroll
  for (int fi = 0; fi < 2; ++fi) {
    int rloc = 32 * wv + 16 * fi + (lane >> 4) * 4;
#pragma unroll
    for (int rr = 0; rr < 4; ++rr) {
      float e = __expf(seg[i0 + rloc + rr]);
#pragma unroll
      for (int fj = 0; fj < 4; ++fj) acc[fi][fj][rr] *= e;
    }
  }

  // ---- phase B: Ydiag (slice-factored) ----
  const float* CBp = CBb + (size_t)sz * CHUNKSZ * CHUNKSZ + (size_t)i0 * CHUNKSZ;
  const ushort* Xp = XhT + ((size_t)s * HK + kh) * HD * LSEQ + z * CHUNKSZ;
  const int ktmax = 4 * it + 4;
  for (int kt = 0; kt < ktmax; ++kt) {
    const int jbase = kt * 32;
    const float sb = seg[jbase];
    // stage A: CBL rows [0,128), cols 16 per thread (r = t>>1, half = t&1)
    {
      const int r = rA;                 // row within block
      const int i = i0 + r;             // row within chunk
      const int cbase = cA;             // 0 or 16
      if (i >= jbase) {
        float f1 = __expf(seg[i] - sb);
        const float* cbrow = CBp + (size_t)r * CHUNKSZ + jbase + cbase;
#pragma unroll
        for (int c = 0; c < 16; c += 2) {
          int j = jbase + cbase + c;
          float v0 = (j     <= i) ? cbrow[c]     * f1 : 0.f;
          float v1 = (j + 1 <= i) ? cbrow[c + 1] * f1 : 0.f;
          *(unsigned*)&As[r * 40 + cbase + c] = (unsigned)f2bf(v0) | ((unsigned)f2bf(v1) << 16);
        }
      } else {
        uint4 zz = {0, 0, 0, 0};
        *(uint4*)&As[r * 40 + cbase]     = zz;
        *(uint4*)&As[r * 40 + cbase + 8] = zz;
      }
    }
    // stage B: xdt rows p (64), cols j (32), scaled by f2s[j]
    {
      const ushort* src = Xp + (size_t)rB * LSEQ + jbase + cB;
      ushort tmp[8]; *(uint4*)tmp = *(const uint4*)src;
#pragma unroll
      for (int i2 = 0; i2 < 4; ++i2) {
        int j = jbase + cB + 2 * i2;
        unsigned wpk = (unsigned)f2bf(bf2f(tmp[2 * i2]) * f2s[j]) |
                       ((unsigned)f2bf(bf2f(tmp[2 * i2 + 1]) * f2s[j + 1]) << 16);
        *(unsigned*)&Bs[rB * 40 + cB + 2 * i2] = wpk;
      }
    }
    __syncthreads();
    if (kt <= 4 * it + wv) {
      short8 a[2], b[4];
#pragma unroll
      for (int f = 0; f < 2; ++f) a[f] = *(const short8*)&As[(32 * wv + 16 * f + lrow) * 40 + lk];
#pragma unroll
      for (int f = 0; f < 4; ++f) b[f] = *(const short8*)&Bs[(16 * f + lrow) * 40 + lk];
#pragma unroll
      for (int fi = 0; fi < 2; ++fi)
#pragma unroll
        for (int fj = 0; fj < 4; ++fj)
          acc[fi][fj] = __builtin_amdgcn_mfma_f32_16x16x32_bf16(a[fi], b[fj], acc[fi][fj], 0, 0, 0);
    }
    __syncthreads();
  }

  float* Yp = Y + (((size_t)s * LSEQ + z * CHUNKSZ + i0) * HK + kh) * HD;
#pragma unroll
  for (int fi = 0; fi < 2; ++fi) {
    int row0 = 32 * wv + 16 * fi + (lane >> 4) * 4;
#pragma unroll
    for (int fj = 0; fj < 4; ++fj) {
      int col = 16 * fj + lrow;
#pragma unroll
      for (int rr = 0; rr < 4; ++rr)
        Yp[(size_t)(row0 + rr) * (HK * HD) + col] = acc[fi][fj][rr];
    }
  }
}

// ---------------- combine 4 directions + D*x + gated RMSNorm + MLP half (bf16 out) ----------------
__global__ __launch_bounds__(256) void k_combine(
    const float* __restrict__ Y, const float* __restrict__ xbcT,
    const float* __restrict__ skipxs, const float* __restrict__ Ds,
    const float* __restrict__ normw, ushort* __restrict__ o768bf)
{
  const int m = blockIdx.x, s = blockIdx.y, t = threadIdx.x;
  const int h = m >> 5, w = m & 31;
  const int l0 = m, l1 = (w << 5) | h, l2 = 1023 - m, l3 = 1023 - ((w << 5) | h);
  const float* Yb = Y + (size_t)s * LSEQ * (HK * HD);
  const float* xrow = xbcT + ((size_t)s * LSEQ + m) * CTOT;
  const float* srow = skipxs + ((size_t)s * LSEQ + m) * 1536;

  float g[2];
  float ss = 0.f;
#pragma unroll
  for (int q = 0; q < 2; ++q) {
    int d = t + q * 256;
    int hh = d >> 6, p = d & 63;
    float dsum = Ds[hh] + Ds[hh + 8] + Ds[hh + 16] + Ds[hh + 24];
    float val = Yb[((size_t)l0 * HK + hh) * HD + p]
              + Yb[((size_t)l1 * HK + 8 + hh) * HD + p]
              + Yb[((size_t)l2 * HK + 16 + hh) * HD + p]
              + Yb[((size_t)l3 * HK + 24 + hh) * HD + p]
              + xrow[d] * dsum;
    float zv = srow[512 + d];
    g[q] = val * siluf(zv);
    ss += g[q] * g[q];
  }
  for (int off = 32; off > 0; off >>= 1) ss += __shfl_down(ss, off, 64);
  __shared__ float red[4];
  if ((t & 63) == 0) red[t >> 6] = ss;
  __syncthreads();
  float total = red[0] + red[1] + red[2] + red[3];
  float scale = rsqrtf(total * (1.f / 512.f) + 1e-5f);

  ushort* orow = o768bf + ((size_t)s * LSEQ + m) * 768;
#pragma unroll
  for (int q = 0; q < 2; ++q) {
    int d = t + q * 256;
    orow[256 + d] = f2bf(g[q] * scale * normw[d]);
  }
  float z0 = srow[t], x0 = srow[256 + t];
  orow[t] = f2bf(siluf(z0) * x0);
}

// ---------------- workspace layout (float units) ----------------
constexpr size_t OFF_SKIPXS = 0;                        // 2048*1536 f32 = 3145728
constexpr size_t OFF_XBCT = 3145728;                    // 2*1024*776 f32 = 1589248
constexpr size_t OFF_XHT  = OFF_XBCT + 1589248;         // bf16 2*32*64*1024 -> 2097152 f
constexpr size_t OFF_BBF  = OFF_XHT + 2097152;          // 524288
constexpr size_t OFF_CBF  = OFF_BBF + 524288;           // 524288
constexpr size_t OFF_BTBF = OFF_CBF + 524288;           // 524288
constexpr size_t OFF_DA   = OFF_BTBF + 524288;          // 65536
constexpr size_t OFF_CB   = OFF_DA + 65536;             // 524288
constexpr size_t OFF_ST   = OFF_CB + 524288;            // 4194304 (statesT bf16; overlays below)
constexpr size_t OFF_PREV = OFF_ST + 4194304;           // 4194304
constexpr size_t OFF_O768 = OFF_PREV + 4194304;         // bf16 2048*768 -> 786432 f
constexpr size_t OFF_WSXT = OFF_O768 + 786432;          // bf16 1536*384 -> 294912 f
constexpr size_t OFF_WBCT = OFF_WSXT + 294912;          // bf16 264*384 -> 50688 f
constexpr size_t OFF_WOUT = OFF_WBCT + 50688;           // bf16 384*768 -> 147456 f
// overlays in ST region (disjoint lifetimes):
constexpr size_t OFF_UBF  = OFF_ST;                     // bf16 2048*384 -> 393216 f
constexpr size_t OFF_UCBF = OFF_UBF + 393216;           // 393216 f
constexpr size_t OFF_BCP  = OFF_UCBF + 393216;          // f32 2048*264 = 540672
constexpr size_t OFF_Y    = OFF_ST;                     // f32 4194304

extern "C" void kernel_launch(void* const* d_in, const int* in_sizes, int n_in,
                              void* d_out, int out_size, void* d_ws, size_t ws_size,
                              hipStream_t stream)
{
  const float* u1     = (const float*)d_in[0];
  const float* u2     = (const float*)d_in[1];
  const float* u2c1   = (const float*)d_in[2];
  const float* u1c2   = (const float*)d_in[3];
  const float* W_skip = (const float*)d_in[4];
  const float* W_xs   = (const float*)d_in[5];
  const float* W_bcdt = (const float*)d_in[6];
  const float* cxw    = (const float*)d_in[7];
  const float* cxb    = (const float*)d_in[8];
  const float* cbw    = (const float*)d_in[9];
  const float* cbb    = (const float*)d_in[10];
  const float* Ds     = (const float*)d_in[11];
  const float* normw  = (const float*)d_in[12];
  const float* W_out  = (const float*)d_in[13];
  const float* dt_b   = (const float*)d_in[14];
  const float* A_logs = (const float*)d_in[15];
  float* out = (float*)d_out;
  float* ws  = (float*)d_ws;

  float*  skipxs  = ws + OFF_SKIPXS;
  float*  xbcT    = ws + OFF_XBCT;
  ushort* XhT     = (ushort*)(ws + OFF_XHT);
  ushort* Bbf     = (ushort*)(ws + OFF_BBF);
  ushort* Cbf     = (ushort*)(ws + OFF_CBF);
  ushort* BTbf    = (ushort*)(ws + OFF_BTBF);
  float*  dAcs    = ws + OFF_DA;
  float*  CBb     = ws + OFF_CB;
  ushort* statesT = (ushort*)(ws + OFF_ST);
  ushort* prevP   = (ushort*)(ws + OFF_PREV);
  ushort* o768bf  = (ushort*)(ws + OFF_O768);
  ushort* WsxT    = (ushort*)(ws + OFF_WSXT);
  ushort* WbcdtT  = (ushort*)(ws + OFF_WBCT);
  ushort* WoutT   = (ushort*)(ws + OFF_WOUT);
  ushort* Ubf     = (ushort*)(ws + OFF_UBF);
  ushort* UCbf    = (ushort*)(ws + OFF_UCBF);
  float*  bc_pre  = ws + OFF_BCP;
  float*  Ybuf    = ws + OFF_Y;

  // prep: casts + weight transposes
  k_cast_u<<<dim3(768, 2), 256, 0, stream>>>(u1, u2, u2c1, u1c2, Ubf, UCbf);
  k_wtransp<<<dim3(16, 6), 256, 0, stream>>>(W_skip, WsxT, 1024, 384);
  k_wtransp<<<dim3(8, 6),  256, 0, stream>>>(W_xs, WsxT + (size_t)1024 * 384, 512, 384);
  k_wtransp<<<dim3(5, 6),  256, 0, stream>>>(W_bcdt, WbcdtT, 264, 384);
  k_wtransp<<<dim3(6, 12), 256, 0, stream>>>(W_out, WoutT, 384, 768);
  // input GEMMs (MFMA)
  gemm_bf16<<<dim3(12, 16), 256, 0, stream>>>(Ubf, WsxT, skipxs, 2048, 1536, 384);
  gemm_bf16<<<dim3(3, 16),  256, 0, stream>>>(UCbf, WbcdtT, bc_pre, 2048, 264, 384);
  // conv + gathers
  k_conv<<<dim3(1024, 2), 256, 0, stream>>>(skipxs, bc_pre, cxw, cxb, cbw, cbb, xbcT);
  k_gather_x2<<<dim3(16, 32, 2), 256, 0, stream>>>(xbcT, dt_b, XhT);
  k_gather_bc<<<dim3(1024, 4, 2), 128, 0, stream>>>(xbcT, dt_b, A_logs, Bbf, Cbf, dAcs);
  k_transp<<<dim3(16, 8, 2), 256, 0, stream>>>(Bbf, BTbf);
  k_cumsum<<<dim3(4, 32, 2), 256, 0, stream>>>(dAcs);
  // scan core (MFMA)
  k_cb_mfma<<<dim3(4, 4, 8), 256, 0, stream>>>(Cbf, Bbf, CBb);
  k_states_mfma<<<dim3(4, 32, 8), 256, 0, stream>>>(BTbf, XhT, dAcs, statesT);
  k_scan2<<<dim3(8, 32, 2), 256, 0, stream>>>(statesT, dAcs, prevP);
  k_y_mfma<<<dim3(2, 32, 8), 256, 0, stream>>>(CBb, XhT, Cbf, prevP, dAcs, Ybuf);
  // epilogue
  k_combine<<<dim3(1024, 2), 256, 0, stream>>>(Ybuf, xbcT, skipxs, Ds, normw, o768bf);
  gemm_bf16<<<dim3(3, 16), 256, 0, stream>>>(o768bf, WoutT, out, 2048, 384, 768);
}

// Round 6
// 171.962 us; speedup vs baseline: 3.2736x; 1.0833x over previous
//
#include <hip/hip_runtime.h>
#include <hip/hip_bf16.h>
#include <cstddef>

// ---------------- problem constants ----------------
#define LSEQ   1024
#define DM     384
#define DSSM   512
#define NSTATE 512      // K * D_STATE (shared across heads in the reference einsums)
#define HK     32       // K * NHEADS combined heads
#define HD     64       // head dim
#define CHUNKSZ 256
#define NC     4
#define CBCDT  264
#define CTOT   776      // 512 + 264
#define DMLP   256

typedef __attribute__((ext_vector_type(8))) short short8;
typedef __attribute__((ext_vector_type(4))) float f32x4;

__device__ __forceinline__ float siluf(float x)    { return x / (1.f + expf(-x)); }
__device__ __forceinline__ float softplusf(float x){ return fmaxf(x, 0.f) + log1pf(expf(-fabsf(x))); }

__device__ __forceinline__ ushort f2bf(float f) {
  union { float f; unsigned u; } v; v.f = f;
  unsigned r = v.u + 0x7fffu + ((v.u >> 16) & 1u);
  return (ushort)(r >> 16);
}
__device__ __forceinline__ float bf2f(ushort h) {
  union { unsigned u; float f; } v; v.u = ((unsigned)h) << 16;
  return v.f;
}

// direction k, sequence pos l -> row-major spatial index m (32x32 grid)
__device__ __forceinline__ int dir_src(int k, int l) {
  switch (k) {
    case 0:  return l;
    case 1:  return ((l & 31) << 5) | (l >> 5);
    case 2:  return 1023 - l;
    default: { int lr = 1023 - l; return ((lr & 31) << 5) | (lr >> 5); }
  }
}

// ---------------- fused prep: cast u/uc -> bf16, weight transpose-casts ----------------
// grid (1782): [0,1536) cast, [1536,1782) wtransp tasks
__global__ __launch_bounds__(256) void k_prep(
    const float* __restrict__ u1, const float* __restrict__ u2,
    const float* __restrict__ uc1, const float* __restrict__ uc2,
    const float* __restrict__ W_skip, const float* __restrict__ W_xs,
    const float* __restrict__ W_bcdt, const float* __restrict__ W_out,
    ushort* __restrict__ Ubf, ushort* __restrict__ UCbf,
    ushort* __restrict__ WsxT, ushort* __restrict__ WbcdtT, ushort* __restrict__ WoutT)
{
  __shared__ __align__(16) ushort T[64 * 72];
  int bid = blockIdx.x;
  const int t = threadIdx.x;
  if (bid < 1536) {
    const int uc = bid >= 768;
    const int base = uc ? bid - 768 : bid;        // FIX: 768 is not pow2, no & mask
    const float* s0 = uc ? uc1 : u1;
    const float* s1 = uc ? uc2 : u2;
    ushort* dst = uc ? UCbf : Ubf;
    const int i = (base * 256 + t) * 4;
    float4 v = (i < 393216) ? *(const float4*)(s0 + i) : *(const float4*)(s1 + i - 393216);
    ushort o[4] = { f2bf(v.x), f2bf(v.y), f2bf(v.z), f2bf(v.w) };
    *(uint2*)(dst + i) = *(const uint2*)o;
    return;
  }
  bid -= 1536;
  const float* src; ushort* dst; int N, ldd, nbx;
  if (bid < 96)        {            src = W_skip; dst = WsxT;                     N = 1024; ldd = 384; nbx = 16; }
  else if (bid < 144)  { bid -= 96; src = W_xs;   dst = WsxT + (size_t)1024*384;  N = 512;  ldd = 384; nbx = 8; }
  else if (bid < 174)  { bid -= 144; src = W_bcdt; dst = WbcdtT;                  N = 264;  ldd = 384; nbx = 5; }
  else                 { bid -= 174; src = W_out;  dst = WoutT;                   N = 384;  ldd = 768; nbx = 6; }
  const int n0 = (bid % nbx) * 64, k0 = (bid / nbx) * 64;
  const int rk = t >> 2, q = t & 3;
  const int k = k0 + rk;
  const float* srow = src + (size_t)k * N + n0 + q * 16;
#pragma unroll
  for (int i = 0; i < 16; ++i) {
    int n = n0 + q * 16 + i;
    T[(q * 16 + i) * 72 + rk] = (n < N) ? f2bf(srow[i]) : (ushort)0;
  }
  __syncthreads();
  int n = n0 + rk;
  if (n < N) {
    ushort* d = dst + (size_t)n * ldd + k0 + q * 16;
    *(uint4*)d       = *(const uint4*)&T[rk * 72 + q * 16];
    *(uint4*)(d + 8) = *(const uint4*)&T[rk * 72 + q * 16 + 8];
  }
}

// ---------------- bf16 MFMA GEMM: C[M][N] f32 = A[M][K] * BT[N][K], pipelined K-step 64 ----------------
__global__ __launch_bounds__(256) void gemm_bf16(
    const ushort* __restrict__ A, const ushort* __restrict__ BT,
    float* __restrict__ C, int M, int N, int K)
{
  __shared__ __align__(16) ushort As[128 * 72];
  __shared__ __align__(16) ushort Bs[128 * 72];
  const int n0 = blockIdx.x * 128, m0 = blockIdx.y * 128;
  const int t = threadIdx.x, lane = t & 63, wv = t >> 6;
  const int wm = wv & 1, wn = wv >> 1;
  const int lrow = lane & 15, lk8 = (lane >> 4) * 8;
  const int rowL = t >> 1, cL = (t & 1) * 32;
  const ushort* pa_src = A + (size_t)(m0 + rowL) * K + cL;
  const int nB = n0 + rowL;
  const ushort* pb_src = BT + (size_t)nB * K + cL;
  const bool bval = (nB < N);
  uint4 pa[4], pb[4];
#define GISSUE(k0) do { \
    pa[0] = *(const uint4*)(pa_src + (k0));      pa[1] = *(const uint4*)(pa_src + (k0) + 8); \
    pa[2] = *(const uint4*)(pa_src + (k0) + 16); pa[3] = *(const uint4*)(pa_src + (k0) + 24); \
    if (bval) { \
      pb[0] = *(const uint4*)(pb_src + (k0));      pb[1] = *(const uint4*)(pb_src + (k0) + 8); \
      pb[2] = *(const uint4*)(pb_src + (k0) + 16); pb[3] = *(const uint4*)(pb_src + (k0) + 24); \
    } else { uint4 z = {0,0,0,0}; pb[0]=z; pb[1]=z; pb[2]=z; pb[3]=z; } \
  } while(0)
  GISSUE(0);
  f32x4 acc[4][4] = {};
  for (int k0 = 0; k0 < K; k0 += 64) {
#pragma unroll
    for (int q2 = 0; q2 < 4; ++q2) *(uint4*)&As[rowL * 72 + cL + q2 * 8] = pa[q2];
#pragma unroll
    for (int q2 = 0; q2 < 4; ++q2) *(uint4*)&Bs[rowL * 72 + cL + q2 * 8] = pb[q2];
    __syncthreads();
    if (k0 + 64 < K) GISSUE(k0 + 64);
#pragma unroll
    for (int sub = 0; sub < 2; ++sub) {
      const int ko = lk8 + sub * 32;
      short8 a[4], b[4];
#pragma unroll
      for (int f = 0; f < 4; ++f) {
        a[f] = *(const short8*)&As[(wm * 64 + 16 * f + lrow) * 72 + ko];
        b[f] = *(const short8*)&Bs[(wn * 64 + 16 * f + lrow) * 72 + ko];
      }
#pragma unroll
      for (int fi = 0; fi < 4; ++fi)
#pragma unroll
        for (int fj = 0; fj < 4; ++fj)
          acc[fi][fj] = __builtin_amdgcn_mfma_f32_16x16x32_bf16(a[fi], b[fj], acc[fi][fj], 0, 0, 0);
    }
    __syncthreads();
  }
#pragma unroll
  for (int fi = 0; fi < 4; ++fi) {
    int row0 = m0 + wm * 64 + 16 * fi + (lane >> 4) * 4;
#pragma unroll
    for (int fj = 0; fj < 4; ++fj) {
      int col = n0 + wn * 64 + 16 * fj + lrow;
      if (col < N)
#pragma unroll
        for (int rr = 0; rr < 4; ++rr)
          C[(size_t)(row0 + rr) * N + col] = acc[fi][fj][rr];
    }
  }
}

// ---------------- depthwise 3x3 conv + bias + SiLU; writes xbcT[s][m][c] ----------------
__global__ __launch_bounds__(256) void k_conv(
    const float* __restrict__ skipxs, const float* __restrict__ bc_pre,
    const float* __restrict__ wxs, const float* __restrict__ bxs,
    const float* __restrict__ wbc, const float* __restrict__ bbc,
    float* __restrict__ xbcT)
{
  const int m = blockIdx.x, s = blockIdx.y;
  const int h = m >> 5, w = m & 31;
  const float* xp = skipxs + (size_t)s * LSEQ * 1536 + 1024;   // xs part, stride 1536
  const float* bp = bc_pre + (size_t)s * LSEQ * CBCDT;
  for (int c = threadIdx.x; c < CTOT; c += 256) {
    const float* src; int stride; const float* wt; float bias;
    if (c < DSSM) { src = xp + c; stride = 1536; wt = wxs + (size_t)c * 9; bias = bxs[c]; }
    else { int cb = c - DSSM; src = bp + cb; stride = CBCDT; wt = wbc + (size_t)cb * 9; bias = bbc[cb]; }
    float acc = bias;
#pragma unroll
    for (int dh = -1; dh <= 1; ++dh) {
      int h2 = h + dh; if (h2 < 0 || h2 > 31) continue;
#pragma unroll
      for (int dw = -1; dw <= 1; ++dw) {
        int w2 = w + dw; if (w2 < 0 || w2 > 31) continue;
        acc += src[(size_t)(h2 * 32 + w2) * stride] * wt[(dh + 1) * 3 + (dw + 1)];
      }
    }
    xbcT[((size_t)s * LSEQ + m) * CTOT + c] = siluf(acc);
  }
}

// ---------------- gather x*dt (bf16) into XhT[s][kh][p=64][l=1024] via LDS transpose ----------------
__global__ __launch_bounds__(256) void k_gather_x2(
    const float* __restrict__ xbcT, const float* __restrict__ dt_bias,
    ushort* __restrict__ XhT)
{
  __shared__ __align__(16) ushort T[64 * 72];
  const int lt = blockIdx.x, kh = blockIdx.y, s = blockIdx.z;
  const int k = kh >> 3, hh = kh & 7;
  const int t = threadIdx.x;
  const int r = t >> 2, q = t & 3;
  const int l = lt * 64 + r;
  const int m = dir_src(k, l);
  const float* row = xbcT + ((size_t)s * LSEQ + m) * CTOT;
  float dtv = softplusf(row[768 + hh] + dt_bias[kh]);
  const float* xp = row + hh * 64 + q * 16;
#pragma unroll
  for (int i = 0; i < 16; ++i)
    T[(q * 16 + i) * 72 + r] = f2bf(xp[i] * dtv);
  __syncthreads();
  ushort* dst = XhT + (((size_t)s * HK + kh) * HD + r) * LSEQ + lt * 64 + q * 16;
  *(uint4*)dst       = *(const uint4*)&T[r * 72 + q * 16];
  *(uint4*)(dst + 8) = *(const uint4*)&T[r * 72 + q * 16 + 8];
}

// ---------------- gather B/C (bf16) + dA ----------------
__global__ __launch_bounds__(128) void k_gather_bc(
    const float* __restrict__ xbcT, const float* __restrict__ dt_bias,
    const float* __restrict__ A_logs,
    ushort* __restrict__ Bbf, ushort* __restrict__ Cbf, float* __restrict__ dAbuf)
{
  const int l = blockIdx.x, k = blockIdx.y, s = blockIdx.z;
  const int n = threadIdx.x;
  const int m = dir_src(k, l);
  const float* row = xbcT + ((size_t)s * LSEQ + m) * CTOT;
  Bbf[((size_t)s * LSEQ + l) * NSTATE + k * 128 + n] = f2bf(row[512 + n]);
  Cbf[((size_t)s * LSEQ + l) * NSTATE + k * 128 + n] = f2bf(row[640 + n]);
  if (n < 8) {
    int kh = k * 8 + n;
    float dtv = softplusf(row[768 + n] + dt_bias[kh]);
    dAbuf[((size_t)s * HK + kh) * LSEQ + l] = dtv * (-expf(A_logs[kh]));
  }
}

// ---------------- transpose Bmat_bf [l][n] -> BmatT_bf [n][l] ----------------
__global__ __launch_bounds__(256) void k_transp(
    const ushort* __restrict__ Bbf, ushort* __restrict__ BT)
{
  __shared__ __align__(16) ushort T[64 * 72];
  const int lt = blockIdx.x, nt = blockIdx.y, s = blockIdx.z;
  const int t = threadIdx.x, r = t >> 2, q = t & 3;
  const ushort* src = Bbf + ((size_t)s * LSEQ + lt * 64 + r) * NSTATE + nt * 64 + q * 16;
  ushort tmp[16];
  *(uint4*)tmp       = *(const uint4*)src;
  *(uint4*)(tmp + 8) = *(const uint4*)(src + 8);
#pragma unroll
  for (int i = 0; i < 16; ++i) T[(q * 16 + i) * 72 + r] = tmp[i];
  __syncthreads();
  ushort* dst = BT + ((size_t)s * NSTATE + nt * 64 + r) * LSEQ + lt * 64 + q * 16;
  *(uint4*)dst       = *(const uint4*)&T[r * 72 + q * 16];
  *(uint4*)(dst + 8) = *(const uint4*)&T[r * 72 + q * 16 + 8];
}

// ---------------- inclusive cumsum of dA within each chunk ----------------
__global__ __launch_bounds__(256) void k_cumsum(float* __restrict__ dAbuf)
{
  __shared__ float buf[CHUNKSZ];
  const int z = blockIdx.x, kh = blockIdx.y, s = blockIdx.z, t = threadIdx.x;
  float* p = dAbuf + ((size_t)s * HK + kh) * LSEQ + z * CHUNKSZ;
  buf[t] = p[t];
  __syncthreads();
  for (int off = 1; off < CHUNKSZ; off <<= 1) {
    float add = (t >= off) ? buf[t - off] : 0.f;
    __syncthreads();
    buf[t] += add;
    __syncthreads();
  }
  p[t] = buf[t];
}

// ---------------- CB[s][z] = Cr * Br^T (MFMA, pipelined, bf16 out) ----------------
__global__ __launch_bounds__(256) void k_cb_mfma(
    const ushort* __restrict__ Cbf, const ushort* __restrict__ Bbf,
    ushort* __restrict__ CBbf)
{
  __shared__ __align__(16) ushort As[64 * 72];
  __shared__ __align__(16) ushort Bs[64 * 72];
  const int jt = blockIdx.x, it = blockIdx.y, sz = blockIdx.z, s = sz >> 2, z = sz & 3;
  const int t = threadIdx.x, lane = t & 63, wv = t >> 6;
  const int lrow = lane & 15, lk8 = (lane >> 4) * 8;
  const int r = t >> 2, c0 = (t & 3) * 16;
  const ushort* Ap = Cbf + ((size_t)s * LSEQ + z * CHUNKSZ + it * 64 + r) * NSTATE + c0;
  const ushort* Bp = Bbf + ((size_t)s * LSEQ + z * CHUNKSZ + jt * 64 + r) * NSTATE + c0;
  uint4 qa[2], qb[2];
#define CBISSUE(k0) do { qa[0]=*(const uint4*)(Ap+(k0)); qa[1]=*(const uint4*)(Ap+(k0)+8); \
                         qb[0]=*(const uint4*)(Bp+(k0)); qb[1]=*(const uint4*)(Bp+(k0)+8); } while(0)
  CBISSUE(0);
  f32x4 acc[4] = {};
  for (int k0 = 0; k0 < NSTATE; k0 += 64) {
    *(uint4*)&As[r * 72 + c0] = qa[0]; *(uint4*)&As[r * 72 + c0 + 8] = qa[1];
    *(uint4*)&Bs[r * 72 + c0] = qb[0]; *(uint4*)&Bs[r * 72 + c0 + 8] = qb[1];
    __syncthreads();
    if (k0 + 64 < NSTATE) CBISSUE(k0 + 64);
#pragma unroll
    for (int sub = 0; sub < 2; ++sub) {
      const int ko = lk8 + sub * 32;
      short8 a = *(const short8*)&As[(16 * wv + lrow) * 72 + ko];
#pragma unroll
      for (int fj = 0; fj < 4; ++fj) {
        short8 b = *(const short8*)&Bs[(16 * fj + lrow) * 72 + ko];
        acc[fj] = __builtin_amdgcn_mfma_f32_16x16x32_bf16(a, b, acc[fj], 0, 0, 0);
      }
    }
    __syncthreads();
  }
  ushort* Cp = CBbf + (size_t)sz * CHUNKSZ * CHUNKSZ;
  const int row0 = it * 64 + 16 * wv + (lane >> 4) * 4;
#pragma unroll
  for (int fj = 0; fj < 4; ++fj) {
    int col = jt * 64 + 16 * fj + lrow;
#pragma unroll
    for (int rr = 0; rr < 4; ++rr)
      Cp[(size_t)(row0 + rr) * CHUNKSZ + col] = f2bf(acc[fj][rr]);
  }
}

// ---------------- statesT = B^T(decay*xdt) (MFMA, pipelined) ----------------
// grid (4 nh, 32 kh, 8 sz), block 256; block = 128 n-rows x 64 p
__global__ __launch_bounds__(256) void k_states_mfma(
    const ushort* __restrict__ BT, const ushort* __restrict__ XhT,
    const float* __restrict__ dAcs, ushort* __restrict__ statesT)
{
  __shared__ __align__(16) ushort As[128 * 72];
  __shared__ __align__(16) ushort Bs[64 * 72];
  __shared__ float decay[CHUNKSZ];
  const int nh = blockIdx.x, kh = blockIdx.y, sz = blockIdx.z, s = sz >> 2, z = sz & 3;
  const int t = threadIdx.x, lane = t & 63, wv = t >> 6;
  const int lrow = lane & 15, lk8 = (lane >> 4) * 8;
  const float* dAp = dAcs + ((size_t)s * HK + kh) * LSEQ + z * CHUNKSZ;
  decay[t] = __expf(dAp[CHUNKSZ - 1] - dAp[t]);
  __syncthreads();
  const int rA = t >> 1, cA = (t & 1) * 32;
  const int rB = t >> 2, cB = (t & 3) * 16;
  const ushort* Ap = BT + ((size_t)s * NSTATE + nh * 128 + rA) * LSEQ + z * CHUNKSZ + cA;
  const ushort* Xp = XhT + (((size_t)s * HK + kh) * HD + rB) * LSEQ + z * CHUNKSZ + cB;
  uint4 qa[4], qb[2];
#define STISSUE(k0) do { \
    qa[0]=*(const uint4*)(Ap+(k0));    qa[1]=*(const uint4*)(Ap+(k0)+8); \
    qa[2]=*(const uint4*)(Ap+(k0)+16); qa[3]=*(const uint4*)(Ap+(k0)+24); \
    qb[0]=*(const uint4*)(Xp+(k0));    qb[1]=*(const uint4*)(Xp+(k0)+8); } while(0)
  STISSUE(0);
  f32x4 acc[2][4] = {};
  for (int k0 = 0; k0 < CHUNKSZ; k0 += 64) {
#pragma unroll
    for (int q2 = 0; q2 < 4; ++q2) *(uint4*)&As[rA * 72 + cA + q2 * 8] = qa[q2];
    {
      ushort tmp[16];
      *(uint4*)&tmp[0] = qb[0]; *(uint4*)&tmp[8] = qb[1];
#pragma unroll
      for (int i2 = 0; i2 < 8; ++i2) {
        int c = k0 + cB + 2 * i2;
        unsigned wpk = (unsigned)f2bf(bf2f(tmp[2 * i2]) * decay[c]) |
                       ((unsigned)f2bf(bf2f(tmp[2 * i2 + 1]) * decay[c + 1]) << 16);
        *(unsigned*)&Bs[rB * 72 + cB + 2 * i2] = wpk;
      }
    }
    __syncthreads();
    if (k0 + 64 < CHUNKSZ) STISSUE(k0 + 64);
#pragma unroll
    for (int sub = 0; sub < 2; ++sub) {
      const int ko = lk8 + sub * 32;
      short8 a[2], b[4];
#pragma unroll
      for (int f = 0; f < 2; ++f) a[f] = *(const short8*)&As[(32 * wv + 16 * f + lrow) * 72 + ko];
#pragma unroll
      for (int f = 0; f < 4; ++f) b[f] = *(const short8*)&Bs[(16 * f + lrow) * 72 + ko];
#pragma unroll
      for (int fi = 0; fi < 2; ++fi)
#pragma unroll
        for (int fj = 0; fj < 4; ++fj)
          acc[fi][fj] = __builtin_amdgcn_mfma_f32_16x16x32_bf16(a[fi], b[fj], acc[fi][fj], 0, 0, 0);
    }
    __syncthreads();
  }
  ushort* Sp = statesT + (((size_t)sz * HK + kh) * NSTATE + nh * 128) * HD;
#pragma unroll
  for (int fi = 0; fi < 2; ++fi) {
    int row0 = 32 * wv + 16 * fi + (lane >> 4) * 4;
#pragma unroll
    for (int fj = 0; fj < 4; ++fj) {
      int col = 16 * fj + lrow;
#pragma unroll
      for (int rr = 0; rr < 4; ++rr)
        Sp[(size_t)(row0 + rr) * HD + col] = f2bf(acc[fi][fj][rr]);
    }
  }
}

// ---------------- inter-chunk scan: statesT (bf16) -> prevP[p][n] (bf16) ----------------
__global__ __launch_bounds__(256) void k_scan2(
    const ushort* __restrict__ statesT, const float* __restrict__ dAcs,
    ushort* __restrict__ prevP)
{
  __shared__ __align__(16) ushort T[64 * 72];
  const int nt = blockIdx.x, kh = blockIdx.y, s = blockIdx.z;
  const int t = threadIdx.x, rn = t >> 2, p0 = (t & 3) * 16;
  const float* dA = dAcs + ((size_t)s * HK + kh) * LSEQ;
  float carry[16];
#pragma unroll
  for (int i = 0; i < 16; ++i) carry[i] = 0.f;
  for (int z = 0; z < NC; ++z) {
    int sz = s * 4 + z;
    const ushort* Sp = statesT + (((size_t)sz * HK + kh) * NSTATE + nt * 64 + rn) * HD + p0;
    ushort raw[16];
    *(uint4*)raw       = *(const uint4*)Sp;
    *(uint4*)(raw + 8) = *(const uint4*)(Sp + 8);
#pragma unroll
    for (int i = 0; i < 16; ++i) T[(p0 + i) * 72 + rn] = f2bf(carry[i]);
    float cdec = __expf(dA[z * CHUNKSZ + CHUNKSZ - 1]);
#pragma unroll
    for (int i = 0; i < 16; ++i) carry[i] = carry[i] * cdec + bf2f(raw[i]);
    __syncthreads();
    ushort* dst = prevP + (((size_t)sz * HK + kh) * HD + rn) * NSTATE + nt * 64 + p0;
    *(uint4*)dst       = *(const uint4*)&T[rn * 72 + p0];
    *(uint4*)(dst + 8) = *(const uint4*)&T[rn * 72 + p0 + 8];
    __syncthreads();
  }
}

// ---------------- Y = Ydiag + Yoff (MFMA, pipelined) ----------------
// grid (2 it, 32 kh, 8 sz), block 256; block = 128 rows x 64 cols
__global__ __launch_bounds__(256) void k_y_mfma(
    const ushort* __restrict__ CBbf, const ushort* __restrict__ XhT,
    const ushort* __restrict__ Cbf, const ushort* __restrict__ prevP,
    const float* __restrict__ dAcs, float* __restrict__ Y)
{
  __shared__ __align__(16) ushort As[128 * 72];
  __shared__ __align__(16) ushort Bs[64 * 72];
  __shared__ float seg[CHUNKSZ];
  __shared__ float f2s[CHUNKSZ];   // f2s[j] = exp(seg[slice_base(j)] - seg[j])
  const int it = blockIdx.x, kh = blockIdx.y, sz = blockIdx.z, s = sz >> 2, z = sz & 3;
  const int t = threadIdx.x, lane = t & 63, wv = t >> 6;
  const int lrow = lane & 15, lk8 = (lane >> 4) * 8;
  const int i0 = it * 128;
  const float* dAp = dAcs + ((size_t)s * HK + kh) * LSEQ + z * CHUNKSZ;
  seg[t] = dAp[t];
  __syncthreads();
  f2s[t] = __expf(seg[(t >> 5) << 5] - seg[t]);

  const int rA = t >> 1, cA = (t & 1) * 32;
  const int rB = t >> 2, cB = (t & 3) * 16;
  f32x4 acc[2][4] = {};
  uint4 qa[4], qb[2];

  // ---- phase A: acc = C @ prev^T ----
  const ushort* Cp = Cbf + ((size_t)s * LSEQ + z * CHUNKSZ + i0 + rA) * NSTATE + cA;
  const ushort* Pp = prevP + (((size_t)sz * HK + kh) * HD + rB) * NSTATE + cB;
#define YISSUEA(k0) do { \
    qa[0]=*(const uint4*)(Cp+(k0));    qa[1]=*(const uint4*)(Cp+(k0)+8); \
    qa[2]=*(const uint4*)(Cp+(k0)+16); qa[3]=*(const uint4*)(Cp+(k0)+24); \
    qb[0]=*(const uint4*)(Pp+(k0));    qb[1]=*(const uint4*)(Pp+(k0)+8); } while(0)
  YISSUEA(0);
  for (int k0 = 0; k0 < NSTATE; k0 += 64) {
#pragma unroll
    for (int q2 = 0; q2 < 4; ++q2) *(uint4*)&As[rA * 72 + cA + q2 * 8] = qa[q2];
    *(uint4*)&Bs[rB * 72 + cB] = qb[0]; *(uint4*)&Bs[rB * 72 + cB + 8] = qb[1];
    __syncthreads();
    if (k0 + 64 < NSTATE) YISSUEA(k0 + 64);
#pragma unroll
    for (int sub = 0; sub < 2; ++sub) {
      const int ko = lk8 + sub * 32;
      short8 a[2], b[4];
#pragma unroll
      for (int f = 0; f < 2; ++f) a[f] = *(const short8*)&As[(32 * wv + 16 * f + lrow) * 72 + ko];
#pragma unroll
      for (int f = 0; f < 4; ++f) b[f] = *(const short8*)&Bs[(16 * f + lrow) * 72 + ko];
#pragma unroll
      for (int fi = 0; fi < 2; ++fi)
#pragma unroll
        for (int fj = 0; fj < 4; ++fj)
          acc[fi][fj] = __builtin_amdgcn_mfma_f32_16x16x32_bf16(a[fi], b[fj], acc[fi][fj], 0, 0, 0);
    }
    __syncthreads();
  }

  // ---- scale Yoff rows by e^{seg_i} ----
#pragma unroll
  for (int fi = 0; fi < 2; ++fi) {
    int rloc = 32 * wv + 16 * fi + (lane >> 4) * 4;
#pragma unroll
    for (int rr = 0; rr < 4; ++rr) {
      float e = __expf(seg[i0 + rloc + rr]);
#pragma unroll
      for (int fj = 0; fj < 4; ++fj) acc[fi][fj][rr] *= e;
    }
  }

  // ---- phase B: Ydiag (slice-factored, CB bf16) ----
  const ushort* CBp = CBbf + ((size_t)sz * CHUNKSZ + i0 + rA) * CHUNKSZ;
  const ushort* Xp = XhT + (((size_t)s * HK + kh) * HD + rB) * LSEQ + z * CHUNKSZ + cB;
  const int nktB = 2 * it + 2;
#define YISSUEB(kt) do { const ushort* sa = CBp + (kt) * 64 + cA; \
    qa[0]=*(const uint4*)sa;      qa[1]=*(const uint4*)(sa+8); \
    qa[2]=*(const uint4*)(sa+16); qa[3]=*(const uint4*)(sa+24); \
    qb[0]=*(const uint4*)(Xp+(kt)*64); qb[1]=*(const uint4*)(Xp+(kt)*64+8); } while(0)
  YISSUEB(0);
  for (int kt = 0; kt < nktB; ++kt) {
    {
      const int i = i0 + rA;
      const int jbase = kt * 64 + cA;
      if (i >= jbase) {
        float f1 = __expf(seg[i] - seg[jbase]);
        ushort tmp[32];
        *(uint4*)&tmp[0] = qa[0]; *(uint4*)&tmp[8] = qa[1];
        *(uint4*)&tmp[16] = qa[2]; *(uint4*)&tmp[24] = qa[3];
#pragma unroll
        for (int c = 0; c < 32; c += 2) {
          int j = jbase + c;
          float v0 = (j     <= i) ? bf2f(tmp[c])     * f1 : 0.f;
          float v1 = (j + 1 <= i) ? bf2f(tmp[c + 1]) * f1 : 0.f;
          *(unsigned*)&As[rA * 72 + cA + c] = (unsigned)f2bf(v0) | ((unsigned)f2bf(v1) << 16);
        }
      } else {
        uint4 zz = {0, 0, 0, 0};
#pragma unroll
        for (int q2 = 0; q2 < 4; ++q2) *(uint4*)&As[rA * 72 + cA + q2 * 8] = zz;
      }
    }
    {
      ushort tmp[16];
      *(uint4*)&tmp[0] = qb[0]; *(uint4*)&tmp[8] = qb[1];
#pragma unroll
      for (int i2 = 0; i2 < 8; ++i2) {
        int j = kt * 64 + cB + 2 * i2;
        unsigned wpk = (unsigned)f2bf(bf2f(tmp[2 * i2]) * f2s[j]) |
                       ((unsigned)f2bf(bf2f(tmp[2 * i2 + 1]) * f2s[j + 1]) << 16);
        *(unsigned*)&Bs[rB * 72 + cB + 2 * i2] = wpk;
      }
    }
    __syncthreads();
    if (kt + 1 < nktB) YISSUEB(kt + 1);
#pragma unroll
    for (int sub = 0; sub < 2; ++sub) {
      if (2 * kt + sub <= 4 * it + wv) {
        const int ko = lk8 + sub * 32;
        short8 a[2], b[4];
#pragma unroll
        for (int f = 0; f < 2; ++f) a[f] = *(const short8*)&As[(32 * wv + 16 * f + lrow) * 72 + ko];
#pragma unroll
        for (int f = 0; f < 4; ++f) b[f] = *(const short8*)&Bs[(16 * f + lrow) * 72 + ko];
#pragma unroll
        for (int fi = 0; fi < 2; ++fi)
#pragma unroll
          for (int fj = 0; fj < 4; ++fj)
            acc[fi][fj] = __builtin_amdgcn_mfma_f32_16x16x32_bf16(a[fi], b[fj], acc[fi][fj], 0, 0, 0);
      }
    }
    __syncthreads();
  }

  float* Yp = Y + (((size_t)s * LSEQ + z * CHUNKSZ + i0) * HK + kh) * HD;
#pragma unroll
  for (int fi = 0; fi < 2; ++fi) {
    int row0 = 32 * wv + 16 * fi + (lane >> 4) * 4;
#pragma unroll
    for (int fj = 0; fj < 4; ++fj) {
      int col = 16 * fj + lrow;
#pragma unroll
      for (int rr = 0; rr < 4; ++rr)
        Yp[(size_t)(row0 + rr) * (HK * HD) + col] = acc[fi][fj][rr];
    }
  }
}

// ---------------- combine 4 directions + D*x + gated RMSNorm + MLP half (bf16 out) ----------------
__global__ __launch_bounds__(256) void k_combine(
    const float* __restrict__ Y, const float* __restrict__ xbcT,
    const float* __restrict__ skipxs, const float* __restrict__ Ds,
    const float* __restrict__ normw, ushort* __restrict__ o768bf)
{
  const int m = blockIdx.x, s = blockIdx.y, t = threadIdx.x;
  const int h = m >> 5, w = m & 31;
  const int l0 = m, l1 = (w << 5) | h, l2 = 1023 - m, l3 = 1023 - ((w << 5) | h);
  const float* Yb = Y + (size_t)s * LSEQ * (HK * HD);
  const float* xrow = xbcT + ((size_t)s * LSEQ + m) * CTOT;
  const float* srow = skipxs + ((size_t)s * LSEQ + m) * 1536;

  float g[2];
  float ss = 0.f;
#pragma unroll
  for (int q = 0; q < 2; ++q) {
    int d = t + q * 256;
    int hh = d >> 6, p = d & 63;
    float dsum = Ds[hh] + Ds[hh + 8] + Ds[hh + 16] + Ds[hh + 24];
    float val = Yb[((size_t)l0 * HK + hh) * HD + p]
              + Yb[((size_t)l1 * HK + 8 + hh) * HD + p]
              + Yb[((size_t)l2 * HK + 16 + hh) * HD + p]
              + Yb[((size_t)l3 * HK + 24 + hh) * HD + p]
              + xrow[d] * dsum;
    float zv = srow[512 + d];
    g[q] = val * siluf(zv);
    ss += g[q] * g[q];
  }
  for (int off = 32; off > 0; off >>= 1) ss += __shfl_down(ss, off, 64);
  __shared__ float red[4];
  if ((t & 63) == 0) red[t >> 6] = ss;
  __syncthreads();
  float total = red[0] + red[1] + red[2] + red[3];
  float scale = rsqrtf(total * (1.f / 512.f) + 1e-5f);

  ushort* orow = o768bf + ((size_t)s * LSEQ + m) * 768;
#pragma unroll
  for (int q = 0; q < 2; ++q) {
    int d = t + q * 256;
    orow[256 + d] = f2bf(g[q] * scale * normw[d]);
  }
  float z0 = srow[t], x0 = srow[256 + t];
  orow[t] = f2bf(siluf(z0) * x0);
}

// ---------------- workspace layout (float units) ----------------
constexpr size_t OFF_SKIPXS = 0;                        // 2048*1536 f32 = 3145728
constexpr size_t OFF_XBCT = 3145728;                    // 2*1024*776 f32 = 1589248
constexpr size_t OFF_XHT  = OFF_XBCT + 1589248;         // bf16 2*32*64*1024 -> 2097152 f
constexpr size_t OFF_BBF  = OFF_XHT + 2097152;          // 524288
constexpr size_t OFF_CBF  = OFF_BBF + 524288;           // 524288
constexpr size_t OFF_BTBF = OFF_CBF + 524288;           // 524288
constexpr size_t OFF_DA   = OFF_BTBF + 524288;          // 65536
constexpr size_t OFF_CB   = OFF_DA + 65536;             // 524288 (bf16 CB uses half; keep slot)
constexpr size_t OFF_ST   = OFF_CB + 524288;            // 4194304 (statesT bf16; overlays below)
constexpr size_t OFF_PREV = OFF_ST + 4194304;           // 4194304
constexpr size_t OFF_O768 = OFF_PREV + 4194304;         // bf16 2048*768 -> 786432 f
constexpr size_t OFF_WSXT = OFF_O768 + 786432;          // bf16 1536*384 -> 294912 f
constexpr size_t OFF_WBCT = OFF_WSXT + 294912;          // bf16 264*384 -> 50688 f
constexpr size_t OFF_WOUT = OFF_WBCT + 50688;           // bf16 384*768 -> 147456 f
// overlays in ST region (disjoint lifetimes):
constexpr size_t OFF_UBF  = OFF_ST;                     // bf16 2048*384 -> 393216 f
constexpr size_t OFF_UCBF = OFF_UBF + 393216;           // 393216 f
constexpr size_t OFF_BCP  = OFF_UCBF + 393216;          // f32 2048*264 = 540672
constexpr size_t OFF_Y    = OFF_ST;                     // f32 4194304

extern "C" void kernel_launch(void* const* d_in, const int* in_sizes, int n_in,
                              void* d_out, int out_size, void* d_ws, size_t ws_size,
                              hipStream_t stream)
{
  const float* u1     = (const float*)d_in[0];
  const float* u2     = (const float*)d_in[1];
  const float* u2c1   = (const float*)d_in[2];
  const float* u1c2   = (const float*)d_in[3];
  const float* W_skip = (const float*)d_in[4];
  const float* W_xs   = (const float*)d_in[5];
  const float* W_bcdt = (const float*)d_in[6];
  const float* cxw    = (const float*)d_in[7];
  const float* cxb    = (const float*)d_in[8];
  const float* cbw    = (const float*)d_in[9];
  const float* cbb    = (const float*)d_in[10];
  const float* Ds     = (const float*)d_in[11];
  const float* normw  = (const float*)d_in[12];
  const float* W_out  = (const float*)d_in[13];
  const float* dt_b   = (const float*)d_in[14];
  const float* A_logs = (const float*)d_in[15];
  float* out = (float*)d_out;
  float* ws  = (float*)d_ws;

  float*  skipxs  = ws + OFF_SKIPXS;
  float*  xbcT    = ws + OFF_XBCT;
  ushort* XhT     = (ushort*)(ws + OFF_XHT);
  ushort* Bbf     = (ushort*)(ws + OFF_BBF);
  ushort* Cbf     = (ushort*)(ws + OFF_CBF);
  ushort* BTbf    = (ushort*)(ws + OFF_BTBF);
  float*  dAcs    = ws + OFF_DA;
  ushort* CBbf    = (ushort*)(ws + OFF_CB);
  ushort* statesT = (ushort*)(ws + OFF_ST);
  ushort* prevP   = (ushort*)(ws + OFF_PREV);
  ushort* o768bf  = (ushort*)(ws + OFF_O768);
  ushort* WsxT    = (ushort*)(ws + OFF_WSXT);
  ushort* WbcdtT  = (ushort*)(ws + OFF_WBCT);
  ushort* WoutT   = (ushort*)(ws + OFF_WOUT);
  ushort* Ubf     = (ushort*)(ws + OFF_UBF);
  ushort* UCbf    = (ushort*)(ws + OFF_UCBF);
  float*  bc_pre  = ws + OFF_BCP;
  float*  Ybuf    = ws + OFF_Y;

  // prep (fused cast + weight transposes)
  k_prep<<<dim3(1782), 256, 0, stream>>>(u1, u2, u2c1, u1c2, W_skip, W_xs, W_bcdt, W_out,
                                         Ubf, UCbf, WsxT, WbcdtT, WoutT);
  // input GEMMs (MFMA, pipelined)
  gemm_bf16<<<dim3(12, 16), 256, 0, stream>>>(Ubf, WsxT, skipxs, 2048, 1536, 384);
  gemm_bf16<<<dim3(3, 16),  256, 0, stream>>>(UCbf, WbcdtT, bc_pre, 2048, 264, 384);
  // conv + gathers
  k_conv<<<dim3(1024, 2), 256, 0, stream>>>(skipxs, bc_pre, cxw, cxb, cbw, cbb, xbcT);
  k_gather_x2<<<dim3(16, 32, 2), 256, 0, stream>>>(xbcT, dt_b, XhT);
  k_gather_bc<<<dim3(1024, 4, 2), 128, 0, stream>>>(xbcT, dt_b, A_logs, Bbf, Cbf, dAcs);
  k_transp<<<dim3(16, 8, 2), 256, 0, stream>>>(Bbf, BTbf);
  k_cumsum<<<dim3(4, 32, 2), 256, 0, stream>>>(dAcs);
  // scan core (MFMA, pipelined)
  k_cb_mfma<<<dim3(4, 4, 8), 256, 0, stream>>>(Cbf, Bbf, CBbf);
  k_states_mfma<<<dim3(4, 32, 8), 256, 0, stream>>>(BTbf, XhT, dAcs, statesT);
  k_scan2<<<dim3(8, 32, 2), 256, 0, stream>>>(statesT, dAcs, prevP);
  k_y_mfma<<<dim3(2, 32, 8), 256, 0, stream>>>(CBbf, XhT, Cbf, prevP, dAcs, Ybuf);
  // epilogue
  k_combine<<<dim3(1024, 2), 256, 0, stream>>>(Ybuf, xbcT, skipxs, Ds, normw, o768bf);
  gemm_bf16<<<dim3(3, 16), 256, 0, stream>>>(o768bf, WoutT, out, 2048, 384, 768);
}

// Round 7
// 170.089 us; speedup vs baseline: 3.3096x; 1.0110x over previous
//
#include <hip/hip_runtime.h>
#include <hip/hip_bf16.h>
#include <cstddef>

// ---------------- problem constants ----------------
#define LSEQ   1024
#define DM     384
#define DSSM   512
#define NSTATE 512
#define HK     32
#define HD     64
#define CHUNKSZ 256
#define NC     4
#define CBCDT  264
#define CTOT   776
#define DMLP   256

typedef __attribute__((ext_vector_type(8))) short short8;
typedef __attribute__((ext_vector_type(4))) float f32x4;

__device__ __forceinline__ float siluf(float x)    { return x / (1.f + expf(-x)); }
__device__ __forceinline__ float softplusf(float x){ return fmaxf(x, 0.f) + log1pf(expf(-fabsf(x))); }

__device__ __forceinline__ ushort f2bf(float f) {
  union { float f; unsigned u; } v; v.f = f;
  unsigned r = v.u + 0x7fffu + ((v.u >> 16) & 1u);
  return (ushort)(r >> 16);
}
__device__ __forceinline__ float bf2f(ushort h) {
  union { unsigned u; float f; } v; v.u = ((unsigned)h) << 16;
  return v.f;
}

__device__ __forceinline__ int dir_src(int k, int l) {
  switch (k) {
    case 0:  return l;
    case 1:  return ((l & 31) << 5) | (l >> 5);
    case 2:  return 1023 - l;
    default: { int lr = 1023 - l; return ((lr & 31) << 5) | (lr >> 5); }
  }
}

// ---------------- weight transpose-casts only: grid 246 ----------------
__global__ __launch_bounds__(256) void k_prep(
    const float* __restrict__ W_skip, const float* __restrict__ W_xs,
    const float* __restrict__ W_bcdt, const float* __restrict__ W_out,
    ushort* __restrict__ WsxT, ushort* __restrict__ WbcdtT, ushort* __restrict__ WoutT)
{
  __shared__ __align__(16) ushort T[64 * 72];
  int bid = blockIdx.x;
  const int t = threadIdx.x;
  const float* src; ushort* dst; int N, ldd, nbx;
  if (bid < 96)        {            src = W_skip; dst = WsxT;                     N = 1024; ldd = 384; nbx = 16; }
  else if (bid < 144)  { bid -= 96; src = W_xs;   dst = WsxT + (size_t)1024*384;  N = 512;  ldd = 384; nbx = 8; }
  else if (bid < 174)  { bid -= 144; src = W_bcdt; dst = WbcdtT;                  N = 264;  ldd = 384; nbx = 5; }
  else                 { bid -= 174; src = W_out;  dst = WoutT;                   N = 384;  ldd = 768; nbx = 6; }
  const int n0 = (bid % nbx) * 64, k0 = (bid / nbx) * 64;
  const int rk = t >> 2, q = t & 3;
  const int k = k0 + rk;
  const float* srow = src + (size_t)k * N + n0 + q * 16;
#pragma unroll
  for (int i = 0; i < 16; ++i) {
    int n = n0 + q * 16 + i;
    T[(q * 16 + i) * 72 + rk] = (n < N) ? f2bf(srow[i]) : (ushort)0;
  }
  __syncthreads();
  int n = n0 + rk;
  if (n < N) {
    ushort* d = dst + (size_t)n * ldd + k0 + q * 16;
    *(uint4*)d       = *(const uint4*)&T[rk * 72 + q * 16];
    *(uint4*)(d + 8) = *(const uint4*)&T[rk * 72 + q * 16 + 8];
  }
}

// ---------------- bf16 MFMA GEMM with f32 A (cast in staging): C = A(f32) * BT(bf16) ----------------
// A rows [0,rows0) from A0, rest from A1. grid (ceil(N/128), M/128), block 256.
__global__ __launch_bounds__(256) void gemm_f32a(
    const float* __restrict__ A0, const float* __restrict__ A1, int rows0,
    const ushort* __restrict__ BT, float* __restrict__ C, int M, int N, int K)
{
  __shared__ __align__(16) ushort As[128 * 72];
  __shared__ __align__(16) ushort Bs[128 * 72];
  const int n0 = blockIdx.x * 128, m0 = blockIdx.y * 128;
  const int t = threadIdx.x, lane = t & 63, wv = t >> 6;
  const int wm = wv & 1, wn = wv >> 1;
  const int lrow = lane & 15, lk8 = (lane >> 4) * 8;
  const int rowL = t >> 1, cL = (t & 1) * 32;
  const float* Af = (m0 < rows0) ? (A0 + (size_t)m0 * K) : (A1 + (size_t)(m0 - rows0) * K);
  const float* pa_src = Af + (size_t)rowL * K + cL;
  const int nB = n0 + rowL;
  const ushort* pb_src = BT + (size_t)nB * K + cL;
  const bool bval = (nB < N);
  float4 fa[8]; uint4 pb[4];
#define GAISSUE(k0) do { \
    _Pragma("unroll") for (int q2 = 0; q2 < 8; ++q2) fa[q2] = *(const float4*)(pa_src + (k0) + q2 * 4); \
    if (bval) { \
      pb[0] = *(const uint4*)(pb_src + (k0));      pb[1] = *(const uint4*)(pb_src + (k0) + 8); \
      pb[2] = *(const uint4*)(pb_src + (k0) + 16); pb[3] = *(const uint4*)(pb_src + (k0) + 24); \
    } else { uint4 z = {0,0,0,0}; pb[0]=z; pb[1]=z; pb[2]=z; pb[3]=z; } \
  } while(0)
  GAISSUE(0);
  f32x4 acc[4][4] = {};
  for (int k0 = 0; k0 < K; k0 += 64) {
#pragma unroll
    for (int q2 = 0; q2 < 8; ++q2) {
      ushort o[4] = { f2bf(fa[q2].x), f2bf(fa[q2].y), f2bf(fa[q2].z), f2bf(fa[q2].w) };
      *(uint2*)&As[rowL * 72 + cL + q2 * 4] = *(const uint2*)o;
    }
#pragma unroll
    for (int q2 = 0; q2 < 4; ++q2) *(uint4*)&Bs[rowL * 72 + cL + q2 * 8] = pb[q2];
    __syncthreads();
    if (k0 + 64 < K) GAISSUE(k0 + 64);
#pragma unroll
    for (int sub = 0; sub < 2; ++sub) {
      const int ko = lk8 + sub * 32;
      short8 a[4], b[4];
#pragma unroll
      for (int f = 0; f < 4; ++f) {
        a[f] = *(const short8*)&As[(wm * 64 + 16 * f + lrow) * 72 + ko];
        b[f] = *(const short8*)&Bs[(wn * 64 + 16 * f + lrow) * 72 + ko];
      }
#pragma unroll
      for (int fi = 0; fi < 4; ++fi)
#pragma unroll
        for (int fj = 0; fj < 4; ++fj)
          acc[fi][fj] = __builtin_amdgcn_mfma_f32_16x16x32_bf16(a[fi], b[fj], acc[fi][fj], 0, 0, 0);
    }
    __syncthreads();
  }
#pragma unroll
  for (int fi = 0; fi < 4; ++fi) {
    int row0 = m0 + wm * 64 + 16 * fi + (lane >> 4) * 4;
#pragma unroll
    for (int fj = 0; fj < 4; ++fj) {
      int col = n0 + wn * 64 + 16 * fj + lrow;
      if (col < N)
#pragma unroll
        for (int rr = 0; rr < 4; ++rr)
          C[(size_t)(row0 + rr) * N + col] = acc[fi][fj][rr];
    }
  }
}

// ---------------- bf16 MFMA GEMM (bf16 A): C = A * BT, pipelined K-step 64 ----------------
__global__ __launch_bounds__(256) void gemm_bf16(
    const ushort* __restrict__ A, const ushort* __restrict__ BT,
    float* __restrict__ C, int M, int N, int K)
{
  __shared__ __align__(16) ushort As[128 * 72];
  __shared__ __align__(16) ushort Bs[128 * 72];
  const int n0 = blockIdx.x * 128, m0 = blockIdx.y * 128;
  const int t = threadIdx.x, lane = t & 63, wv = t >> 6;
  const int wm = wv & 1, wn = wv >> 1;
  const int lrow = lane & 15, lk8 = (lane >> 4) * 8;
  const int rowL = t >> 1, cL = (t & 1) * 32;
  const ushort* pa_src = A + (size_t)(m0 + rowL) * K + cL;
  const int nB = n0 + rowL;
  const ushort* pb_src = BT + (size_t)nB * K + cL;
  const bool bval = (nB < N);
  uint4 pa[4], pb[4];
#define GISSUE(k0) do { \
    pa[0] = *(const uint4*)(pa_src + (k0));      pa[1] = *(const uint4*)(pa_src + (k0) + 8); \
    pa[2] = *(const uint4*)(pa_src + (k0) + 16); pa[3] = *(const uint4*)(pa_src + (k0) + 24); \
    if (bval) { \
      pb[0] = *(const uint4*)(pb_src + (k0));      pb[1] = *(const uint4*)(pb_src + (k0) + 8); \
      pb[2] = *(const uint4*)(pb_src + (k0) + 16); pb[3] = *(const uint4*)(pb_src + (k0) + 24); \
    } else { uint4 z = {0,0,0,0}; pb[0]=z; pb[1]=z; pb[2]=z; pb[3]=z; } \
  } while(0)
  GISSUE(0);
  f32x4 acc[4][4] = {};
  for (int k0 = 0; k0 < K; k0 += 64) {
#pragma unroll
    for (int q2 = 0; q2 < 4; ++q2) *(uint4*)&As[rowL * 72 + cL + q2 * 8] = pa[q2];
#pragma unroll
    for (int q2 = 0; q2 < 4; ++q2) *(uint4*)&Bs[rowL * 72 + cL + q2 * 8] = pb[q2];
    __syncthreads();
    if (k0 + 64 < K) GISSUE(k0 + 64);
#pragma unroll
    for (int sub = 0; sub < 2; ++sub) {
      const int ko = lk8 + sub * 32;
      short8 a[4], b[4];
#pragma unroll
      for (int f = 0; f < 4; ++f) {
        a[f] = *(const short8*)&As[(wm * 64 + 16 * f + lrow) * 72 + ko];
        b[f] = *(const short8*)&Bs[(wn * 64 + 16 * f + lrow) * 72 + ko];
      }
#pragma unroll
      for (int fi = 0; fi < 4; ++fi)
#pragma unroll
        for (int fj = 0; fj < 4; ++fj)
          acc[fi][fj] = __builtin_amdgcn_mfma_f32_16x16x32_bf16(a[fi], b[fj], acc[fi][fj], 0, 0, 0);
    }
    __syncthreads();
  }
#pragma unroll
  for (int fi = 0; fi < 4; ++fi) {
    int row0 = m0 + wm * 64 + 16 * fi + (lane >> 4) * 4;
#pragma unroll
    for (int fj = 0; fj < 4; ++fj) {
      int col = n0 + wn * 64 + 16 * fj + lrow;
      if (col < N)
#pragma unroll
        for (int rr = 0; rr < 4; ++rr)
          C[(size_t)(row0 + rr) * N + col] = acc[fi][fj][rr];
    }
  }
}

// ---------------- depthwise 3x3 conv + bias + SiLU; writes xbcT[s][m][c] ----------------
__global__ __launch_bounds__(256) void k_conv(
    const float* __restrict__ skipxs, const float* __restrict__ bc_pre,
    const float* __restrict__ wxs, const float* __restrict__ bxs,
    const float* __restrict__ wbc, const float* __restrict__ bbc,
    float* __restrict__ xbcT)
{
  const int m = blockIdx.x, s = blockIdx.y;
  const int h = m >> 5, w = m & 31;
  const float* xp = skipxs + (size_t)s * LSEQ * 1536 + 1024;
  const float* bp = bc_pre + (size_t)s * LSEQ * CBCDT;
  for (int c = threadIdx.x; c < CTOT; c += 256) {
    const float* src; int stride; const float* wt; float bias;
    if (c < DSSM) { src = xp + c; stride = 1536; wt = wxs + (size_t)c * 9; bias = bxs[c]; }
    else { int cb = c - DSSM; src = bp + cb; stride = CBCDT; wt = wbc + (size_t)cb * 9; bias = bbc[cb]; }
    float acc = bias;
#pragma unroll
    for (int dh = -1; dh <= 1; ++dh) {
      int h2 = h + dh; if (h2 < 0 || h2 > 31) continue;
#pragma unroll
      for (int dw = -1; dw <= 1; ++dw) {
        int w2 = w + dw; if (w2 < 0 || w2 > 31) continue;
        acc += src[(size_t)(h2 * 32 + w2) * stride] * wt[(dh + 1) * 3 + (dw + 1)];
      }
    }
    xbcT[((size_t)s * LSEQ + m) * CTOT + c] = siluf(acc);
  }
}

// ---------------- gather x*dt (bf16) into XhT[s][kh][p][l] via LDS transpose ----------------
__global__ __launch_bounds__(256) void k_gather_x2(
    const float* __restrict__ xbcT, const float* __restrict__ dt_bias,
    ushort* __restrict__ XhT)
{
  __shared__ __align__(16) ushort T[64 * 72];
  const int lt = blockIdx.x, kh = blockIdx.y, s = blockIdx.z;
  const int k = kh >> 3, hh = kh & 7;
  const int t = threadIdx.x;
  const int r = t >> 2, q = t & 3;
  const int l = lt * 64 + r;
  const int m = dir_src(k, l);
  const float* row = xbcT + ((size_t)s * LSEQ + m) * CTOT;
  float dtv = softplusf(row[768 + hh] + dt_bias[kh]);
  const float* xp = row + hh * 64 + q * 16;
#pragma unroll
  for (int i = 0; i < 16; ++i)
    T[(q * 16 + i) * 72 + r] = f2bf(xp[i] * dtv);
  __syncthreads();
  ushort* dst = XhT + (((size_t)s * HK + kh) * HD + r) * LSEQ + lt * 64 + q * 16;
  *(uint4*)dst       = *(const uint4*)&T[r * 72 + q * 16];
  *(uint4*)(dst + 8) = *(const uint4*)&T[r * 72 + q * 16 + 8];
}

// ---------------- gather B/C (bf16) + dA ----------------
__global__ __launch_bounds__(128) void k_gather_bc(
    const float* __restrict__ xbcT, const float* __restrict__ dt_bias,
    const float* __restrict__ A_logs,
    ushort* __restrict__ Bbf, ushort* __restrict__ Cbf, float* __restrict__ dAbuf)
{
  const int l = blockIdx.x, k = blockIdx.y, s = blockIdx.z;
  const int n = threadIdx.x;
  const int m = dir_src(k, l);
  const float* row = xbcT + ((size_t)s * LSEQ + m) * CTOT;
  Bbf[((size_t)s * LSEQ + l) * NSTATE + k * 128 + n] = f2bf(row[512 + n]);
  Cbf[((size_t)s * LSEQ + l) * NSTATE + k * 128 + n] = f2bf(row[640 + n]);
  if (n < 8) {
    int kh = k * 8 + n;
    float dtv = softplusf(row[768 + n] + dt_bias[kh]);
    dAbuf[((size_t)s * HK + kh) * LSEQ + l] = dtv * (-expf(A_logs[kh]));
  }
}

// ---------------- transpose Bmat_bf [l][n] -> BmatT_bf [n][l] ----------------
__global__ __launch_bounds__(256) void k_transp(
    const ushort* __restrict__ Bbf, ushort* __restrict__ BT)
{
  __shared__ __align__(16) ushort T[64 * 72];
  const int lt = blockIdx.x, nt = blockIdx.y, s = blockIdx.z;
  const int t = threadIdx.x, r = t >> 2, q = t & 3;
  const ushort* src = Bbf + ((size_t)s * LSEQ + lt * 64 + r) * NSTATE + nt * 64 + q * 16;
  ushort tmp[16];
  *(uint4*)tmp       = *(const uint4*)src;
  *(uint4*)(tmp + 8) = *(const uint4*)(src + 8);
#pragma unroll
  for (int i = 0; i < 16; ++i) T[(q * 16 + i) * 72 + r] = tmp[i];
  __syncthreads();
  ushort* dst = BT + ((size_t)s * NSTATE + nt * 64 + r) * LSEQ + lt * 64 + q * 16;
  *(uint4*)dst       = *(const uint4*)&T[r * 72 + q * 16];
  *(uint4*)(dst + 8) = *(const uint4*)&T[r * 72 + q * 16 + 8];
}

// ---------------- inclusive cumsum of dA within each chunk ----------------
__global__ __launch_bounds__(256) void k_cumsum(float* __restrict__ dAbuf)
{
  __shared__ float buf[CHUNKSZ];
  const int z = blockIdx.x, kh = blockIdx.y, s = blockIdx.z, t = threadIdx.x;
  float* p = dAbuf + ((size_t)s * HK + kh) * LSEQ + z * CHUNKSZ;
  buf[t] = p[t];
  __syncthreads();
  for (int off = 1; off < CHUNKSZ; off <<= 1) {
    float add = (t >= off) ? buf[t - off] : 0.f;
    __syncthreads();
    buf[t] += add;
    __syncthreads();
  }
  p[t] = buf[t];
}

// ---------------- CB[s][z] = Cr * Br^T (MFMA, pipelined, bf16 out) ----------------
__global__ __launch_bounds__(256) void k_cb_mfma(
    const ushort* __restrict__ Cbf, const ushort* __restrict__ Bbf,
    ushort* __restrict__ CBbf)
{
  __shared__ __align__(16) ushort As[64 * 72];
  __shared__ __align__(16) ushort Bs[64 * 72];
  const int jt = blockIdx.x, it = blockIdx.y, sz = blockIdx.z, s = sz >> 2, z = sz & 3;
  const int t = threadIdx.x, lane = t & 63, wv = t >> 6;
  const int lrow = lane & 15, lk8 = (lane >> 4) * 8;
  const int r = t >> 2, c0 = (t & 3) * 16;
  const ushort* Ap = Cbf + ((size_t)s * LSEQ + z * CHUNKSZ + it * 64 + r) * NSTATE + c0;
  const ushort* Bp = Bbf + ((size_t)s * LSEQ + z * CHUNKSZ + jt * 64 + r) * NSTATE + c0;
  uint4 qa[2], qb[2];
#define CBISSUE(k0) do { qa[0]=*(const uint4*)(Ap+(k0)); qa[1]=*(const uint4*)(Ap+(k0)+8); \
                         qb[0]=*(const uint4*)(Bp+(k0)); qb[1]=*(const uint4*)(Bp+(k0)+8); } while(0)
  CBISSUE(0);
  f32x4 acc[4] = {};
  for (int k0 = 0; k0 < NSTATE; k0 += 64) {
    *(uint4*)&As[r * 72 + c0] = qa[0]; *(uint4*)&As[r * 72 + c0 + 8] = qa[1];
    *(uint4*)&Bs[r * 72 + c0] = qb[0]; *(uint4*)&Bs[r * 72 + c0 + 8] = qb[1];
    __syncthreads();
    if (k0 + 64 < NSTATE) CBISSUE(k0 + 64);
#pragma unroll
    for (int sub = 0; sub < 2; ++sub) {
      const int ko = lk8 + sub * 32;
      short8 a = *(const short8*)&As[(16 * wv + lrow) * 72 + ko];
#pragma unroll
      for (int fj = 0; fj < 4; ++fj) {
        short8 b = *(const short8*)&Bs[(16 * fj + lrow) * 72 + ko];
        acc[fj] = __builtin_amdgcn_mfma_f32_16x16x32_bf16(a, b, acc[fj], 0, 0, 0);
      }
    }
    __syncthreads();
  }
  ushort* Cp = CBbf + (size_t)sz * CHUNKSZ * CHUNKSZ;
  const int row0 = it * 64 + 16 * wv + (lane >> 4) * 4;
#pragma unroll
  for (int fj = 0; fj < 4; ++fj) {
    int col = jt * 64 + 16 * fj + lrow;
#pragma unroll
    for (int rr = 0; rr < 4; ++rr)
      Cp[(size_t)(row0 + rr) * CHUNKSZ + col] = f2bf(acc[fj][rr]);
  }
}

// ---------------- fused states + inter-chunk scan: writes prevP directly ----------------
// grid (8 nh, 32 kh, 2 s), block 256; block = 64 n-rows x 64 p, loops z=0..3 with f32 carry
__global__ __launch_bounds__(256) void k_states_scan(
    const ushort* __restrict__ BT, const ushort* __restrict__ XhT,
    const float* __restrict__ dAcs, ushort* __restrict__ prevP)
{
  __shared__ __align__(16) ushort As[64 * 72];
  __shared__ __align__(16) ushort Bs[64 * 72];
  __shared__ __align__(16) ushort Tr[64 * 72];   // [p][n] transpose staging
  __shared__ float decay[CHUNKSZ];
  const int nh = blockIdx.x, kh = blockIdx.y, s = blockIdx.z;
  const int t = threadIdx.x, lane = t & 63, wv = t >> 6;
  const int lrow = lane & 15, lk8 = (lane >> 4) * 8;
  const int rA = t >> 2, cA = (t & 3) * 16;
  const float* dA = dAcs + ((size_t)s * HK + kh) * LSEQ;
  float carry[4][4];
#pragma unroll
  for (int fj = 0; fj < 4; ++fj)
#pragma unroll
    for (int rr = 0; rr < 4; ++rr) carry[fj][rr] = 0.f;

  for (int z = 0; z < NC; ++z) {
    __syncthreads();   // previous iteration's LDS fully consumed
    const float dlast = dA[z * CHUNKSZ + CHUNKSZ - 1];
    decay[t] = __expf(dlast - dA[z * CHUNKSZ + t]);
    // stage carry (state entering chunk z) transposed into Tr[p][n]
    {
      const int n_base = 16 * wv + (lane >> 4) * 4;
#pragma unroll
      for (int fj = 0; fj < 4; ++fj) {
        const int p = 16 * fj + lrow;
#pragma unroll
        for (int rr = 0; rr < 4; ++rr)
          Tr[p * 72 + n_base + rr] = f2bf(carry[fj][rr]);
      }
    }
    __syncthreads();
    // write prevP for sz = s*4+z : [p][NSTATE], 64 p rows x 64 n cols of this block
    {
      const int sz = s * 4 + z;
      ushort* dst = prevP + (((size_t)sz * HK + kh) * HD + rA) * NSTATE + nh * 64 + cA;
      *(uint4*)dst       = *(const uint4*)&Tr[rA * 72 + cA];
      *(uint4*)(dst + 8) = *(const uint4*)&Tr[rA * 72 + cA + 8];
    }
    // compute chunk state via MFMA (pipelined K=256)
    const ushort* Ap = BT + ((size_t)s * NSTATE + nh * 64 + rA) * LSEQ + z * CHUNKSZ + cA;
    const ushort* Xp = XhT + (((size_t)s * HK + kh) * HD + rA) * LSEQ + z * CHUNKSZ + cA;
    uint4 qa[2], qb[2];
#define SSISSUE(k0) do { qa[0]=*(const uint4*)(Ap+(k0)); qa[1]=*(const uint4*)(Ap+(k0)+8); \
                         qb[0]=*(const uint4*)(Xp+(k0)); qb[1]=*(const uint4*)(Xp+(k0)+8); } while(0)
    SSISSUE(0);
    f32x4 acc[4] = {};
    for (int k0 = 0; k0 < CHUNKSZ; k0 += 64) {
      *(uint4*)&As[rA * 72 + cA] = qa[0]; *(uint4*)&As[rA * 72 + cA + 8] = qa[1];
      {
        ushort tmp[16];
        *(uint4*)&tmp[0] = qb[0]; *(uint4*)&tmp[8] = qb[1];
#pragma unroll
        for (int i2 = 0; i2 < 8; ++i2) {
          int c = k0 + cA + 2 * i2;
          unsigned wpk = (unsigned)f2bf(bf2f(tmp[2 * i2]) * decay[c]) |
                         ((unsigned)f2bf(bf2f(tmp[2 * i2 + 1]) * decay[c + 1]) << 16);
          *(unsigned*)&Bs[rA * 72 + cA + 2 * i2] = wpk;
        }
      }
      __syncthreads();
      if (k0 + 64 < CHUNKSZ) SSISSUE(k0 + 64);
#pragma unroll
      for (int sub = 0; sub < 2; ++sub) {
        const int ko = lk8 + sub * 32;
        short8 a = *(const short8*)&As[(16 * wv + lrow) * 72 + ko];
#pragma unroll
        for (int fj = 0; fj < 4; ++fj) {
          short8 b = *(const short8*)&Bs[(16 * fj + lrow) * 72 + ko];
          acc[fj] = __builtin_amdgcn_mfma_f32_16x16x32_bf16(a, b, acc[fj], 0, 0, 0);
        }
      }
      __syncthreads();
    }
    // carry = carry * exp(dlast) + chunk_state
    const float cdec = __expf(dlast);
#pragma unroll
    for (int fj = 0; fj < 4; ++fj)
#pragma unroll
      for (int rr = 0; rr < 4; ++rr)
        carry[fj][rr] = carry[fj][rr] * cdec + acc[fj][rr];
  }
}

// ---------------- Y = Ydiag + Yoff (MFMA, pipelined, bf16 out) ----------------
// grid (2 it, 32 kh, 8 sz), block 256
__global__ __launch_bounds__(256) void k_y_mfma(
    const ushort* __restrict__ CBbf, const ushort* __restrict__ XhT,
    const ushort* __restrict__ Cbf, const ushort* __restrict__ prevP,
    const float* __restrict__ dAcs, ushort* __restrict__ Ybf)
{
  __shared__ __align__(16) ushort As[128 * 72];
  __shared__ __align__(16) ushort Bs[64 * 72];
  __shared__ float seg[CHUNKSZ];
  __shared__ float f2s[CHUNKSZ];
  const int it = blockIdx.x, kh = blockIdx.y, sz = blockIdx.z, s = sz >> 2, z = sz & 3;
  const int t = threadIdx.x, lane = t & 63, wv = t >> 6;
  const int lrow = lane & 15, lk8 = (lane >> 4) * 8;
  const int i0 = it * 128;
  const float* dAp = dAcs + ((size_t)s * HK + kh) * LSEQ + z * CHUNKSZ;
  seg[t] = dAp[t];
  __syncthreads();
  f2s[t] = __expf(seg[(t >> 5) << 5] - seg[t]);

  const int rA = t >> 1, cA = (t & 1) * 32;
  const int rB = t >> 2, cB = (t & 3) * 16;
  f32x4 acc[2][4] = {};
  uint4 qa[4], qb[2];

  // phase A: acc = C @ prev^T
  const ushort* Cp = Cbf + ((size_t)s * LSEQ + z * CHUNKSZ + i0 + rA) * NSTATE + cA;
  const ushort* Pp = prevP + (((size_t)sz * HK + kh) * HD + rB) * NSTATE + cB;
#define YISSUEA(k0) do { \
    qa[0]=*(const uint4*)(Cp+(k0));    qa[1]=*(const uint4*)(Cp+(k0)+8); \
    qa[2]=*(const uint4*)(Cp+(k0)+16); qa[3]=*(const uint4*)(Cp+(k0)+24); \
    qb[0]=*(const uint4*)(Pp+(k0));    qb[1]=*(const uint4*)(Pp+(k0)+8); } while(0)
  YISSUEA(0);
  for (int k0 = 0; k0 < NSTATE; k0 += 64) {
#pragma unroll
    for (int q2 = 0; q2 < 4; ++q2) *(uint4*)&As[rA * 72 + cA + q2 * 8] = qa[q2];
    *(uint4*)&Bs[rB * 72 + cB] = qb[0]; *(uint4*)&Bs[rB * 72 + cB + 8] = qb[1];
    __syncthreads();
    if (k0 + 64 < NSTATE) YISSUEA(k0 + 64);
#pragma unroll
    for (int sub = 0; sub < 2; ++sub) {
      const int ko = lk8 + sub * 32;
      short8 a[2], b[4];
#pragma unroll
      for (int f = 0; f < 2; ++f) a[f] = *(const short8*)&As[(32 * wv + 16 * f + lrow) * 72 + ko];
#pragma unroll
      for (int f = 0; f < 4; ++f) b[f] = *(const short8*)&Bs[(16 * f + lrow) * 72 + ko];
#pragma unroll
      for (int fi = 0; fi < 2; ++fi)
#pragma unroll
        for (int fj = 0; fj < 4; ++fj)
          acc[fi][fj] = __builtin_amdgcn_mfma_f32_16x16x32_bf16(a[fi], b[fj], acc[fi][fj], 0, 0, 0);
    }
    __syncthreads();
  }

  // scale Yoff rows by e^{seg_i}
#pragma unroll
  for (int fi = 0; fi < 2; ++fi) {
    int rloc = 32 * wv + 16 * fi + (lane >> 4) * 4;
#pragma unroll
    for (int rr = 0; rr < 4; ++rr) {
      float e = __expf(seg[i0 + rloc + rr]);
#pragma unroll
      for (int fj = 0; fj < 4; ++fj) acc[fi][fj][rr] *= e;
    }
  }

  // phase B: Ydiag (slice-factored, CB bf16)
  const ushort* CBp = CBbf + ((size_t)sz * CHUNKSZ + i0 + rA) * CHUNKSZ;
  const ushort* Xp = XhT + (((size_t)s * HK + kh) * HD + rB) * LSEQ + z * CHUNKSZ + cB;
  const int nktB = 2 * it + 2;
#define YISSUEB(kt) do { const ushort* sa = CBp + (kt) * 64 + cA; \
    qa[0]=*(const uint4*)sa;      qa[1]=*(const uint4*)(sa+8); \
    qa[2]=*(const uint4*)(sa+16); qa[3]=*(const uint4*)(sa+24); \
    qb[0]=*(const uint4*)(Xp+(kt)*64); qb[1]=*(const uint4*)(Xp+(kt)*64+8); } while(0)
  YISSUEB(0);
  for (int kt = 0; kt < nktB; ++kt) {
    {
      const int i = i0 + rA;
      const int jbase = kt * 64 + cA;
      if (i >= jbase) {
        float f1 = __expf(seg[i] - seg[jbase]);
        ushort tmp[32];
        *(uint4*)&tmp[0] = qa[0]; *(uint4*)&tmp[8] = qa[1];
        *(uint4*)&tmp[16] = qa[2]; *(uint4*)&tmp[24] = qa[3];
#pragma unroll
        for (int c = 0; c < 32; c += 2) {
          int j = jbase + c;
          float v0 = (j     <= i) ? bf2f(tmp[c])     * f1 : 0.f;
          float v1 = (j + 1 <= i) ? bf2f(tmp[c + 1]) * f1 : 0.f;
          *(unsigned*)&As[rA * 72 + cA + c] = (unsigned)f2bf(v0) | ((unsigned)f2bf(v1) << 16);
        }
      } else {
        uint4 zz = {0, 0, 0, 0};
#pragma unroll
        for (int q2 = 0; q2 < 4; ++q2) *(uint4*)&As[rA * 72 + cA + q2 * 8] = zz;
      }
    }
    {
      ushort tmp[16];
      *(uint4*)&tmp[0] = qb[0]; *(uint4*)&tmp[8] = qb[1];
#pragma unroll
      for (int i2 = 0; i2 < 8; ++i2) {
        int j = kt * 64 + cB + 2 * i2;
        unsigned wpk = (unsigned)f2bf(bf2f(tmp[2 * i2]) * f2s[j]) |
                       ((unsigned)f2bf(bf2f(tmp[2 * i2 + 1]) * f2s[j + 1]) << 16);
        *(unsigned*)&Bs[rB * 72 + cB + 2 * i2] = wpk;
      }
    }
    __syncthreads();
    if (kt + 1 < nktB) YISSUEB(kt + 1);
#pragma unroll
    for (int sub = 0; sub < 2; ++sub) {
      if (2 * kt + sub <= 4 * it + wv) {
        const int ko = lk8 + sub * 32;
        short8 a[2], b[4];
#pragma unroll
        for (int f = 0; f < 2; ++f) a[f] = *(const short8*)&As[(32 * wv + 16 * f + lrow) * 72 + ko];
#pragma unroll
        for (int f = 0; f < 4; ++f) b[f] = *(const short8*)&Bs[(16 * f + lrow) * 72 + ko];
#pragma unroll
        for (int fi = 0; fi < 2; ++fi)
#pragma unroll
          for (int fj = 0; fj < 4; ++fj)
            acc[fi][fj] = __builtin_amdgcn_mfma_f32_16x16x32_bf16(a[fi], b[fj], acc[fi][fj], 0, 0, 0);
      }
    }
    __syncthreads();
  }

  ushort* Yp = Ybf + (((size_t)s * LSEQ + z * CHUNKSZ + i0) * HK + kh) * HD;
#pragma unroll
  for (int fi = 0; fi < 2; ++fi) {
    int row0 = 32 * wv + 16 * fi + (lane >> 4) * 4;
#pragma unroll
    for (int fj = 0; fj < 4; ++fj) {
      int col = 16 * fj + lrow;
#pragma unroll
      for (int rr = 0; rr < 4; ++rr)
        Yp[(size_t)(row0 + rr) * (HK * HD) + col] = f2bf(acc[fi][fj][rr]);
    }
  }
}

// ---------------- combine 4 directions + D*x + gated RMSNorm + MLP half (bf16 out) ----------------
__global__ __launch_bounds__(256) void k_combine(
    const ushort* __restrict__ Ybf, const float* __restrict__ xbcT,
    const float* __restrict__ skipxs, const float* __restrict__ Ds,
    const float* __restrict__ normw, ushort* __restrict__ o768bf)
{
  const int m = blockIdx.x, s = blockIdx.y, t = threadIdx.x;
  const int h = m >> 5, w = m & 31;
  const int l0 = m, l1 = (w << 5) | h, l2 = 1023 - m, l3 = 1023 - ((w << 5) | h);
  const ushort* Yb = Ybf + (size_t)s * LSEQ * (HK * HD);
  const float* xrow = xbcT + ((size_t)s * LSEQ + m) * CTOT;
  const float* srow = skipxs + ((size_t)s * LSEQ + m) * 1536;

  float g[2];
  float ss = 0.f;
#pragma unroll
  for (int q = 0; q < 2; ++q) {
    int d = t + q * 256;
    int hh = d >> 6, p = d & 63;
    float dsum = Ds[hh] + Ds[hh + 8] + Ds[hh + 16] + Ds[hh + 24];
    float val = bf2f(Yb[((size_t)l0 * HK + hh) * HD + p])
              + bf2f(Yb[((size_t)l1 * HK + 8 + hh) * HD + p])
              + bf2f(Yb[((size_t)l2 * HK + 16 + hh) * HD + p])
              + bf2f(Yb[((size_t)l3 * HK + 24 + hh) * HD + p])
              + xrow[d] * dsum;
    float zv = srow[512 + d];
    g[q] = val * siluf(zv);
    ss += g[q] * g[q];
  }
  for (int off = 32; off > 0; off >>= 1) ss += __shfl_down(ss, off, 64);
  __shared__ float red[4];
  if ((t & 63) == 0) red[t >> 6] = ss;
  __syncthreads();
  float total = red[0] + red[1] + red[2] + red[3];
  float scale = rsqrtf(total * (1.f / 512.f) + 1e-5f);

  ushort* orow = o768bf + ((size_t)s * LSEQ + m) * 768;
#pragma unroll
  for (int q = 0; q < 2; ++q) {
    int d = t + q * 256;
    orow[256 + d] = f2bf(g[q] * scale * normw[d]);
  }
  float z0 = srow[t], x0 = srow[256 + t];
  orow[t] = f2bf(siluf(z0) * x0);
}

// ---------------- workspace layout (float units) ----------------
constexpr size_t OFF_SKIPXS = 0;                         // 2048*1536 f32 = 3145728
constexpr size_t OFF_XBCT   = 3145728;                   // 1589248
constexpr size_t OFF_XHT    = OFF_XBCT + 1589248;        // bf16 -> 2097152 f
constexpr size_t OFF_BBF    = OFF_XHT + 2097152;         // 524288
constexpr size_t OFF_CBF    = OFF_BBF + 524288;          // 524288
constexpr size_t OFF_BTBF   = OFF_CBF + 524288;          // 524288
constexpr size_t OFF_DA     = OFF_BTBF + 524288;         // 65536
constexpr size_t OFF_CB     = OFF_DA + 65536;            // bf16 8*256*256 -> 262144 f
constexpr size_t OFF_PREV   = OFF_CB + 262144;           // bf16 8*32*64*512 -> 4194304 f
constexpr size_t OFF_Y      = OFF_PREV + 4194304;        // bf16 2048*2048 -> 2097152 f
constexpr size_t OFF_O768   = OFF_Y + 2097152;           // bf16 -> 786432 f
constexpr size_t OFF_WSXT   = OFF_O768 + 786432;         // 294912
constexpr size_t OFF_WBCT   = OFF_WSXT + 294912;         // 50688
constexpr size_t OFF_WOUT   = OFF_WBCT + 50688;          // 147456
// overlay: bc_pre (gemm2 -> conv) in PREV region (prevP written later by k_states_scan)
constexpr size_t OFF_BCP    = OFF_PREV;                  // f32 2048*264 = 540672

extern "C" void kernel_launch(void* const* d_in, const int* in_sizes, int n_in,
                              void* d_out, int out_size, void* d_ws, size_t ws_size,
                              hipStream_t stream)
{
  const float* u1     = (const float*)d_in[0];
  const float* u2     = (const float*)d_in[1];
  const float* u2c1   = (const float*)d_in[2];
  const float* u1c2   = (const float*)d_in[3];
  const float* W_skip = (const float*)d_in[4];
  const float* W_xs   = (const float*)d_in[5];
  const float* W_bcdt = (const float*)d_in[6];
  const float* cxw    = (const float*)d_in[7];
  const float* cxb    = (const float*)d_in[8];
  const float* cbw    = (const float*)d_in[9];
  const float* cbb    = (const float*)d_in[10];
  const float* Ds     = (const float*)d_in[11];
  const float* normw  = (const float*)d_in[12];
  const float* W_out  = (const float*)d_in[13];
  const float* dt_b   = (const float*)d_in[14];
  const float* A_logs = (const float*)d_in[15];
  float* out = (float*)d_out;
  float* ws  = (float*)d_ws;

  float*  skipxs  = ws + OFF_SKIPXS;
  float*  xbcT    = ws + OFF_XBCT;
  ushort* XhT     = (ushort*)(ws + OFF_XHT);
  ushort* Bbf     = (ushort*)(ws + OFF_BBF);
  ushort* Cbf     = (ushort*)(ws + OFF_CBF);
  ushort* BTbf    = (ushort*)(ws + OFF_BTBF);
  float*  dAcs    = ws + OFF_DA;
  ushort* CBbf    = (ushort*)(ws + OFF_CB);
  ushort* prevP   = (ushort*)(ws + OFF_PREV);
  ushort* Ybf     = (ushort*)(ws + OFF_Y);
  ushort* o768bf  = (ushort*)(ws + OFF_O768);
  ushort* WsxT    = (ushort*)(ws + OFF_WSXT);
  ushort* WbcdtT  = (ushort*)(ws + OFF_WBCT);
  ushort* WoutT   = (ushort*)(ws + OFF_WOUT);
  float*  bc_pre  = ws + OFF_BCP;

  // weight transposes
  k_prep<<<dim3(246), 256, 0, stream>>>(W_skip, W_xs, W_bcdt, W_out, WsxT, WbcdtT, WoutT);
  // input GEMMs (f32 A read directly, cast in staging)
  gemm_f32a<<<dim3(12, 16), 256, 0, stream>>>(u1, u2, 1024, WsxT, skipxs, 2048, 1536, 384);
  gemm_f32a<<<dim3(3, 16),  256, 0, stream>>>(u2c1, u1c2, 1024, WbcdtT, bc_pre, 2048, 264, 384);
  // conv + gathers
  k_conv<<<dim3(1024, 2), 256, 0, stream>>>(skipxs, bc_pre, cxw, cxb, cbw, cbb, xbcT);
  k_gather_x2<<<dim3(16, 32, 2), 256, 0, stream>>>(xbcT, dt_b, XhT);
  k_gather_bc<<<dim3(1024, 4, 2), 128, 0, stream>>>(xbcT, dt_b, A_logs, Bbf, Cbf, dAcs);
  k_transp<<<dim3(16, 8, 2), 256, 0, stream>>>(Bbf, BTbf);
  k_cumsum<<<dim3(4, 32, 2), 256, 0, stream>>>(dAcs);
  // scan core
  k_cb_mfma<<<dim3(4, 4, 8), 256, 0, stream>>>(Cbf, Bbf, CBbf);
  k_states_scan<<<dim3(8, 32, 2), 256, 0, stream>>>(BTbf, XhT, dAcs, prevP);
  k_y_mfma<<<dim3(2, 32, 8), 256, 0, stream>>>(CBbf, XhT, Cbf, prevP, dAcs, Ybf);
  // epilogue
  k_combine<<<dim3(1024, 2), 256, 0, stream>>>(Ybf, xbcT, skipxs, Ds, normw, o768bf);
  gemm_bf16<<<dim3(3, 16), 256, 0, stream>>>(o768bf, WoutT, out, 2048, 384, 768);
}

// Round 9
// 129.202 us; speedup vs baseline: 4.3570x; 1.3165x over previous
//
#include <hip/hip_runtime.h>
#include <hip/hip_bf16.h>
#include <cstddef>

// ---------------- problem constants ----------------
#define LSEQ   1024
#define DM     384
#define DSSM   512
#define NSTATE 512
#define HK     32
#define HD     64
#define CHUNKSZ 256
#define NC     4
#define CBCDT  264
#define CTOT   776
#define DMLP   256

typedef __attribute__((ext_vector_type(8))) short short8;
typedef __attribute__((ext_vector_type(4))) float f32x4;

__device__ __forceinline__ float siluf(float x)    { return x / (1.f + expf(-x)); }
__device__ __forceinline__ float softplusf(float x){ return fmaxf(x, 0.f) + log1pf(expf(-fabsf(x))); }

__device__ __forceinline__ ushort f2bf(float f) {
  union { float f; unsigned u; } v; v.f = f;
  unsigned r = v.u + 0x7fffu + ((v.u >> 16) & 1u);
  return (ushort)(r >> 16);
}
__device__ __forceinline__ float bf2f(ushort h) {
  union { unsigned u; float f; } v; v.u = ((unsigned)h) << 16;
  return v.f;
}

__device__ __forceinline__ int dir_src(int k, int l) {
  switch (k) {
    case 0:  return l;
    case 1:  return ((l & 31) << 5) | (l >> 5);
    case 2:  return 1023 - l;
    default: { int lr = 1023 - l; return ((lr & 31) << 5) | (lr >> 5); }
  }
}

// ---------------- weight transpose-casts: grid 246 ----------------
__global__ __launch_bounds__(256) void k_prep(
    const float* __restrict__ W_skip, const float* __restrict__ W_xs,
    const float* __restrict__ W_bcdt, const float* __restrict__ W_out,
    ushort* __restrict__ WsxT, ushort* __restrict__ WbcdtT, ushort* __restrict__ WoutT)
{
  __shared__ __align__(16) ushort T[64 * 72];
  int bid = blockIdx.x;
  const int t = threadIdx.x;
  const float* src; ushort* dst; int N, ldd, nbx;
  if (bid < 96)        {            src = W_skip; dst = WsxT;                     N = 1024; ldd = 384; nbx = 16; }
  else if (bid < 144)  { bid -= 96; src = W_xs;   dst = WsxT + (size_t)1024*384;  N = 512;  ldd = 384; nbx = 8; }
  else if (bid < 174)  { bid -= 144; src = W_bcdt; dst = WbcdtT;                  N = 264;  ldd = 384; nbx = 5; }
  else                 { bid -= 174; src = W_out;  dst = WoutT;                   N = 384;  ldd = 768; nbx = 6; }
  const int n0 = (bid % nbx) * 64, k0 = (bid / nbx) * 64;
  const int rk = t >> 2, q = t & 3;
  const int k = k0 + rk;
  const float* srow = src + (size_t)k * N + n0 + q * 16;
#pragma unroll
  for (int i = 0; i < 16; ++i) {
    int n = n0 + q * 16 + i;
    T[(q * 16 + i) * 72 + rk] = (n < N) ? f2bf(srow[i]) : (ushort)0;
  }
  __syncthreads();
  int n = n0 + rk;
  if (n < N) {
    ushort* d = dst + (size_t)n * ldd + k0 + q * 16;
    *(uint4*)d       = *(const uint4*)&T[rk * 72 + q * 16];
    *(uint4*)(d + 8) = *(const uint4*)&T[rk * 72 + q * 16 + 8];
  }
}

// ---------------- f32-A GEMM body (cast in staging), 128x128 tile ----------------
__device__ __forceinline__ void gemm_f32a_body(
    ushort* As, ushort* Bs,
    const float* __restrict__ A0, const float* __restrict__ A1, int rows0,
    const ushort* __restrict__ BT, float* __restrict__ C, int N, int K)
{
  const int n0 = blockIdx.x * 128, m0 = blockIdx.y * 128;
  const int t = threadIdx.x, lane = t & 63, wv = t >> 6;
  const int wm = wv & 1, wn = wv >> 1;
  const int lrow = lane & 15, lk8 = (lane >> 4) * 8;
  const int rowL = t >> 1, cL = (t & 1) * 32;
  const float* Af = (m0 < rows0) ? (A0 + (size_t)m0 * K) : (A1 + (size_t)(m0 - rows0) * K);
  const float* pa_src = Af + (size_t)rowL * K + cL;
  const int nB = n0 + rowL;
  const ushort* pb_src = BT + (size_t)nB * K + cL;
  const bool bval = (nB < N);
  float4 fa[8]; uint4 pb[4];
#define GAISSUE(k0) do { \
    _Pragma("unroll") for (int q2 = 0; q2 < 8; ++q2) fa[q2] = *(const float4*)(pa_src + (k0) + q2 * 4); \
    if (bval) { \
      pb[0] = *(const uint4*)(pb_src + (k0));      pb[1] = *(const uint4*)(pb_src + (k0) + 8); \
      pb[2] = *(const uint4*)(pb_src + (k0) + 16); pb[3] = *(const uint4*)(pb_src + (k0) + 24); \
    } else { uint4 z = {0,0,0,0}; pb[0]=z; pb[1]=z; pb[2]=z; pb[3]=z; } \
  } while(0)
  GAISSUE(0);
  f32x4 acc[4][4] = {};
  for (int k0 = 0; k0 < K; k0 += 64) {
#pragma unroll
    for (int q2 = 0; q2 < 8; ++q2) {
      ushort o[4] = { f2bf(fa[q2].x), f2bf(fa[q2].y), f2bf(fa[q2].z), f2bf(fa[q2].w) };
      *(uint2*)&As[rowL * 72 + cL + q2 * 4] = *(const uint2*)o;
    }
#pragma unroll
    for (int q2 = 0; q2 < 4; ++q2) *(uint4*)&Bs[rowL * 72 + cL + q2 * 8] = pb[q2];
    __syncthreads();
    if (k0 + 64 < K) GAISSUE(k0 + 64);
#pragma unroll
    for (int sub = 0; sub < 2; ++sub) {
      const int ko = lk8 + sub * 32;
      short8 a[4], b[4];
#pragma unroll
      for (int f = 0; f < 4; ++f) {
        a[f] = *(const short8*)&As[(wm * 64 + 16 * f + lrow) * 72 + ko];
        b[f] = *(const short8*)&Bs[(wn * 64 + 16 * f + lrow) * 72 + ko];
      }
#pragma unroll
      for (int fi = 0; fi < 4; ++fi)
#pragma unroll
        for (int fj = 0; fj < 4; ++fj)
          acc[fi][fj] = __builtin_amdgcn_mfma_f32_16x16x32_bf16(a[fi], b[fj], acc[fi][fj], 0, 0, 0);
    }
    __syncthreads();
  }
#pragma unroll
  for (int fi = 0; fi < 4; ++fi) {
    int row0 = m0 + wm * 64 + 16 * fi + (lane >> 4) * 4;
#pragma unroll
    for (int fj = 0; fj < 4; ++fj) {
      int col = n0 + wn * 64 + 16 * fj + lrow;
      if (col < N)
#pragma unroll
        for (int rr = 0; rr < 4; ++rr)
          C[(size_t)(row0 + rr) * N + col] = acc[fi][fj][rr];
    }
  }
}

// ---------------- fused input GEMMs: z=0 skipxs (12x16), z=1 bcdt (3x16) ----------------
__global__ __launch_bounds__(256) void k_gemm_in(
    const float* __restrict__ u1, const float* __restrict__ u2,
    const float* __restrict__ uc1, const float* __restrict__ uc2,
    const ushort* __restrict__ WsxT, const ushort* __restrict__ WbcdtT,
    float* __restrict__ skipxs, float* __restrict__ bc_pre)
{
  __shared__ __align__(16) ushort As[128 * 72];
  __shared__ __align__(16) ushort Bs[128 * 72];
  if (blockIdx.z == 0) {
    gemm_f32a_body(As, Bs, u1, u2, 1024, WsxT, skipxs, 1536, 384);
  } else {
    if (blockIdx.x >= 3) return;
    gemm_f32a_body(As, Bs, uc1, uc2, 1024, WbcdtT, bc_pre, 264, 384);
  }
}

// ---------------- depthwise 3x3 conv + bias + SiLU; writes xbcT[s][m][c] ----------------
__global__ __launch_bounds__(256) void k_conv(
    const float* __restrict__ skipxs, const float* __restrict__ bc_pre,
    const float* __restrict__ wxs, const float* __restrict__ bxs,
    const float* __restrict__ wbc, const float* __restrict__ bbc,
    float* __restrict__ xbcT)
{
  const int m = blockIdx.x, s = blockIdx.y;
  const int h = m >> 5, w = m & 31;
  const float* xp = skipxs + (size_t)s * LSEQ * 1536 + 1024;
  const float* bp = bc_pre + (size_t)s * LSEQ * CBCDT;
  for (int c = threadIdx.x; c < CTOT; c += 256) {
    const float* src; int stride; const float* wt; float bias;
    if (c < DSSM) { src = xp + c; stride = 1536; wt = wxs + (size_t)c * 9; bias = bxs[c]; }
    else { int cb = c - DSSM; src = bp + cb; stride = CBCDT; wt = wbc + (size_t)cb * 9; bias = bbc[cb]; }
    float acc = bias;
#pragma unroll
    for (int dh = -1; dh <= 1; ++dh) {
      int h2 = h + dh; if (h2 < 0 || h2 > 31) continue;
#pragma unroll
      for (int dw = -1; dw <= 1; ++dw) {
        int w2 = w + dw; if (w2 < 0 || w2 > 31) continue;
        acc += src[(size_t)(h2 * 32 + w2) * stride] * wt[(dh + 1) * 3 + (dw + 1)];
      }
    }
    xbcT[((size_t)s * LSEQ + m) * CTOT + c] = siluf(acc);
  }
}

// ---------------- fused gathers: [0,512) Xh, [512,576) B/C/BT, [576,592) dA+cumsum ----------------
__global__ __launch_bounds__(256) void k_gather_all(
    const float* __restrict__ xbcT, const float* __restrict__ dt_bias,
    const float* __restrict__ A_logs,
    ushort* __restrict__ XhT, ushort* __restrict__ Bbf, ushort* __restrict__ Cbf,
    ushort* __restrict__ BT, float* __restrict__ dAcs)
{
  __shared__ __align__(16) ushort U[128 * 72];
  const int bid = blockIdx.x, s = blockIdx.y, t = threadIdx.x;
  if (bid < 512) {
    // gather x*dt -> XhT[s][kh][p][l]   (16 lt x 32 kh)
    const int lt = bid & 15, kh = bid >> 4;
    const int k = kh >> 3, hh = kh & 7;
    const int r = t >> 2, q = t & 3;
    const int l = lt * 64 + r;
    const int m = dir_src(k, l);
    const float* row = xbcT + ((size_t)s * LSEQ + m) * CTOT;
    float dtv = softplusf(row[768 + hh] + dt_bias[kh]);
    const float* xp = row + hh * 64 + q * 16;
#pragma unroll
    for (int i = 0; i < 16; ++i)
      U[(q * 16 + i) * 72 + r] = f2bf(xp[i] * dtv);
    __syncthreads();
    ushort* dst = XhT + (((size_t)s * HK + kh) * HD + r) * LSEQ + lt * 64 + q * 16;
    *(uint4*)dst       = *(const uint4*)&U[r * 72 + q * 16];
    *(uint4*)(dst + 8) = *(const uint4*)&U[r * 72 + q * 16 + 8];
    return;
  }
  if (bid < 576) {
    // gather B/C (bf16) + in-block transpose -> BT   (16 lt x 4 k)
    const int idx = bid - 512;
    const int lt = idx & 15, k = idx >> 4;
    const int r = t >> 2, q = t & 3;
    const int l = lt * 64 + r;
    const int m = dir_src(k, l);
    const float* row = xbcT + ((size_t)s * LSEQ + m) * CTOT;
    {
      const float* bsrc = row + 512 + q * 32;
      ushort ub[32];
#pragma unroll
      for (int i2 = 0; i2 < 8; ++i2) {
        float4 v = *(const float4*)(bsrc + i2 * 4);
        ub[i2 * 4 + 0] = f2bf(v.x); ub[i2 * 4 + 1] = f2bf(v.y);
        ub[i2 * 4 + 2] = f2bf(v.z); ub[i2 * 4 + 3] = f2bf(v.w);
      }
      ushort* bd = Bbf + ((size_t)s * LSEQ + l) * NSTATE + k * 128 + q * 32;
#pragma unroll
      for (int i2 = 0; i2 < 4; ++i2) *(uint4*)(bd + i2 * 8) = *(const uint4*)&ub[i2 * 8];
#pragma unroll
      for (int i = 0; i < 32; ++i) U[(q * 32 + i) * 72 + r] = ub[i];
    }
    {
      const float* csrc = row + 640 + q * 32;
      ushort uc[32];
#pragma unroll
      for (int i2 = 0; i2 < 8; ++i2) {
        float4 v = *(const float4*)(csrc + i2 * 4);
        uc[i2 * 4 + 0] = f2bf(v.x); uc[i2 * 4 + 1] = f2bf(v.y);
        uc[i2 * 4 + 2] = f2bf(v.z); uc[i2 * 4 + 3] = f2bf(v.w);
      }
      ushort* cd = Cbf + ((size_t)s * LSEQ + l) * NSTATE + k * 128 + q * 32;
#pragma unroll
      for (int i2 = 0; i2 < 4; ++i2) *(uint4*)(cd + i2 * 8) = *(const uint4*)&uc[i2 * 8];
    }
    __syncthreads();
    {
      const int n = t >> 1, half = t & 1;
      ushort* dst = BT + ((size_t)s * NSTATE + k * 128 + n) * LSEQ + lt * 64 + half * 32;
      const ushort* src = &U[n * 72 + half * 32];
#pragma unroll
      for (int i2 = 0; i2 < 4; ++i2) *(uint4*)(dst + i2 * 8) = *(const uint4*)(src + i2 * 8);
    }
    return;
  }
  // dA + per-chunk inclusive cumsum   (4 k x 4 z)
  {
    float* Lf = (float*)U;
    const int idx = bid - 576;
    const int z = idx & 3, k = idx >> 2;
    const int m = dir_src(k, z * 256 + t);
    const float* rowdt = xbcT + ((size_t)s * LSEQ + m) * CTOT + 768;
    float4 d0 = *(const float4*)rowdt;
    float4 d1 = *(const float4*)(rowdt + 4);
    float dv[8] = { d0.x, d0.y, d0.z, d0.w, d1.x, d1.y, d1.z, d1.w };
#pragma unroll
    for (int hh = 0; hh < 8; ++hh) {
      int kh = k * 8 + hh;
      float dAv = softplusf(dv[hh] + dt_bias[kh]) * (-expf(A_logs[kh]));
      Lf[hh * 256 + t] = dAv;
    }
    __syncthreads();
    const int hh = t >> 5, seg = t & 31;
    float p[8]; float run = 0.f;
#pragma unroll
    for (int i = 0; i < 8; ++i) { run += Lf[hh * 256 + seg * 8 + i]; p[i] = run; }
    float sc = run, tot = run;
#pragma unroll
    for (int d = 1; d < 32; d <<= 1) {
      float o = __shfl_up(sc, d, 32);
      if (seg >= d) sc += o;
    }
    float off = sc - tot;
    float* dst = dAcs + ((size_t)s * HK + k * 8 + hh) * LSEQ + z * 256 + seg * 8;
#pragma unroll
    for (int i = 0; i < 8; ++i) dst[i] = p[i] + off;
  }
}

// ---------------- fused scan core: [0,80) CB lower-tri tiles, [80,592) states+scan ----------------
__global__ __launch_bounds__(256) void k_scan_core(
    const ushort* __restrict__ Cbf, const ushort* __restrict__ Bbf, ushort* __restrict__ CBbf,
    const ushort* __restrict__ BT, const ushort* __restrict__ XhT,
    const float* __restrict__ dAcs, ushort* __restrict__ prevP)
{
  __shared__ __align__(16) ushort As[64 * 72];
  __shared__ __align__(16) ushort Bs[64 * 72];
  __shared__ __align__(16) ushort Tr[64 * 72];
  __shared__ float decay[CHUNKSZ];
  const int bid = blockIdx.x, t = threadIdx.x;
  const int lane = t & 63, wv = t >> 6;
  const int lrow = lane & 15, lk8 = (lane >> 4) * 8;

  if (bid < 80) {
    // CB = C @ B^T, lower-triangular 64x64 tiles only (jt <= it)
    const int sz = bid & 7, pidx = bid >> 3, s = sz >> 2, z = sz & 3;
    int it = 0; { while ((it + 1) * (it + 2) / 2 <= pidx) ++it; }
    const int jt = pidx - it * (it + 1) / 2;
    const int r = t >> 2, c0 = (t & 3) * 16;
    const ushort* Ap = Cbf + ((size_t)s * LSEQ + z * CHUNKSZ + it * 64 + r) * NSTATE + c0;
    const ushort* Bp = Bbf + ((size_t)s * LSEQ + z * CHUNKSZ + jt * 64 + r) * NSTATE + c0;
    uint4 qa[2], qb[2];
#define CBISSUE(k0) do { qa[0]=*(const uint4*)(Ap+(k0)); qa[1]=*(const uint4*)(Ap+(k0)+8); \
                         qb[0]=*(const uint4*)(Bp+(k0)); qb[1]=*(const uint4*)(Bp+(k0)+8); } while(0)
    CBISSUE(0);
    f32x4 acc[4] = {};
    for (int k0 = 0; k0 < NSTATE; k0 += 64) {
      *(uint4*)&As[r * 72 + c0] = qa[0]; *(uint4*)&As[r * 72 + c0 + 8] = qa[1];
      *(uint4*)&Bs[r * 72 + c0] = qb[0]; *(uint4*)&Bs[r * 72 + c0 + 8] = qb[1];
      __syncthreads();
      if (k0 + 64 < NSTATE) CBISSUE(k0 + 64);
#pragma unroll
      for (int sub = 0; sub < 2; ++sub) {
        const int ko = lk8 + sub * 32;
        short8 a = *(const short8*)&As[(16 * wv + lrow) * 72 + ko];
#pragma unroll
        for (int fj = 0; fj < 4; ++fj) {
          short8 b = *(const short8*)&Bs[(16 * fj + lrow) * 72 + ko];
          acc[fj] = __builtin_amdgcn_mfma_f32_16x16x32_bf16(a, b, acc[fj], 0, 0, 0);
        }
      }
      __syncthreads();
    }
    ushort* Cp = CBbf + (size_t)sz * CHUNKSZ * CHUNKSZ;
    const int row0 = it * 64 + 16 * wv + (lane >> 4) * 4;
#pragma unroll
    for (int fj = 0; fj < 4; ++fj) {
      int col = jt * 64 + 16 * fj + lrow;
#pragma unroll
      for (int rr = 0; rr < 4; ++rr)
        Cp[(size_t)(row0 + rr) * CHUNKSZ + col] = f2bf(acc[fj][rr]);
    }
    return;
  }

  // states + inter-chunk scan -> prevP
  {
    const int idx = bid - 80;
    const int nh = idx & 7, kh = (idx >> 3) & 31, s = idx >> 8;
    const int rA = t >> 2, cA = (t & 3) * 16;
    const float* dA = dAcs + ((size_t)s * HK + kh) * LSEQ;
    float carry[4][4];
#pragma unroll
    for (int fj = 0; fj < 4; ++fj)
#pragma unroll
      for (int rr = 0; rr < 4; ++rr) carry[fj][rr] = 0.f;

    for (int z = 0; z < NC; ++z) {
      __syncthreads();
      const float dlast = dA[z * CHUNKSZ + CHUNKSZ - 1];
      decay[t] = __expf(dlast - dA[z * CHUNKSZ + t]);
      {
        const int n_base = 16 * wv + (lane >> 4) * 4;
#pragma unroll
        for (int fj = 0; fj < 4; ++fj) {
          const int p = 16 * fj + lrow;
#pragma unroll
          for (int rr = 0; rr < 4; ++rr)
            Tr[p * 72 + n_base + rr] = f2bf(carry[fj][rr]);
        }
      }
      __syncthreads();
      {
        const int sz = s * 4 + z;
        ushort* dst = prevP + (((size_t)sz * HK + kh) * HD + rA) * NSTATE + nh * 64 + cA;
        *(uint4*)dst       = *(const uint4*)&Tr[rA * 72 + cA];
        *(uint4*)(dst + 8) = *(const uint4*)&Tr[rA * 72 + cA + 8];
      }
      const ushort* Ap = BT + ((size_t)s * NSTATE + nh * 64 + rA) * LSEQ + z * CHUNKSZ + cA;
      const ushort* Xp = XhT + (((size_t)s * HK + kh) * HD + rA) * LSEQ + z * CHUNKSZ + cA;
      uint4 qa[2], qb[2];
#define SSISSUE(k0) do { qa[0]=*(const uint4*)(Ap+(k0)); qa[1]=*(const uint4*)(Ap+(k0)+8); \
                         qb[0]=*(const uint4*)(Xp+(k0)); qb[1]=*(const uint4*)(Xp+(k0)+8); } while(0)
      SSISSUE(0);
      f32x4 acc[4] = {};
      for (int k0 = 0; k0 < CHUNKSZ; k0 += 64) {
        *(uint4*)&As[rA * 72 + cA] = qa[0]; *(uint4*)&As[rA * 72 + cA + 8] = qa[1];
        {
          ushort tmp[16];
          *(uint4*)&tmp[0] = qb[0]; *(uint4*)&tmp[8] = qb[1];
#pragma unroll
          for (int i2 = 0; i2 < 8; ++i2) {
            int c = k0 + cA + 2 * i2;
            unsigned wpk = (unsigned)f2bf(bf2f(tmp[2 * i2]) * decay[c]) |
                           ((unsigned)f2bf(bf2f(tmp[2 * i2 + 1]) * decay[c + 1]) << 16);
            *(unsigned*)&Bs[rA * 72 + cA + 2 * i2] = wpk;
          }
        }
        __syncthreads();
        if (k0 + 64 < CHUNKSZ) SSISSUE(k0 + 64);
#pragma unroll
        for (int sub = 0; sub < 2; ++sub) {
          const int ko = lk8 + sub * 32;
          short8 a = *(const short8*)&As[(16 * wv + lrow) * 72 + ko];
#pragma unroll
          for (int fj = 0; fj < 4; ++fj) {
            short8 b = *(const short8*)&Bs[(16 * fj + lrow) * 72 + ko];
            acc[fj] = __builtin_amdgcn_mfma_f32_16x16x32_bf16(a, b, acc[fj], 0, 0, 0);
          }
        }
        __syncthreads();
      }
      const float cdec = __expf(dlast);
#pragma unroll
      for (int fj = 0; fj < 4; ++fj)
#pragma unroll
        for (int rr = 0; rr < 4; ++rr)
          carry[fj][rr] = carry[fj][rr] * cdec + acc[fj][rr];
    }
  }
}

// ---------------- Y = Ydiag + Yoff (MFMA, pipelined, bf16 out) ----------------
__global__ __launch_bounds__(256) void k_y_mfma(
    const ushort* __restrict__ CBbf, const ushort* __restrict__ XhT,
    const ushort* __restrict__ Cbf, const ushort* __restrict__ prevP,
    const float* __restrict__ dAcs, ushort* __restrict__ Ybf)
{
  __shared__ __align__(16) ushort As[128 * 72];
  __shared__ __align__(16) ushort Bs[64 * 72];
  __shared__ float seg[CHUNKSZ];
  __shared__ float f2s[CHUNKSZ];
  const int it = blockIdx.x, kh = blockIdx.y, sz = blockIdx.z, s = sz >> 2, z = sz & 3;
  const int t = threadIdx.x, lane = t & 63, wv = t >> 6;
  const int lrow = lane & 15, lk8 = (lane >> 4) * 8;
  const int i0 = it * 128;
  const float* dAp = dAcs + ((size_t)s * HK + kh) * LSEQ + z * CHUNKSZ;
  seg[t] = dAp[t];
  __syncthreads();
  f2s[t] = __expf(seg[(t >> 5) << 5] - seg[t]);

  const int rA = t >> 1, cA = (t & 1) * 32;
  const int rB = t >> 2, cB = (t & 3) * 16;
  f32x4 acc[2][4] = {};
  uint4 qa[4], qb[2];

  // phase A: acc = C @ prev^T
  const ushort* Cp = Cbf + ((size_t)s * LSEQ + z * CHUNKSZ + i0 + rA) * NSTATE + cA;
  const ushort* Pp = prevP + (((size_t)sz * HK + kh) * HD + rB) * NSTATE + cB;
#define YISSUEA(k0) do { \
    qa[0]=*(const uint4*)(Cp+(k0));    qa[1]=*(const uint4*)(Cp+(k0)+8); \
    qa[2]=*(const uint4*)(Cp+(k0)+16); qa[3]=*(const uint4*)(Cp+(k0)+24); \
    qb[0]=*(const uint4*)(Pp+(k0));    qb[1]=*(const uint4*)(Pp+(k0)+8); } while(0)
  YISSUEA(0);
  for (int k0 = 0; k0 < NSTATE; k0 += 64) {
#pragma unroll
    for (int q2 = 0; q2 < 4; ++q2) *(uint4*)&As[rA * 72 + cA + q2 * 8] = qa[q2];
    *(uint4*)&Bs[rB * 72 + cB] = qb[0]; *(uint4*)&Bs[rB * 72 + cB + 8] = qb[1];
    __syncthreads();
    if (k0 + 64 < NSTATE) YISSUEA(k0 + 64);
#pragma unroll
    for (int sub = 0; sub < 2; ++sub) {
      const int ko = lk8 + sub * 32;
      short8 a[2], b[4];
#pragma unroll
      for (int f = 0; f < 2; ++f) a[f] = *(const short8*)&As[(32 * wv + 16 * f + lrow) * 72 + ko];
#pragma unroll
      for (int f = 0; f < 4; ++f) b[f] = *(const short8*)&Bs[(16 * f + lrow) * 72 + ko];
#pragma unroll
      for (int fi = 0; fi < 2; ++fi)
#pragma unroll
        for (int fj = 0; fj < 4; ++fj)
          acc[fi][fj] = __builtin_amdgcn_mfma_f32_16x16x32_bf16(a[fi], b[fj], acc[fi][fj], 0, 0, 0);
    }
    __syncthreads();
  }

  // prefetch phase-B tile 0 while rescaling
  const ushort* CBp = CBbf + ((size_t)sz * CHUNKSZ + i0 + rA) * CHUNKSZ;
  const ushort* Xp = XhT + (((size_t)s * HK + kh) * HD + rB) * LSEQ + z * CHUNKSZ + cB;
  const int nktB = 2 * it + 2;
#define YISSUEB(kt) do { const ushort* sa = CBp + (kt) * 64 + cA; \
    qa[0]=*(const uint4*)sa;      qa[1]=*(const uint4*)(sa+8); \
    qa[2]=*(const uint4*)(sa+16); qa[3]=*(const uint4*)(sa+24); \
    qb[0]=*(const uint4*)(Xp+(kt)*64); qb[1]=*(const uint4*)(Xp+(kt)*64+8); } while(0)
  YISSUEB(0);

  // scale Yoff rows by e^{seg_i}
#pragma unroll
  for (int fi = 0; fi < 2; ++fi) {
    int rloc = 32 * wv + 16 * fi + (lane >> 4) * 4;
#pragma unroll
    for (int rr = 0; rr < 4; ++rr) {
      float e = __expf(seg[i0 + rloc + rr]);
#pragma unroll
      for (int fj = 0; fj < 4; ++fj) acc[fi][fj][rr] *= e;
    }
  }

  // phase B: Ydiag (slice-factored, CB bf16)
  for (int kt = 0; kt < nktB; ++kt) {
    {
      const int i = i0 + rA;
      const int jbase = kt * 64 + cA;
      if (i >= jbase) {
        float f1 = __expf(seg[i] - seg[jbase]);
        ushort tmp[32];
        *(uint4*)&tmp[0] = qa[0]; *(uint4*)&tmp[8] = qa[1];
        *(uint4*)&tmp[16] = qa[2]; *(uint4*)&tmp[24] = qa[3];
#pragma unroll
        for (int c = 0; c < 32; c += 2) {
          int j = jbase + c;
          float v0 = (j     <= i) ? bf2f(tmp[c])     * f1 : 0.f;
          float v1 = (j + 1 <= i) ? bf2f(tmp[c + 1]) * f1 : 0.f;
          *(unsigned*)&As[rA * 72 + cA + c] = (unsigned)f2bf(v0) | ((unsigned)f2bf(v1) << 16);
        }
      } else {
        uint4 zz = {0, 0, 0, 0};
#pragma unroll
        for (int q2 = 0; q2 < 4; ++q2) *(uint4*)&As[rA * 72 + cA + q2 * 8] = zz;
      }
    }
    {
      ushort tmp[16];
      *(uint4*)&tmp[0] = qb[0]; *(uint4*)&tmp[8] = qb[1];
#pragma unroll
      for (int i2 = 0; i2 < 8; ++i2) {
        int j = kt * 64 + cB + 2 * i2;
        unsigned wpk = (unsigned)f2bf(bf2f(tmp[2 * i2]) * f2s[j]) |
                       ((unsigned)f2bf(bf2f(tmp[2 * i2 + 1]) * f2s[j + 1]) << 16);
        *(unsigned*)&Bs[rB * 72 + cB + 2 * i2] = wpk;
      }
    }
    __syncthreads();
    if (kt + 1 < nktB) YISSUEB(kt + 1);
#pragma unroll
    for (int sub = 0; sub < 2; ++sub) {
      if (2 * kt + sub <= 4 * it + wv) {
        const int ko = lk8 + sub * 32;
        short8 a[2], b[4];
#pragma unroll
        for (int f = 0; f < 2; ++f) a[f] = *(const short8*)&As[(32 * wv + 16 * f + lrow) * 72 + ko];
#pragma unroll
        for (int f = 0; f < 4; ++f) b[f] = *(const short8*)&Bs[(16 * f + lrow) * 72 + ko];
#pragma unroll
        for (int fi = 0; fi < 2; ++fi)
#pragma unroll
          for (int fj = 0; fj < 4; ++fj)
            acc[fi][fj] = __builtin_amdgcn_mfma_f32_16x16x32_bf16(a[fi], b[fj], acc[fi][fj], 0, 0, 0);
      }
    }
    __syncthreads();
  }

  ushort* Yp = Ybf + (((size_t)s * LSEQ + z * CHUNKSZ + i0) * HK + kh) * HD;
#pragma unroll
  for (int fi = 0; fi < 2; ++fi) {
    int row0 = 32 * wv + 16 * fi + (lane >> 4) * 4;
#pragma unroll
    for (int fj = 0; fj < 4; ++fj) {
      int col = 16 * fj + lrow;
#pragma unroll
      for (int rr = 0; rr < 4; ++rr)
        Yp[(size_t)(row0 + rr) * (HK * HD) + col] = f2bf(acc[fi][fj][rr]);
    }
  }
}

// ---------------- combine 4 directions + D*x + gated RMSNorm + MLP half (bf16 out) ----------------
__global__ __launch_bounds__(256) void k_combine(
    const ushort* __restrict__ Ybf, const float* __restrict__ xbcT,
    const float* __restrict__ skipxs, const float* __restrict__ Ds,
    const float* __restrict__ normw, ushort* __restrict__ o768bf)
{
  const int m = blockIdx.x, s = blockIdx.y, t = threadIdx.x;
  const int h = m >> 5, w = m & 31;
  const int l0 = m, l1 = (w << 5) | h, l2 = 1023 - m, l3 = 1023 - ((w << 5) | h);
  const ushort* Yb = Ybf + (size_t)s * LSEQ * (HK * HD);
  const float* xrow = xbcT + ((size_t)s * LSEQ + m) * CTOT;
  const float* srow = skipxs + ((size_t)s * LSEQ + m) * 1536;

  float g[2];
  float ss = 0.f;
#pragma unroll
  for (int q = 0; q < 2; ++q) {
    int d = t + q * 256;
    int hh = d >> 6, p = d & 63;
    float dsum = Ds[hh] + Ds[hh + 8] + Ds[hh + 16] + Ds[hh + 24];
    float val = bf2f(Yb[((size_t)l0 * HK + hh) * HD + p])
              + bf2f(Yb[((size_t)l1 * HK + 8 + hh) * HD + p])
              + bf2f(Yb[((size_t)l2 * HK + 16 + hh) * HD + p])
              + bf2f(Yb[((size_t)l3 * HK + 24 + hh) * HD + p])
              + xrow[d] * dsum;
    float zv = srow[512 + d];
    g[q] = val * siluf(zv);
    ss += g[q] * g[q];
  }
  for (int off = 32; off > 0; off >>= 1) ss += __shfl_down(ss, off, 64);
  __shared__ float red[4];
  if ((t & 63) == 0) red[t >> 6] = ss;
  __syncthreads();
  float total = red[0] + red[1] + red[2] + red[3];
  float scale = rsqrtf(total * (1.f / 512.f) + 1e-5f);

  ushort* orow = o768bf + ((size_t)s * LSEQ + m) * 768;
#pragma unroll
  for (int q = 0; q < 2; ++q) {
    int d = t + q * 256;
    orow[256 + d] = f2bf(g[q] * scale * normw[d]);
  }
  float z0 = srow[t], x0 = srow[256 + t];
  orow[t] = f2bf(siluf(z0) * x0);
}

// ---------------- 64x64-tile bf16 GEMM (for small-N out GEMM) ----------------
__global__ __launch_bounds__(256) void gemm64_bf16(
    const ushort* __restrict__ A, const ushort* __restrict__ BT,
    float* __restrict__ C, int M, int N, int K)
{
  __shared__ __align__(16) ushort As[64 * 72];
  __shared__ __align__(16) ushort Bs[64 * 72];
  const int n0 = blockIdx.x * 64, m0 = blockIdx.y * 64;
  const int t = threadIdx.x, lane = t & 63, wv = t >> 6;
  const int wm = wv & 1, wn = wv >> 1;
  const int lrow = lane & 15, lk8 = (lane >> 4) * 8;
  const int rowL = t >> 2, cL = (t & 3) * 16;
  const ushort* pa_src = A + (size_t)(m0 + rowL) * K + cL;
  const int nB = n0 + rowL;
  const ushort* pb_src = BT + (size_t)nB * K + cL;
  const bool bval = (nB < N);
  uint4 pa[2], pb[2];
#define G64ISSUE(k0) do { \
    pa[0]=*(const uint4*)(pa_src+(k0)); pa[1]=*(const uint4*)(pa_src+(k0)+8); \
    if (bval) { pb[0]=*(const uint4*)(pb_src+(k0)); pb[1]=*(const uint4*)(pb_src+(k0)+8); } \
    else { uint4 z={0,0,0,0}; pb[0]=z; pb[1]=z; } } while(0)
  G64ISSUE(0);
  f32x4 acc[2][2] = {};
  for (int k0 = 0; k0 < K; k0 += 64) {
    *(uint4*)&As[rowL * 72 + cL] = pa[0]; *(uint4*)&As[rowL * 72 + cL + 8] = pa[1];
    *(uint4*)&Bs[rowL * 72 + cL] = pb[0]; *(uint4*)&Bs[rowL * 72 + cL + 8] = pb[1];
    __syncthreads();
    if (k0 + 64 < K) G64ISSUE(k0 + 64);
#pragma unroll
    for (int sub = 0; sub < 2; ++sub) {
      const int ko = lk8 + sub * 32;
      short8 a[2], b[2];
#pragma unroll
      for (int f = 0; f < 2; ++f) {
        a[f] = *(const short8*)&As[(wm * 32 + 16 * f + lrow) * 72 + ko];
        b[f] = *(const short8*)&Bs[(wn * 32 + 16 * f + lrow) * 72 + ko];
      }
#pragma unroll
      for (int fi = 0; fi < 2; ++fi)
#pragma unroll
        for (int fj = 0; fj < 2; ++fj)
          acc[fi][fj] = __builtin_amdgcn_mfma_f32_16x16x32_bf16(a[fi], b[fj], acc[fi][fj], 0, 0, 0);
    }
    __syncthreads();
  }
#pragma unroll
  for (int fi = 0; fi < 2; ++fi) {
    int row0 = m0 + wm * 32 + 16 * fi + (lane >> 4) * 4;
#pragma unroll
    for (int fj = 0; fj < 2; ++fj) {
      int col = n0 + wn * 32 + 16 * fj + lrow;
      if (col < N)
#pragma unroll
        for (int rr = 0; rr < 4; ++rr)
          C[(size_t)(row0 + rr) * N + col] = acc[fi][fj][rr];
    }
  }
}

// ---------------- workspace layout (float units) ----------------
constexpr size_t OFF_SKIPXS = 0;                         // 2048*1536 f32 = 3145728
constexpr size_t OFF_XBCT   = 3145728;                   // 1589248
constexpr size_t OFF_XHT    = OFF_XBCT + 1589248;        // bf16 -> 2097152 f
constexpr size_t OFF_BBF    = OFF_XHT + 2097152;         // 524288
constexpr size_t OFF_CBF    = OFF_BBF + 524288;          // 524288
constexpr size_t OFF_BTBF   = OFF_CBF + 524288;          // 524288
constexpr size_t OFF_DA     = OFF_BTBF + 524288;         // 65536
constexpr size_t OFF_CB     = OFF_DA + 65536;            // bf16 -> 262144 f
constexpr size_t OFF_PREV   = OFF_CB + 262144;           // bf16 -> 4194304 f
constexpr size_t OFF_Y      = OFF_PREV + 4194304;        // bf16 -> 2097152 f
constexpr size_t OFF_O768   = OFF_Y + 2097152;           // bf16 -> 786432 f
constexpr size_t OFF_WSXT   = OFF_O768 + 786432;         // 294912
constexpr size_t OFF_WBCT   = OFF_WSXT + 294912;         // 50688
constexpr size_t OFF_WOUT   = OFF_WBCT + 50688;          // 147456
constexpr size_t OFF_BCP    = OFF_PREV;                  // overlay: bc_pre (dead before prevP written)

extern "C" void kernel_launch(void* const* d_in, const int* in_sizes, int n_in,
                              void* d_out, int out_size, void* d_ws, size_t ws_size,
                              hipStream_t stream)
{
  const float* u1     = (const float*)d_in[0];
  const float* u2     = (const float*)d_in[1];
  const float* u2c1   = (const float*)d_in[2];
  const float* u1c2   = (const float*)d_in[3];
  const float* W_skip = (const float*)d_in[4];
  const float* W_xs   = (const float*)d_in[5];
  const float* W_bcdt = (const float*)d_in[6];
  const float* cxw    = (const float*)d_in[7];
  const float* cxb    = (const float*)d_in[8];
  const float* cbw    = (const float*)d_in[9];
  const float* cbb    = (const float*)d_in[10];
  const float* Ds     = (const float*)d_in[11];
  const float* normw  = (const float*)d_in[12];
  const float* W_out  = (const float*)d_in[13];
  const float* dt_b   = (const float*)d_in[14];
  const float* A_logs = (const float*)d_in[15];
  float* out = (float*)d_out;
  float* ws  = (float*)d_ws;

  float*  skipxs  = ws + OFF_SKIPXS;
  float*  xbcT    = ws + OFF_XBCT;
  ushort* XhT     = (ushort*)(ws + OFF_XHT);
  ushort* Bbf     = (ushort*)(ws + OFF_BBF);
  ushort* Cbf     = (ushort*)(ws + OFF_CBF);
  ushort* BTbf    = (ushort*)(ws + OFF_BTBF);
  float*  dAcs    = ws + OFF_DA;
  ushort* CBbf    = (ushort*)(ws + OFF_CB);
  ushort* prevP   = (ushort*)(ws + OFF_PREV);
  ushort* Ybf     = (ushort*)(ws + OFF_Y);
  ushort* o768bf  = (ushort*)(ws + OFF_O768);
  ushort* WsxT    = (ushort*)(ws + OFF_WSXT);
  ushort* WbcdtT  = (ushort*)(ws + OFF_WBCT);
  ushort* WoutT   = (ushort*)(ws + OFF_WOUT);
  float*  bc_pre  = ws + OFF_BCP;

  // 1: weight transposes
  k_prep<<<dim3(246), 256, 0, stream>>>(W_skip, W_xs, W_bcdt, W_out, WsxT, WbcdtT, WoutT);
  // 2: both input GEMMs in one launch (concurrent blocks)
  k_gemm_in<<<dim3(12, 16, 2), 256, 0, stream>>>(u1, u2, u2c1, u1c2, WsxT, WbcdtT, skipxs, bc_pre);
  // 3: conv
  k_conv<<<dim3(1024, 2), 256, 0, stream>>>(skipxs, bc_pre, cxw, cxb, cbw, cbb, xbcT);
  // 4: all gathers + cumsum in one launch
  k_gather_all<<<dim3(592, 2), 256, 0, stream>>>(xbcT, dt_b, A_logs, XhT, Bbf, Cbf, BTbf, dAcs);
  // 5: CB (lower-tri) + states/scan in one launch
  k_scan_core<<<dim3(592), 256, 0, stream>>>(Cbf, Bbf, CBbf, BTbf, XhT, dAcs, prevP);
  // 6: Y
  k_y_mfma<<<dim3(2, 32, 8), 256, 0, stream>>>(CBbf, XhT, Cbf, prevP, dAcs, Ybf);
  // 7: combine
  k_combine<<<dim3(1024, 2), 256, 0, stream>>>(Ybf, xbcT, skipxs, Ds, normw, o768bf);
  // 8: out GEMM (64-tile, 192 blocks)
  gemm64_bf16<<<dim3(6, 32), 256, 0, stream>>>(o768bf, WoutT, out, 2048, 384, 768);
}